// Round 1
// baseline (9244.659 us; speedup 1.0000x reference)
//
#include <hip/hip_runtime.h>
#include <math.h>

#define DEV_INLINE __device__ __forceinline__

namespace {

constexpr int Bn = 8, Cn = 32, Nn = 16384, Rn = 32, Vn = Rn * Rn * Rn;

DEV_INLINE float siluf(float x) { return x / (1.0f + expf(-x)); }

// ---------------- coords: per-batch mean, max-norm, nc, voxel idx ----------------
__global__ void k_coords(const float* __restrict__ coords,
                         float* __restrict__ nc, int* __restrict__ vidx) {
  int b = blockIdx.x;
  int t = threadIdx.x;  // 256
  __shared__ float red[256];
  __shared__ float mean_s[3];
  __shared__ float denom_s;
  const float* cb = coords + (size_t)b * 3 * Nn;

  float sx = 0.f, sy = 0.f, sz = 0.f;
  for (int n = t; n < Nn; n += 256) {
    sx += cb[n]; sy += cb[Nn + n]; sz += cb[2 * Nn + n];
  }
  float vals[3] = {sx, sy, sz};
  for (int a = 0; a < 3; ++a) {
    red[t] = vals[a]; __syncthreads();
    for (int s = 128; s > 0; s >>= 1) {
      if (t < s) red[t] += red[t + s];
      __syncthreads();
    }
    if (t == 0) mean_s[a] = red[0] / (float)Nn;
    __syncthreads();
  }
  float mx = mean_s[0], my = mean_s[1], mz = mean_s[2];

  float mq = 0.f;
  for (int n = t; n < Nn; n += 256) {
    float x = cb[n] - mx, y = cb[Nn + n] - my, z = cb[2 * Nn + n] - mz;
    mq = fmaxf(mq, x * x + y * y + z * z);
  }
  red[t] = mq; __syncthreads();
  for (int s = 128; s > 0; s >>= 1) {
    if (t < s) red[t] = fmaxf(red[t], red[t + s]);
    __syncthreads();
  }
  if (t == 0) denom_s = 2.0f * sqrtf(red[0]);
  __syncthreads();
  float inv = 1.0f / denom_s;

  float* ncb = nc + (size_t)b * 3 * Nn;
  int* ib = vidx + (size_t)b * Nn;
  for (int n = t; n < Nn; n += 256) {
    float x = (cb[n] - mx) * inv + 0.5f;
    float y = (cb[Nn + n] - my) * inv + 0.5f;
    float z = (cb[2 * Nn + n] - mz) * inv + 0.5f;
    x = fminf(fmaxf(x * (float)Rn, 0.f), (float)(Rn - 1));
    y = fminf(fmaxf(y * (float)Rn, 0.f), (float)(Rn - 1));
    z = fminf(fmaxf(z * (float)Rn, 0.f), (float)(Rn - 1));
    ncb[n] = x; ncb[Nn + n] = y; ncb[2 * Nn + n] = z;
    int vx = (int)rintf(x), vy = (int)rintf(y), vz = (int)rintf(z);
    ib[n] = (vx * Rn + vy) * Rn + vz;
  }
}

// ---------------- weight transpose: w[co][ci][k] -> wt[k][co][ci] ----------------
__global__ void k_twz(const float* __restrict__ w, float* __restrict__ wt) {
  int i = blockIdx.x * 256 + threadIdx.x;  // 27648 dest elements
  if (i >= 27 * 32 * 32) return;
  int ci = i & 31, co = (i >> 5) & 31, k = i >> 10;
  wt[i] = w[(co * 32 + ci) * 27 + k];
}

// ---------------- modulation vectors m = silu(cond) @ mw.T + mb ----------------
__global__ void k_mods(const float* __restrict__ cond,
                       const float* __restrict__ w1, const float* __restrict__ b1,
                       const float* __restrict__ w2, const float* __restrict__ b2,
                       const float* __restrict__ wp, const float* __restrict__ bp,
                       float* __restrict__ m1, float* __restrict__ m2,
                       float* __restrict__ mp) {
  __shared__ float sc[2048];  // silu(cond), 8 x 256
  int t = threadIdx.x;
  for (int i = t; i < 2048; i += 256) sc[i] = siluf(cond[i]);
  __syncthreads();
  for (int o = t; o < 1536; o += 256) {
    int mat = o / 512, rem = o - mat * 512;
    int b = rem >> 6, oo = rem & 63;
    const float* w = (mat == 0) ? w1 : ((mat == 1) ? w2 : wp);
    const float* bb = (mat == 0) ? b1 : ((mat == 1) ? b2 : bp);
    float acc = bb[oo];
    const float* wrow = w + oo * 256;
    const float* scb = sc + b * 256;
    for (int k = 0; k < 256; ++k) acc += wrow[k] * scb[k];
    float* dst = (mat == 0) ? m1 : ((mat == 1) ? m2 : mp);
    dst[b * 64 + oo] = acc;
  }
}

// ---------------- scatter-add features into voxel grid ----------------
__global__ void k_scatter(const float* __restrict__ feat, const int* __restrict__ vidx,
                          float* __restrict__ sums, float* __restrict__ cnt) {
  int i = blockIdx.x * 256 + threadIdx.x;  // over B*N
  int b = i >> 14, n = i & (Nn - 1);
  int v = vidx[i];
  float* dst = sums + (size_t)(b * Vn + v) * Cn;
  const float* f = feat + (size_t)b * Cn * Nn + n;
  #pragma unroll
  for (int c = 0; c < Cn; ++c) atomicAdd(dst + c, f[(size_t)c * Nn]);
  atomicAdd(cnt + b * Vn + v, 1.0f);
}

// ---------------- divide sums by counts ----------------
__global__ void k_normvox(const float* __restrict__ sums, const float* __restrict__ cnt,
                          float4* __restrict__ out) {
  int i = blockIdx.x * 256 + threadIdx.x;  // over B*V*8 float4s
  int bv = i >> 3;
  float invc = 1.0f / fmaxf(cnt[bv], 1.0f);
  float4 v = reinterpret_cast<const float4*>(sums)[i];
  v.x *= invc; v.y *= invc; v.z *= invc; v.w *= invc;
  out[i] = v;
}

// ---------------- 3x3x3 conv, channel-last, optional fused affine+silu on input ----------------
template <bool AFF>
__global__ __launch_bounds__(256, 4) void k_conv(
    const float* __restrict__ in, const float* __restrict__ wt,
    const float* __restrict__ bias, const float* __restrict__ Ac,
    const float* __restrict__ Bc, float* __restrict__ out) {
  __shared__ float lds[9 * 1024];  // [plane][z][ci] 36.9 KB -> 4 blocks/CU
  int blk = blockIdx.x;
  int y = blk & 31, x = (blk >> 5) & 31, b = blk >> 10;
  int t = threadIdx.x;

  float4 A4, B4;
  if (AFF) {
    A4 = reinterpret_cast<const float4*>(Ac)[b * 8 + (t & 7)];
    B4 = reinterpret_cast<const float4*>(Bc)[b * 8 + (t & 7)];
  }
  #pragma unroll
  for (int p = 0; p < 9; ++p) {
    int dx = p / 3, dy = p % 3;
    int gx = x + dx - 1, gy = y + dy - 1;
    float4 val = make_float4(0.f, 0.f, 0.f, 0.f);
    if (gx >= 0 && gx < 32 && gy >= 0 && gy < 32) {
      const float4* src = reinterpret_cast<const float4*>(
          in + ((size_t)b * Vn + (size_t)(gx * 32 + gy) * 32) * 32);
      val = src[t];
      if (AFF) {
        val.x = siluf(val.x * A4.x + B4.x);
        val.y = siluf(val.y * A4.y + B4.y);
        val.z = siluf(val.z * A4.z + B4.z);
        val.w = siluf(val.w * A4.w + B4.w);
      }
    }
    reinterpret_cast<float4*>(lds)[p * 256 + t] = val;
  }
  __syncthreads();

  int co = t & 31, z0 = (t >> 5) * 4;
  float bco = bias[co];
  float acc0 = bco, acc1 = bco, acc2 = bco, acc3 = bco;
  for (int pq = 0; pq < 9; ++pq) {
    const float4* P = reinterpret_cast<const float4*>(lds + pq * 1024);
    #pragma unroll
    for (int ci4 = 0; ci4 < 8; ++ci4) {
      float4 a0, a1, a2, a3, a4, a5;
      a0 = (z0 - 1 >= 0) ? P[(z0 - 1) * 8 + ci4] : make_float4(0.f, 0.f, 0.f, 0.f);
      a1 = P[(z0 + 0) * 8 + ci4];
      a2 = P[(z0 + 1) * 8 + ci4];
      a3 = P[(z0 + 2) * 8 + ci4];
      a4 = P[(z0 + 3) * 8 + ci4];
      a5 = (z0 + 4 < 32) ? P[(z0 + 4) * 8 + ci4] : make_float4(0.f, 0.f, 0.f, 0.f);
      #pragma unroll
      for (int dz = 0; dz < 3; ++dz) {
        float4 w4 = reinterpret_cast<const float4*>(wt)[((pq * 3 + dz) * 32 + co) * 8 + ci4];
        const float4 i0 = dz == 0 ? a0 : (dz == 1 ? a1 : a2);
        const float4 i1 = dz == 0 ? a1 : (dz == 1 ? a2 : a3);
        const float4 i2 = dz == 0 ? a2 : (dz == 1 ? a3 : a4);
        const float4 i3 = dz == 0 ? a3 : (dz == 1 ? a4 : a5);
        acc0 += w4.x * i0.x + w4.y * i0.y + w4.z * i0.z + w4.w * i0.w;
        acc1 += w4.x * i1.x + w4.y * i1.y + w4.z * i1.z + w4.w * i1.w;
        acc2 += w4.x * i2.x + w4.y * i2.y + w4.z * i2.z + w4.w * i2.w;
        acc3 += w4.x * i3.x + w4.y * i3.y + w4.z * i3.z + w4.w * i3.w;
      }
    }
  }
  float* o = out + ((size_t)b * Vn + (size_t)(x * 32 + y) * 32 + z0) * 32 + co;
  o[0] = acc0; o[32] = acc1; o[64] = acc2; o[96] = acc3;
}

// ---------------- per-channel sum/sumsq on channel-last (B,V,C) ----------------
__global__ void k_stats_cl(const float* __restrict__ x, float* __restrict__ psum,
                           float* __restrict__ psq) {
  int blk = blockIdx.x;  // B*128
  int b = blk >> 7, chunk = blk & 127;
  int t = threadIdx.x;
  int g = t & 7, sub = t >> 3;
  float sx = 0, sy = 0, sz = 0, sw = 0, qx = 0, qy = 0, qz = 0, qw = 0;
  const float4* xb = reinterpret_cast<const float4*>(x + (size_t)b * Vn * Cn);
  for (int it = 0; it < 8; ++it) {
    int v = chunk * 256 + it * 32 + sub;
    float4 val = xb[v * 8 + g];
    sx += val.x; sy += val.y; sz += val.z; sw += val.w;
    qx += val.x * val.x; qy += val.y * val.y; qz += val.z * val.z; qw += val.w * val.w;
  }
  for (int m = 8; m <= 32; m <<= 1) {
    sx += __shfl_xor(sx, m); sy += __shfl_xor(sy, m);
    sz += __shfl_xor(sz, m); sw += __shfl_xor(sw, m);
    qx += __shfl_xor(qx, m); qy += __shfl_xor(qy, m);
    qz += __shfl_xor(qz, m); qw += __shfl_xor(qw, m);
  }
  if ((t & 63) < 8) {
    int c = b * 32 + g * 4;
    atomicAdd(&psum[c + 0], sx); atomicAdd(&psum[c + 1], sy);
    atomicAdd(&psum[c + 2], sz); atomicAdd(&psum[c + 3], sw);
    atomicAdd(&psq[c + 0], qx); atomicAdd(&psq[c + 1], qy);
    atomicAdd(&psq[c + 2], qz); atomicAdd(&psq[c + 3], qw);
  }
}

// ---------------- AdaGN affine coefficients (stage 1) ----------------
__global__ void k_coef1(const float* __restrict__ psum, const float* __restrict__ psq,
                        const float* __restrict__ mod, const float* __restrict__ g,
                        const float* __restrict__ bgn, float* __restrict__ A,
                        float* __restrict__ Bc) {
  int t = threadIdx.x;  // 256 = B*C
  int b = t >> 5, c = t & 31, grp = c >> 2;
  float s = 0, q = 0;
  for (int j = 0; j < 4; ++j) {
    s += psum[b * 32 + grp * 4 + j];
    q += psq[b * 32 + grp * 4 + j];
  }
  const float cntf = 4.0f * (float)Vn;
  float mean = s / cntf;
  float var = q / cntf - mean * mean;
  float rstd = rsqrtf(var + 1e-5f);
  float scale = mod[b * 64 + c], shift = mod[b * 64 + 32 + c];
  A[t] = rstd * g[c] * scale;
  Bc[t] = (bgn[c] - mean * rstd * g[c]) * scale + shift;
}

// ---------------- AdaGN stage 2 + SE -> final gather affine S,T ----------------
__global__ void k_coef2(const float* __restrict__ psum, const float* __restrict__ psq,
                        const float* __restrict__ mod, const float* __restrict__ g,
                        const float* __restrict__ bgn, const float* __restrict__ sw1,
                        const float* __restrict__ sw2, float* __restrict__ S,
                        float* __restrict__ T) {
  __shared__ float zm[8][32];
  __shared__ float hh[8][4];
  int t = threadIdx.x;  // 256 = B*C
  int b = t >> 5, c = t & 31, grp = c >> 2;
  float s = 0, q = 0;
  for (int j = 0; j < 4; ++j) {
    s += psum[b * 32 + grp * 4 + j];
    q += psq[b * 32 + grp * 4 + j];
  }
  const float cntf = 4.0f * (float)Vn;
  float mean = s / cntf;
  float var = q / cntf - mean * mean;
  float rstd = rsqrtf(var + 1e-5f);
  float scale = mod[b * 64 + c], shift = mod[b * 64 + 32 + c];
  float A = rstd * g[c] * scale;
  float Bv = (bgn[c] - mean * rstd * g[c]) * scale + shift;
  float chmean = psum[b * 32 + c] / (float)Vn;
  zm[b][c] = A * chmean + Bv;
  __syncthreads();
  if (t < 32) {
    int b2 = t >> 2, j = t & 3;
    float h = 0;
    for (int cc = 0; cc < 32; ++cc) h += sw1[j * 32 + cc] * zm[b2][cc];
    hh[b2][j] = fmaxf(h, 0.f);
  }
  __syncthreads();
  float sig = 0;
  for (int j = 0; j < 4; ++j) sig += sw2[c * 4 + j] * hh[b][j];
  sig = 1.0f / (1.0f + expf(-sig));
  S[t] = A * sig;
  T[t] = Bv * sig;
}

// ---------------- trilinear devoxelize with fused affine (adagn2*SE) ----------------
__global__ void k_devox(const float* __restrict__ vox, const float* __restrict__ nc,
                        const float* __restrict__ S, const float* __restrict__ T,
                        float* __restrict__ out) {
  int i = blockIdx.x * 256 + threadIdx.x;  // B*N
  int b = i >> 14, n = i & (Nn - 1);
  const float* ncb = nc + (size_t)b * 3 * Nn;
  float fx = ncb[n], fy = ncb[Nn + n], fz = ncb[2 * Nn + n];
  float lxf = floorf(fx), lyf = floorf(fy), lzf = floorf(fz);
  float wx1 = fx - lxf, wy1 = fy - lyf, wz1 = fz - lzf;
  int lx = (int)lxf, ly = (int)lyf, lz = (int)lzf;
  int hx = min(lx + 1, 31), hy = min(ly + 1, 31), hz = min(lz + 1, 31);
  float4 acc[8];
  #pragma unroll
  for (int q = 0; q < 8; ++q) acc[q] = make_float4(0.f, 0.f, 0.f, 0.f);
  #pragma unroll
  for (int corner = 0; corner < 8; ++corner) {
    int cx = (corner & 4) ? hx : lx;
    int cy = (corner & 2) ? hy : ly;
    int cz = (corner & 1) ? hz : lz;
    float ww = ((corner & 4) ? wx1 : 1.f - wx1) *
               ((corner & 2) ? wy1 : 1.f - wy1) *
               ((corner & 1) ? wz1 : 1.f - wz1);
    const float4* p = reinterpret_cast<const float4*>(
        vox + ((size_t)b * Vn + (size_t)((cx * 32 + cy) * 32 + cz)) * 32);
    #pragma unroll
    for (int q = 0; q < 8; ++q) {
      float4 v = p[q];
      acc[q].x += ww * v.x; acc[q].y += ww * v.y;
      acc[q].z += ww * v.z; acc[q].w += ww * v.w;
    }
  }
  const float4* S4 = reinterpret_cast<const float4*>(S + b * 32);
  const float4* T4 = reinterpret_cast<const float4*>(T + b * 32);
  float* o = out + (size_t)b * 32 * Nn + n;
  #pragma unroll
  for (int q = 0; q < 8; ++q) {
    float4 sv = S4[q], tv = T4[q], a = acc[q];
    o[(size_t)(q * 4 + 0) * Nn] = a.x * sv.x + tv.x;
    o[(size_t)(q * 4 + 1) * Nn] = a.y * sv.y + tv.y;
    o[(size_t)(q * 4 + 2) * Nn] = a.z * sv.z + tv.z;
    o[(size_t)(q * 4 + 3) * Nn] = a.w * sv.w + tv.w;
  }
}

// ---------------- point branch: 1x1 conv (32x32 GEMM per point) ----------------
__global__ void k_pxlin(const float* __restrict__ feat, const float* __restrict__ w,
                        const float* __restrict__ bias, float* __restrict__ px) {
  __shared__ float lw[1024];
  __shared__ float lb[32];
  int t = threadIdx.x;
  for (int i = t; i < 1024; i += 256) lw[i] = w[i];
  if (t < 32) lb[t] = bias[t];
  __syncthreads();
  int blk = blockIdx.x;  // B*64
  int b = blk >> 6, tile = blk & 63;
  int n = tile * 256 + t;
  float fr[32];
  const float* fb = feat + (size_t)b * 32 * Nn + n;
  #pragma unroll
  for (int ci = 0; ci < 32; ++ci) fr[ci] = fb[(size_t)ci * Nn];
  float* ob = px + (size_t)b * 32 * Nn + n;
  for (int co = 0; co < 32; ++co) {
    float acc = lb[co];
    #pragma unroll
    for (int ci = 0; ci < 32; ++ci) acc += lw[co * 32 + ci] * fr[ci];
    ob[(size_t)co * Nn] = acc;
  }
}

// ---------------- point-branch group stats (channel-first) ----------------
__global__ void k_statsp(const float* __restrict__ px, float* __restrict__ mean_out,
                         float* __restrict__ rstd_out) {
  int blk = blockIdx.x;  // 64 = B*G
  int b = blk >> 3, g = blk & 7;
  const float4* base = reinterpret_cast<const float4*>(
      px + (size_t)b * 32 * Nn + (size_t)g * 4 * Nn);
  float s = 0, q = 0;
  int t = threadIdx.x;
  for (int i = t; i < 16384; i += 256) {
    float4 v = base[i];
    s += v.x + v.y + v.z + v.w;
    q += v.x * v.x + v.y * v.y + v.z * v.z + v.w * v.w;
  }
  __shared__ float rs[256], rq[256];
  rs[t] = s; rq[t] = q; __syncthreads();
  for (int st = 128; st > 0; st >>= 1) {
    if (t < st) { rs[t] += rs[t + st]; rq[t] += rq[t + st]; }
    __syncthreads();
  }
  if (t == 0) {
    float mean = rs[0] / 65536.f;
    float var = rq[0] / 65536.f - mean * mean;
    mean_out[blk] = mean;
    rstd_out[blk] = rsqrtf(var + 1e-5f);
  }
}

// ---------------- point-branch affine coefficients ----------------
__global__ void k_coefp(const float* __restrict__ mean, const float* __restrict__ rstd,
                        const float* __restrict__ mod, const float* __restrict__ g,
                        const float* __restrict__ bgn, float* __restrict__ A,
                        float* __restrict__ Bc) {
  int t = threadIdx.x;  // 256
  int b = t >> 5, c = t & 31, grp = c >> 2;
  float m = mean[b * 8 + grp], r = rstd[b * 8 + grp];
  float scale = mod[b * 64 + c], shift = mod[b * 64 + 32 + c];
  A[t] = r * g[c] * scale;
  Bc[t] = (bgn[c] - m * r * g[c]) * scale + shift;
}

// ---------------- final: out += silu(px*A+B) ----------------
__global__ void k_final(const float* __restrict__ px, const float* __restrict__ A,
                        const float* __restrict__ Bc, float* __restrict__ out) {
  int i = blockIdx.x * 256 + threadIdx.x;  // B*C*N
  int bc = i >> 14;
  float y = px[i] * A[bc] + Bc[bc];
  out[i] += y / (1.0f + expf(-y));
}

}  // namespace

extern "C" void kernel_launch(void* const* d_in, const int* in_sizes, int n_in,
                              void* d_out, int out_size, void* d_ws, size_t ws_size,
                              hipStream_t stream) {
  (void)in_sizes; (void)n_in; (void)out_size; (void)ws_size;
  const float* features = (const float*)d_in[0];
  const float* coords = (const float*)d_in[1];
  const float* condition = (const float*)d_in[2];
  const float* conv1_w = (const float*)d_in[3];
  const float* conv1_b = (const float*)d_in[4];
  const float* gn1_g = (const float*)d_in[5];
  const float* gn1_b = (const float*)d_in[6];
  const float* mod1_w = (const float*)d_in[7];
  const float* mod1_b = (const float*)d_in[8];
  const float* conv2_w = (const float*)d_in[9];
  const float* conv2_b = (const float*)d_in[10];
  const float* gn2_g = (const float*)d_in[11];
  const float* gn2_b = (const float*)d_in[12];
  const float* mod2_w = (const float*)d_in[13];
  const float* mod2_b = (const float*)d_in[14];
  const float* se_w1 = (const float*)d_in[15];
  const float* se_w2 = (const float*)d_in[16];
  const float* pc_w = (const float*)d_in[17];
  const float* pc_b = (const float*)d_in[18];
  const float* gnp_g = (const float*)d_in[19];
  const float* gnp_b = (const float*)d_in[20];
  const float* modp_w = (const float*)d_in[21];
  const float* modp_b = (const float*)d_in[22];

  char* w = (char*)d_ws;
  float* bufA = (float*)w; w += (size_t)Bn * Vn * Cn * 4;      // 33.5 MB
  float* bufB = (float*)w; w += (size_t)Bn * Vn * Cn * 4;      // 33.5 MB
  float* cnt = (float*)w;  w += (size_t)Bn * Vn * 4;           // 1 MB
  float* psum1 = (float*)w; w += 256 * 4;
  float* psq1 = (float*)w;  w += 256 * 4;
  float* psum2 = (float*)w; w += 256 * 4;
  float* psq2 = (float*)w;  w += 256 * 4;
  float* ncb = (float*)w;  w += (size_t)Bn * 3 * Nn * 4;
  int* vidx = (int*)w;     w += (size_t)Bn * Nn * 4;
  float* wt1 = (float*)w;  w += 27648 * 4;
  float* wt2 = (float*)w;  w += 27648 * 4;
  float* m1 = (float*)w;   w += 512 * 4;
  float* m2 = (float*)w;   w += 512 * 4;
  float* mp = (float*)w;   w += 512 * 4;
  float* A1 = (float*)w;   w += 256 * 4;
  float* B1 = (float*)w;   w += 256 * 4;
  float* Sc = (float*)w;   w += 256 * 4;
  float* Tc = (float*)w;   w += 256 * 4;
  float* Ap = (float*)w;   w += 256 * 4;
  float* Bp = (float*)w;   w += 256 * 4;
  float* pmean = (float*)w; w += 64 * 4;
  float* prstd = (float*)w; w += 64 * 4;
  float* out = (float*)d_out;

  // zero the scatter accumulators (bufA) and cnt+psums (contiguous block)
  hipMemsetAsync(bufA, 0, (size_t)Bn * Vn * Cn * 4, stream);
  hipMemsetAsync(cnt, 0, (size_t)Bn * Vn * 4 + 4 * 256 * 4, stream);

  k_coords<<<Bn, 256, 0, stream>>>(coords, ncb, vidx);
  k_twz<<<108, 256, 0, stream>>>(conv1_w, wt1);
  k_twz<<<108, 256, 0, stream>>>(conv2_w, wt2);
  k_mods<<<1, 256, 0, stream>>>(condition, mod1_w, mod1_b, mod2_w, mod2_b,
                                modp_w, modp_b, m1, m2, mp);
  k_scatter<<<(Bn * Nn) / 256, 256, 0, stream>>>(features, vidx, bufA, cnt);
  k_normvox<<<(Bn * Vn * 8) / 256, 256, 0, stream>>>(bufA, cnt, (float4*)bufB);
  k_conv<false><<<Bn * 32 * 32, 256, 0, stream>>>(bufB, wt1, conv1_b, nullptr,
                                                  nullptr, bufA);
  k_stats_cl<<<Bn * 128, 256, 0, stream>>>(bufA, psum1, psq1);
  k_coef1<<<1, 256, 0, stream>>>(psum1, psq1, m1, gn1_g, gn1_b, A1, B1);
  k_conv<true><<<Bn * 32 * 32, 256, 0, stream>>>(bufA, wt2, conv2_b, A1, B1, bufB);
  k_stats_cl<<<Bn * 128, 256, 0, stream>>>(bufB, psum2, psq2);
  k_coef2<<<1, 256, 0, stream>>>(psum2, psq2, m2, gn2_g, gn2_b, se_w1, se_w2, Sc, Tc);
  k_devox<<<(Bn * Nn) / 256, 256, 0, stream>>>(bufB, ncb, Sc, Tc, out);
  k_pxlin<<<Bn * 64, 256, 0, stream>>>(features, pc_w, pc_b, bufA);
  k_statsp<<<64, 256, 0, stream>>>(bufA, pmean, prstd);
  k_coefp<<<1, 256, 0, stream>>>(pmean, prstd, mp, gnp_g, gnp_b, Ap, Bp);
  k_final<<<(Bn * Cn * Nn) / 256, 256, 0, stream>>>(bufA, Ap, Bp, out);
}

// Round 2
// 779.011 us; speedup vs baseline: 11.8672x; 11.8672x over previous
//
#include <hip/hip_runtime.h>
#include <math.h>

#define DEV_INLINE __device__ __forceinline__

namespace {

typedef unsigned short u16;
typedef unsigned int u32;
typedef __attribute__((ext_vector_type(8))) short short8v;
typedef __attribute__((ext_vector_type(4))) float f32x4;

constexpr int Bn = 8, Cn = 32, Nn = 16384, Rn = 32, Vn = Rn * Rn * Rn;

DEV_INLINE float siluf(float x) { return x / (1.0f + expf(-x)); }
DEV_INLINE float bf2f(u16 u) { union { u32 i; float f; } x; x.i = (u32)u << 16; return x.f; }
DEV_INLINE u16 f2bf(float f) {
  union { float f; u32 i; } x; x.f = f;
  return (u16)((x.i + 0x7FFFu + ((x.i >> 16) & 1u)) >> 16);
}
DEV_INLINE u32 pack2(float a, float b) { return (u32)f2bf(a) | ((u32)f2bf(b) << 16); }
DEV_INLINE void unpack8(uint4 u, float* f) {
  f[0] = bf2f(u.x & 0xffff); f[1] = bf2f(u.x >> 16);
  f[2] = bf2f(u.y & 0xffff); f[3] = bf2f(u.y >> 16);
  f[4] = bf2f(u.z & 0xffff); f[5] = bf2f(u.z >> 16);
  f[6] = bf2f(u.w & 0xffff); f[7] = bf2f(u.w >> 16);
}

// ---------------- coords: per-batch mean, max-norm, nc, voxel idx ----------------
__global__ void k_coords(const float* __restrict__ coords,
                         float* __restrict__ nc, int* __restrict__ vidx) {
  int b = blockIdx.x;
  int t = threadIdx.x;  // 256
  __shared__ float red[256];
  __shared__ float mean_s[3];
  __shared__ float denom_s;
  const float* cb = coords + (size_t)b * 3 * Nn;

  float sx = 0.f, sy = 0.f, sz = 0.f;
  for (int n = t; n < Nn; n += 256) {
    sx += cb[n]; sy += cb[Nn + n]; sz += cb[2 * Nn + n];
  }
  float vals[3] = {sx, sy, sz};
  for (int a = 0; a < 3; ++a) {
    red[t] = vals[a]; __syncthreads();
    for (int s = 128; s > 0; s >>= 1) {
      if (t < s) red[t] += red[t + s];
      __syncthreads();
    }
    if (t == 0) mean_s[a] = red[0] / (float)Nn;
    __syncthreads();
  }
  float mx = mean_s[0], my = mean_s[1], mz = mean_s[2];

  float mq = 0.f;
  for (int n = t; n < Nn; n += 256) {
    float x = cb[n] - mx, y = cb[Nn + n] - my, z = cb[2 * Nn + n] - mz;
    mq = fmaxf(mq, x * x + y * y + z * z);
  }
  red[t] = mq; __syncthreads();
  for (int s = 128; s > 0; s >>= 1) {
    if (t < s) red[t] = fmaxf(red[t], red[t + s]);
    __syncthreads();
  }
  if (t == 0) denom_s = 2.0f * sqrtf(red[0]);
  __syncthreads();
  float inv = 1.0f / denom_s;

  float* ncb = nc + (size_t)b * 3 * Nn;
  int* ib = vidx + (size_t)b * Nn;
  for (int n = t; n < Nn; n += 256) {
    float x = (cb[n] - mx) * inv + 0.5f;
    float y = (cb[Nn + n] - my) * inv + 0.5f;
    float z = (cb[2 * Nn + n] - mz) * inv + 0.5f;
    x = fminf(fmaxf(x * (float)Rn, 0.f), (float)(Rn - 1));
    y = fminf(fmaxf(y * (float)Rn, 0.f), (float)(Rn - 1));
    z = fminf(fmaxf(z * (float)Rn, 0.f), (float)(Rn - 1));
    ncb[n] = x; ncb[Nn + n] = y; ncb[2 * Nn + n] = z;
    int vx = (int)rintf(x), vy = (int)rintf(y), vz = (int)rintf(z);
    ib[n] = (vx * Rn + vy) * Rn + vz;
  }
}

// ---------------- weight transpose: w[co][ci][k] -> wt_bf16[k][co][ci] ----------------
__global__ void k_twz(const float* __restrict__ w, u16* __restrict__ wt) {
  int i = blockIdx.x * 256 + threadIdx.x;
  if (i >= 27 * 32 * 32) return;
  int ci = i & 31, co = (i >> 5) & 31, k = i >> 10;
  wt[i] = f2bf(w[(co * 32 + ci) * 27 + k]);
}

// ---------------- modulation vectors m = silu(cond) @ mw.T + mb ----------------
__global__ void k_mods(const float* __restrict__ cond,
                       const float* __restrict__ w1, const float* __restrict__ b1,
                       const float* __restrict__ w2, const float* __restrict__ b2,
                       const float* __restrict__ wp, const float* __restrict__ bp,
                       float* __restrict__ m1, float* __restrict__ m2,
                       float* __restrict__ mp) {
  __shared__ float sc[2048];
  int t = threadIdx.x;
  for (int i = t; i < 2048; i += 256) sc[i] = siluf(cond[i]);
  __syncthreads();
  for (int o = t; o < 1536; o += 256) {
    int mat = o / 512, rem = o - mat * 512;
    int b = rem >> 6, oo = rem & 63;
    const float* w = (mat == 0) ? w1 : ((mat == 1) ? w2 : wp);
    const float* bb = (mat == 0) ? b1 : ((mat == 1) ? b2 : bp);
    float acc = bb[oo];
    const float* wrow = w + oo * 256;
    const float* scb = sc + b * 256;
    for (int k = 0; k < 256; ++k) acc += wrow[k] * scb[k];
    float* dst = (mat == 0) ? m1 : ((mat == 1) ? m2 : mp);
    dst[b * 64 + oo] = acc;
  }
}

// ---------------- scatter-add features into voxel grid (f32 sums) ----------------
__global__ void k_scatter(const float* __restrict__ feat, const int* __restrict__ vidx,
                          float* __restrict__ sums, float* __restrict__ cnt) {
  int i = blockIdx.x * 256 + threadIdx.x;  // over B*N
  int b = i >> 14, n = i & (Nn - 1);
  int v = vidx[i];
  float* dst = sums + (size_t)(b * Vn + v) * Cn;
  const float* f = feat + (size_t)b * Cn * Nn + n;
  #pragma unroll
  for (int c = 0; c < Cn; ++c) atomicAdd(dst + c, f[(size_t)c * Nn]);
  atomicAdd(cnt + b * Vn + v, 1.0f);
}

// ---------------- divide sums by counts, convert to bf16 ----------------
__global__ void k_normvox(const float* __restrict__ sums, const float* __restrict__ cnt,
                          uint4* __restrict__ outv) {
  int i = blockIdx.x * 256 + threadIdx.x;  // over B*V*4 uint4 chunks
  int bv = i >> 2;
  float invc = 1.0f / fmaxf(cnt[bv], 1.0f);
  float4 v0 = reinterpret_cast<const float4*>(sums)[i * 2];
  float4 v1 = reinterpret_cast<const float4*>(sums)[i * 2 + 1];
  uint4 o;
  o.x = pack2(v0.x * invc, v0.y * invc);
  o.y = pack2(v0.z * invc, v0.w * invc);
  o.z = pack2(v1.x * invc, v1.y * invc);
  o.w = pack2(v1.z * invc, v1.w * invc);
  outv[i] = o;
}

// ---------------- 3x3x3 conv as implicit GEMM on bf16 MFMA ----------------
// Block = (b, x, y-pair). 512 threads = 8 waves: (yy, z-tile, co-tile).
// LDS: full weights [27][co32][ci32] bf16 (54 KB) + input halo [3dx][4y][34z][32ci]
// bf16 (25.5 KB). Per tap per wave: A-frag = W[co-tile rows][ci], B-frag =
// X[z rows][ci], both contiguous-1KB LDS reads; D[co][z] (m91-verified layout).
template <bool AFF>
__global__ __launch_bounds__(512, 4) void k_conv(
    const u16* __restrict__ in, const u16* __restrict__ wt,
    const float* __restrict__ bias, const float* __restrict__ Ac,
    const float* __restrict__ Bc, u16* __restrict__ out) {
  __shared__ uint4 lds_w4[3456];   // 55296 B
  __shared__ uint4 lds_x4[1632];   // 26112 B
  int t = threadIdx.x;
  int blk = blockIdx.x;
  int yp = blk & 15, x = (blk >> 4) & 31, b = blk >> 9;
  int y0 = yp * 2;
  size_t bbase = (size_t)b * Vn;

  const uint4* gw = reinterpret_cast<const uint4*>(wt);
  for (int i = t; i < 3456; i += 512) lds_w4[i] = gw[i];

  for (int i = t; i < 1632; i += 512) {
    int rowid = i >> 2, c4 = i & 3;
    int col = rowid / 34, r = rowid - col * 34;
    int dxp = col >> 2, yy = col & 3;
    int gx = x + dxp - 1, gy = y0 + yy - 1, z = r - 1;
    uint4 val = make_uint4(0u, 0u, 0u, 0u);
    if (gx >= 0 && gx < 32 && gy >= 0 && gy < 32 && z >= 0 && z < 32) {
      val = *reinterpret_cast<const uint4*>(
          in + (bbase + (size_t)((gx * 32 + gy) * 32 + z)) * 32 + c4 * 8);
      if (AFF) {
        float f[8];
        unpack8(val, f);
        float4 A0 = reinterpret_cast<const float4*>(Ac)[b * 8 + c4 * 2];
        float4 A1 = reinterpret_cast<const float4*>(Ac)[b * 8 + c4 * 2 + 1];
        float4 B0 = reinterpret_cast<const float4*>(Bc)[b * 8 + c4 * 2];
        float4 B1 = reinterpret_cast<const float4*>(Bc)[b * 8 + c4 * 2 + 1];
        f[0] = siluf(f[0] * A0.x + B0.x); f[1] = siluf(f[1] * A0.y + B0.y);
        f[2] = siluf(f[2] * A0.z + B0.z); f[3] = siluf(f[3] * A0.w + B0.w);
        f[4] = siluf(f[4] * A1.x + B1.x); f[5] = siluf(f[5] * A1.y + B1.y);
        f[6] = siluf(f[6] * A1.z + B1.z); f[7] = siluf(f[7] * A1.w + B1.w);
        val.x = pack2(f[0], f[1]); val.y = pack2(f[2], f[3]);
        val.z = pack2(f[4], f[5]); val.w = pack2(f[6], f[7]);
      }
    }
    lds_x4[i] = val;  // layout [col][r][c4] == linear i
  }
  __syncthreads();

  int w = t >> 6, lane = t & 63, lr = lane & 15, lh = lane >> 4;
  int yy_out = w & 1, mt = (w >> 1) & 1, nt = (w >> 2) & 1;
  int y = y0 + yy_out;
  int co0 = nt * 16 + lh * 4;

  f32x4 acc;
  acc[0] = bias[co0]; acc[1] = bias[co0 + 1];
  acc[2] = bias[co0 + 2]; acc[3] = bias[co0 + 3];

  const u16* lw = reinterpret_cast<const u16*>(lds_w4);
  const u16* lx = reinterpret_cast<const u16*>(lds_x4);

  #pragma unroll
  for (int dxp = 0; dxp < 3; ++dxp) {
    #pragma unroll
    for (int dyp = 0; dyp < 3; ++dyp) {
      int col = dxp * 4 + yy_out + dyp;
      #pragma unroll
      for (int dzp = 0; dzp < 3; ++dzp) {
        int k = (dxp * 3 + dyp) * 3 + dzp;
        short8v a = *reinterpret_cast<const short8v*>(
            lw + ((k * 32 + nt * 16 + lr) * 32 + lh * 8));
        short8v bb = *reinterpret_cast<const short8v*>(
            lx + ((col * 34 + mt * 16 + lr + dzp) * 32 + lh * 8));
        acc = __builtin_amdgcn_mfma_f32_16x16x32_bf16(a, bb, acc, 0, 0, 0);
      }
    }
  }

  int z = mt * 16 + lr;
  size_t off = (bbase + (size_t)((x * 32 + y) * 32 + z)) * 32 + co0;
  uint2 o;
  o.x = pack2(acc[0], acc[1]);
  o.y = pack2(acc[2], acc[3]);
  *reinterpret_cast<uint2*>(out + off) = o;
}

// ---------------- per-channel sum/sumsq on channel-last bf16 (B,V,C) ----------------
__global__ void k_stats_cl(const u16* __restrict__ x, float* __restrict__ psum,
                           float* __restrict__ psq) {
  int blk = blockIdx.x;  // B*128
  int b = blk >> 7, chunk = blk & 127;
  int t = threadIdx.x;
  int c8 = t & 3, vsub = t >> 2;
  float s[8], q[8];
  #pragma unroll
  for (int j = 0; j < 8; ++j) { s[j] = 0.f; q[j] = 0.f; }
  const uint4* xb = reinterpret_cast<const uint4*>(x + (size_t)b * Vn * Cn);
  for (int it = 0; it < 4; ++it) {
    int v = chunk * 256 + it * 64 + vsub;
    uint4 u = xb[v * 4 + c8];
    float f[8];
    unpack8(u, f);
    #pragma unroll
    for (int j = 0; j < 8; ++j) { s[j] += f[j]; q[j] += f[j] * f[j]; }
  }
  #pragma unroll
  for (int m = 4; m <= 32; m <<= 1) {
    #pragma unroll
    for (int j = 0; j < 8; ++j) {
      s[j] += __shfl_xor(s[j], m);
      q[j] += __shfl_xor(q[j], m);
    }
  }
  if ((t & 63) < 4) {
    int base = b * 32 + c8 * 8;
    #pragma unroll
    for (int j = 0; j < 8; ++j) {
      atomicAdd(&psum[base + j], s[j]);
      atomicAdd(&psq[base + j], q[j]);
    }
  }
}

// ---------------- AdaGN affine coefficients (stage 1) ----------------
__global__ void k_coef1(const float* __restrict__ psum, const float* __restrict__ psq,
                        const float* __restrict__ mod, const float* __restrict__ g,
                        const float* __restrict__ bgn, float* __restrict__ A,
                        float* __restrict__ Bc) {
  int t = threadIdx.x;  // 256 = B*C
  int b = t >> 5, c = t & 31, grp = c >> 2;
  float s = 0, q = 0;
  for (int j = 0; j < 4; ++j) {
    s += psum[b * 32 + grp * 4 + j];
    q += psq[b * 32 + grp * 4 + j];
  }
  const float cntf = 4.0f * (float)Vn;
  float mean = s / cntf;
  float var = q / cntf - mean * mean;
  float rstd = rsqrtf(var + 1e-5f);
  float scale = mod[b * 64 + c], shift = mod[b * 64 + 32 + c];
  A[t] = rstd * g[c] * scale;
  Bc[t] = (bgn[c] - mean * rstd * g[c]) * scale + shift;
}

// ---------------- AdaGN stage 2 + SE -> final gather affine S,T ----------------
__global__ void k_coef2(const float* __restrict__ psum, const float* __restrict__ psq,
                        const float* __restrict__ mod, const float* __restrict__ g,
                        const float* __restrict__ bgn, const float* __restrict__ sw1,
                        const float* __restrict__ sw2, float* __restrict__ S,
                        float* __restrict__ T) {
  __shared__ float zm[8][32];
  __shared__ float hh[8][4];
  int t = threadIdx.x;  // 256 = B*C
  int b = t >> 5, c = t & 31, grp = c >> 2;
  float s = 0, q = 0;
  for (int j = 0; j < 4; ++j) {
    s += psum[b * 32 + grp * 4 + j];
    q += psq[b * 32 + grp * 4 + j];
  }
  const float cntf = 4.0f * (float)Vn;
  float mean = s / cntf;
  float var = q / cntf - mean * mean;
  float rstd = rsqrtf(var + 1e-5f);
  float scale = mod[b * 64 + c], shift = mod[b * 64 + 32 + c];
  float A = rstd * g[c] * scale;
  float Bv = (bgn[c] - mean * rstd * g[c]) * scale + shift;
  float chmean = psum[b * 32 + c] / (float)Vn;
  zm[b][c] = A * chmean + Bv;
  __syncthreads();
  if (t < 32) {
    int b2 = t >> 2, j = t & 3;
    float h = 0;
    for (int cc = 0; cc < 32; ++cc) h += sw1[j * 32 + cc] * zm[b2][cc];
    hh[b2][j] = fmaxf(h, 0.f);
  }
  __syncthreads();
  float sig = 0;
  for (int j = 0; j < 4; ++j) sig += sw2[c * 4 + j] * hh[b][j];
  sig = 1.0f / (1.0f + expf(-sig));
  S[t] = A * sig;
  T[t] = Bv * sig;
}

// ---------------- trilinear devoxelize (bf16 vox) with fused affine ----------------
__global__ void k_devox(const u16* __restrict__ vox, const float* __restrict__ nc,
                        const float* __restrict__ S, const float* __restrict__ T,
                        float* __restrict__ out) {
  int i = blockIdx.x * 256 + threadIdx.x;  // B*N
  int b = i >> 14, n = i & (Nn - 1);
  const float* ncb = nc + (size_t)b * 3 * Nn;
  float fx = ncb[n], fy = ncb[Nn + n], fz = ncb[2 * Nn + n];
  float lxf = floorf(fx), lyf = floorf(fy), lzf = floorf(fz);
  float wx1 = fx - lxf, wy1 = fy - lyf, wz1 = fz - lzf;
  int lx = (int)lxf, ly = (int)lyf, lz = (int)lzf;
  int hx = min(lx + 1, 31), hy = min(ly + 1, 31), hz = min(lz + 1, 31);
  float a[32];
  #pragma unroll
  for (int c = 0; c < 32; ++c) a[c] = 0.f;
  for (int corner = 0; corner < 8; ++corner) {
    int cx = (corner & 4) ? hx : lx;
    int cy = (corner & 2) ? hy : ly;
    int cz = (corner & 1) ? hz : lz;
    float ww = ((corner & 4) ? wx1 : 1.f - wx1) *
               ((corner & 2) ? wy1 : 1.f - wy1) *
               ((corner & 1) ? wz1 : 1.f - wz1);
    const uint4* p = reinterpret_cast<const uint4*>(
        vox + ((size_t)b * Vn + (size_t)((cx * 32 + cy) * 32 + cz)) * 32);
    #pragma unroll
    for (int qq = 0; qq < 4; ++qq) {
      float f[8];
      unpack8(p[qq], f);
      #pragma unroll
      for (int j = 0; j < 8; ++j) a[qq * 8 + j] += ww * f[j];
    }
  }
  float* o = out + (size_t)b * 32 * Nn + n;
  #pragma unroll
  for (int c = 0; c < 32; ++c) {
    o[(size_t)c * Nn] = a[c] * S[b * 32 + c] + T[b * 32 + c];
  }
}

// ---------------- point branch: 1x1 conv (32x32 GEMM per point) ----------------
__global__ void k_pxlin(const float* __restrict__ feat, const float* __restrict__ w,
                        const float* __restrict__ bias, float* __restrict__ px) {
  __shared__ float lw[1024];
  __shared__ float lb[32];
  int t = threadIdx.x;
  for (int i = t; i < 1024; i += 256) lw[i] = w[i];
  if (t < 32) lb[t] = bias[t];
  __syncthreads();
  int blk = blockIdx.x;  // B*64
  int b = blk >> 6, tile = blk & 63;
  int n = tile * 256 + t;
  float fr[32];
  const float* fb = feat + (size_t)b * 32 * Nn + n;
  #pragma unroll
  for (int ci = 0; ci < 32; ++ci) fr[ci] = fb[(size_t)ci * Nn];
  float* ob = px + (size_t)b * 32 * Nn + n;
  for (int co = 0; co < 32; ++co) {
    float acc = lb[co];
    #pragma unroll
    for (int ci = 0; ci < 32; ++ci) acc += lw[co * 32 + ci] * fr[ci];
    ob[(size_t)co * Nn] = acc;
  }
}

// ---------------- point-branch group stats (channel-first) ----------------
__global__ void k_statsp(const float* __restrict__ px, float* __restrict__ mean_out,
                         float* __restrict__ rstd_out) {
  int blk = blockIdx.x;  // 64 = B*G
  int b = blk >> 3, g = blk & 7;
  const float4* base = reinterpret_cast<const float4*>(
      px + (size_t)b * 32 * Nn + (size_t)g * 4 * Nn);
  float s = 0, q = 0;
  int t = threadIdx.x;
  for (int i = t; i < 16384; i += 256) {
    float4 v = base[i];
    s += v.x + v.y + v.z + v.w;
    q += v.x * v.x + v.y * v.y + v.z * v.z + v.w * v.w;
  }
  __shared__ float rs[256], rq[256];
  rs[t] = s; rq[t] = q; __syncthreads();
  for (int st = 128; st > 0; st >>= 1) {
    if (t < st) { rs[t] += rs[t + st]; rq[t] += rq[t + st]; }
    __syncthreads();
  }
  if (t == 0) {
    float mean = rs[0] / 65536.f;
    float var = rq[0] / 65536.f - mean * mean;
    mean_out[blk] = mean;
    rstd_out[blk] = rsqrtf(var + 1e-5f);
  }
}

// ---------------- point-branch affine coefficients ----------------
__global__ void k_coefp(const float* __restrict__ mean, const float* __restrict__ rstd,
                        const float* __restrict__ mod, const float* __restrict__ g,
                        const float* __restrict__ bgn, float* __restrict__ A,
                        float* __restrict__ Bc) {
  int t = threadIdx.x;  // 256
  int b = t >> 5, c = t & 31, grp = c >> 2;
  float m = mean[b * 8 + grp], r = rstd[b * 8 + grp];
  float scale = mod[b * 64 + c], shift = mod[b * 64 + 32 + c];
  A[t] = r * g[c] * scale;
  Bc[t] = (bgn[c] - m * r * g[c]) * scale + shift;
}

// ---------------- final: out += silu(px*A+B) ----------------
__global__ void k_final(const float* __restrict__ px, const float* __restrict__ A,
                        const float* __restrict__ Bc, float* __restrict__ out) {
  int i = blockIdx.x * 256 + threadIdx.x;  // B*C*N
  int bc = i >> 14;
  float y = px[i] * A[bc] + Bc[bc];
  out[i] += y / (1.0f + expf(-y));
}

}  // namespace

extern "C" void kernel_launch(void* const* d_in, const int* in_sizes, int n_in,
                              void* d_out, int out_size, void* d_ws, size_t ws_size,
                              hipStream_t stream) {
  (void)in_sizes; (void)n_in; (void)out_size; (void)ws_size;
  const float* features = (const float*)d_in[0];
  const float* coords = (const float*)d_in[1];
  const float* condition = (const float*)d_in[2];
  const float* conv1_w = (const float*)d_in[3];
  const float* conv1_b = (const float*)d_in[4];
  const float* gn1_g = (const float*)d_in[5];
  const float* gn1_b = (const float*)d_in[6];
  const float* mod1_w = (const float*)d_in[7];
  const float* mod1_b = (const float*)d_in[8];
  const float* conv2_w = (const float*)d_in[9];
  const float* conv2_b = (const float*)d_in[10];
  const float* gn2_g = (const float*)d_in[11];
  const float* gn2_b = (const float*)d_in[12];
  const float* mod2_w = (const float*)d_in[13];
  const float* mod2_b = (const float*)d_in[14];
  const float* se_w1 = (const float*)d_in[15];
  const float* se_w2 = (const float*)d_in[16];
  const float* pc_w = (const float*)d_in[17];
  const float* pc_b = (const float*)d_in[18];
  const float* gnp_g = (const float*)d_in[19];
  const float* gnp_b = (const float*)d_in[20];
  const float* modp_w = (const float*)d_in[21];
  const float* modp_b = (const float*)d_in[22];

  char* w = (char*)d_ws;
  // region0 (33.5 MB): scatter sums f32, later vox1+vox2 bf16
  float* sums = (float*)w;
  u16* vox1 = (u16*)w;
  u16* vox2 = (u16*)(w + 16777216);
  w += 33554432;
  // region1 (16.8 MB): vox0 bf16, later px f32
  u16* vox0 = (u16*)w;
  float* px = (float*)w;
  w += 16777216;
  float* cnt = (float*)w;   w += 1048576;
  float* psum1 = (float*)w; w += 1024;
  float* psq1 = (float*)w;  w += 1024;
  float* psum2 = (float*)w; w += 1024;
  float* psq2 = (float*)w;  w += 1024;
  float* ncb = (float*)w;   w += 1572864;
  int* vidx = (int*)w;      w += 524288;
  u16* wt1b = (u16*)w;      w += 55296;
  u16* wt2b = (u16*)w;      w += 55296;
  float* m1 = (float*)w;    w += 2048;
  float* m2 = (float*)w;    w += 2048;
  float* mp = (float*)w;    w += 2048;
  float* A1 = (float*)w;    w += 1024;
  float* B1 = (float*)w;    w += 1024;
  float* Sc = (float*)w;    w += 1024;
  float* Tc = (float*)w;    w += 1024;
  float* Ap = (float*)w;    w += 1024;
  float* Bp = (float*)w;    w += 1024;
  float* pmean = (float*)w; w += 256;
  float* prstd = (float*)w; w += 256;
  float* out = (float*)d_out;

  hipMemsetAsync(sums, 0, 33554432, stream);
  hipMemsetAsync(cnt, 0, 1048576 + 4096, stream);

  k_coords<<<Bn, 256, 0, stream>>>(coords, ncb, vidx);
  k_twz<<<108, 256, 0, stream>>>(conv1_w, wt1b);
  k_twz<<<108, 256, 0, stream>>>(conv2_w, wt2b);
  k_mods<<<1, 256, 0, stream>>>(condition, mod1_w, mod1_b, mod2_w, mod2_b,
                                modp_w, modp_b, m1, m2, mp);
  k_scatter<<<(Bn * Nn) / 256, 256, 0, stream>>>(features, vidx, sums, cnt);
  k_normvox<<<4096, 256, 0, stream>>>(sums, cnt, (uint4*)vox0);
  k_conv<false><<<4096, 512, 0, stream>>>(vox0, wt1b, conv1_b, nullptr, nullptr, vox1);
  k_stats_cl<<<Bn * 128, 256, 0, stream>>>(vox1, psum1, psq1);
  k_coef1<<<1, 256, 0, stream>>>(psum1, psq1, m1, gn1_g, gn1_b, A1, B1);
  k_conv<true><<<4096, 512, 0, stream>>>(vox1, wt2b, conv2_b, A1, B1, vox2);
  k_stats_cl<<<Bn * 128, 256, 0, stream>>>(vox2, psum2, psq2);
  k_coef2<<<1, 256, 0, stream>>>(psum2, psq2, m2, gn2_g, gn2_b, se_w1, se_w2, Sc, Tc);
  k_devox<<<(Bn * Nn) / 256, 256, 0, stream>>>(vox2, ncb, Sc, Tc, out);
  k_pxlin<<<Bn * 64, 256, 0, stream>>>(features, pc_w, pc_b, px);
  k_statsp<<<64, 256, 0, stream>>>(px, pmean, prstd);
  k_coefp<<<1, 256, 0, stream>>>(pmean, prstd, mp, gnp_g, gnp_b, Ap, Bp);
  k_final<<<(Bn * Cn * Nn) / 256, 256, 0, stream>>>(px, Ap, Bp, out);
}

// Round 3
// 633.256 us; speedup vs baseline: 14.5986x; 1.2302x over previous
//
#include <hip/hip_runtime.h>
#include <math.h>

#define DEV_INLINE __device__ __forceinline__

namespace {

typedef unsigned short u16;
typedef unsigned int u32;
typedef __attribute__((ext_vector_type(8))) short short8v;
typedef __attribute__((ext_vector_type(4))) float f32x4;

constexpr int Bn = 8, Cn = 32, Nn = 16384, Rn = 32, Vn = Rn * Rn * Rn;

DEV_INLINE float siluf(float x) { return x / (1.0f + expf(-x)); }
DEV_INLINE float bf2f(u16 u) { union { u32 i; float f; } x; x.i = (u32)u << 16; return x.f; }
DEV_INLINE u16 f2bf(float f) {
  union { float f; u32 i; } x; x.f = f;
  return (u16)((x.i + 0x7FFFu + ((x.i >> 16) & 1u)) >> 16);
}
DEV_INLINE u32 pack2(float a, float b) { return (u32)f2bf(a) | ((u32)f2bf(b) << 16); }
DEV_INLINE void unpack8(uint4 u, float* f) {
  f[0] = bf2f(u.x & 0xffff); f[1] = bf2f(u.x >> 16);
  f[2] = bf2f(u.y & 0xffff); f[3] = bf2f(u.y >> 16);
  f[4] = bf2f(u.z & 0xffff); f[5] = bf2f(u.z >> 16);
  f[6] = bf2f(u.w & 0xffff); f[7] = bf2f(u.w >> 16);
}

// ---------------- coords: mean, max-norm, nc, voxel idx, histogram ----------------
__global__ void k_coords(const float* __restrict__ coords,
                         float* __restrict__ nc, int* __restrict__ vidx,
                         int* __restrict__ hist) {
  int b = blockIdx.x;
  int t = threadIdx.x;  // 256
  __shared__ float red[256];
  __shared__ float mean_s[3];
  __shared__ float denom_s;
  const float* cb = coords + (size_t)b * 3 * Nn;

  float sx = 0.f, sy = 0.f, sz = 0.f;
  for (int n = t; n < Nn; n += 256) {
    sx += cb[n]; sy += cb[Nn + n]; sz += cb[2 * Nn + n];
  }
  float vals[3] = {sx, sy, sz};
  for (int a = 0; a < 3; ++a) {
    red[t] = vals[a]; __syncthreads();
    for (int s = 128; s > 0; s >>= 1) {
      if (t < s) red[t] += red[t + s];
      __syncthreads();
    }
    if (t == 0) mean_s[a] = red[0] / (float)Nn;
    __syncthreads();
  }
  float mx = mean_s[0], my = mean_s[1], mz = mean_s[2];

  float mq = 0.f;
  for (int n = t; n < Nn; n += 256) {
    float x = cb[n] - mx, y = cb[Nn + n] - my, z = cb[2 * Nn + n] - mz;
    mq = fmaxf(mq, x * x + y * y + z * z);
  }
  red[t] = mq; __syncthreads();
  for (int s = 128; s > 0; s >>= 1) {
    if (t < s) red[t] = fmaxf(red[t], red[t + s]);
    __syncthreads();
  }
  if (t == 0) denom_s = 2.0f * sqrtf(red[0]);
  __syncthreads();
  float inv = 1.0f / denom_s;

  float* ncb = nc + (size_t)b * 3 * Nn;
  int* ib = vidx + (size_t)b * Nn;
  for (int n = t; n < Nn; n += 256) {
    float x = (cb[n] - mx) * inv + 0.5f;
    float y = (cb[Nn + n] - my) * inv + 0.5f;
    float z = (cb[2 * Nn + n] - mz) * inv + 0.5f;
    x = fminf(fmaxf(x * (float)Rn, 0.f), (float)(Rn - 1));
    y = fminf(fmaxf(y * (float)Rn, 0.f), (float)(Rn - 1));
    z = fminf(fmaxf(z * (float)Rn, 0.f), (float)(Rn - 1));
    ncb[n] = x; ncb[Nn + n] = y; ncb[2 * Nn + n] = z;
    int vx = (int)rintf(x), vy = (int)rintf(y), vz = (int)rintf(z);
    int v = (vx * Rn + vy) * Rn + vz;
    ib[n] = v;
    atomicAdd(&hist[b * Vn + v], 1);
  }
}

// ---------------- transpose features (B,C,N) f32 -> (B,N,C) f32 ----------------
__global__ void k_ftr(const float* __restrict__ feat, float* __restrict__ featT) {
  __shared__ float lds[32 * 65];
  int t = threadIdx.x;
  int blk = blockIdx.x;  // B * N/64
  int b = blk >> 8, tile = blk & 255;
  int n0 = tile * 64;
  for (int idx = t; idx < 2048; idx += 256) {
    int c = idx >> 6, nn = idx & 63;
    lds[c * 65 + nn] = feat[((size_t)b * 32 + c) * Nn + n0 + nn];
  }
  __syncthreads();
  for (int idx = t; idx < 2048; idx += 256) {
    int n = idx >> 5, c = idx & 31;
    featT[((size_t)b * Nn + n0 + n) * 32 + c] = lds[c * 65 + n];
  }
}

// ---------------- scan stage 1: per-1024-chunk exclusive prefix ----------------
__global__ void k_scan1(const int* __restrict__ hist, int* __restrict__ offs,
                        int* __restrict__ bsum) {
  __shared__ int sd[256];
  int t = threadIdx.x, blk = blockIdx.x;  // 256 blocks
  int4 h = reinterpret_cast<const int4*>(hist)[blk * 256 + t];
  int s = h.x + h.y + h.z + h.w;
  sd[t] = s; __syncthreads();
  for (int off = 1; off < 256; off <<= 1) {
    int add = (t >= off) ? sd[t - off] : 0;
    __syncthreads();
    sd[t] += add;
    __syncthreads();
  }
  int excl = sd[t] - s;
  int4 o;
  o.x = excl; o.y = excl + h.x; o.z = o.y + h.y; o.w = o.z + h.z;
  reinterpret_cast<int4*>(offs)[blk * 256 + t] = o;
  if (t == 0) bsum[blk] = sd[255];
}

// ---------------- scan stage 2: exclusive scan of 256 block sums ----------------
__global__ void k_scan2(const int* __restrict__ bsum, int* __restrict__ bbase) {
  __shared__ int sd[256];
  int t = threadIdx.x;
  int s = bsum[t];
  sd[t] = s; __syncthreads();
  for (int off = 1; off < 256; off <<= 1) {
    int add = (t >= off) ? sd[t - off] : 0;
    __syncthreads();
    sd[t] += add;
    __syncthreads();
  }
  bbase[t] = sd[t] - s;
}

// ---------------- cursor-scatter point indices into sorted order ----------------
__global__ void k_sortidx(const int* __restrict__ vidx, int* __restrict__ offs,
                          const int* __restrict__ bbase, int* __restrict__ pidx) {
  int i = blockIdx.x * 256 + threadIdx.x;  // B*N
  int b = i >> 14, n = i & (Nn - 1);
  int g = b * Vn + vidx[i];
  int p = atomicAdd(&offs[g], 1) + bbase[g >> 10];
  pidx[p] = n;
}

// ---------------- per-voxel average -> bf16 channel-last vox0 ----------------
__global__ void k_voxavg(const int* __restrict__ hist, const int* __restrict__ offs,
                         const int* __restrict__ bbase, const int* __restrict__ pidx,
                         const float* __restrict__ featT, uint2* __restrict__ vox0) {
  int t = threadIdx.x;
  int wv = blockIdx.x * 4 + (t >> 6);  // global voxel id, B*V total
  int lane = t & 63;
  int c4 = lane & 7, j = lane >> 3;
  int b = wv >> 15;
  int cnt = hist[wv];
  float ax = 0.f, ay = 0.f, az = 0.f, aw = 0.f;
  if (cnt > 0) {
    int end = offs[wv] + bbase[wv >> 10];  // offs is post-scatter cursor = local end
    int start = end - cnt;
    const float4* ft = reinterpret_cast<const float4*>(featT) + (size_t)b * Nn * 8;
    for (int k = start + j; k < end; k += 8) {
      int n = pidx[k];
      float4 v = ft[n * 8 + c4];
      ax += v.x; ay += v.y; az += v.z; aw += v.w;
    }
    #pragma unroll
    for (int m = 8; m <= 32; m <<= 1) {
      ax += __shfl_xor(ax, m); ay += __shfl_xor(ay, m);
      az += __shfl_xor(az, m); aw += __shfl_xor(aw, m);
    }
    float invc = 1.0f / (float)cnt;
    ax *= invc; ay *= invc; az *= invc; aw *= invc;
  }
  if (j == 0) {
    uint2 o;
    o.x = pack2(ax, ay);
    o.y = pack2(az, aw);
    vox0[(size_t)wv * 8 + c4] = o;
  }
}

// ---------------- weight transpose: w[co][ci][k] -> wt_bf16[k][co][ci] ----------------
__global__ void k_twz(const float* __restrict__ w, u16* __restrict__ wt) {
  int i = blockIdx.x * 256 + threadIdx.x;
  if (i >= 27 * 32 * 32) return;
  int ci = i & 31, co = (i >> 5) & 31, k = i >> 10;
  wt[i] = f2bf(w[(co * 32 + ci) * 27 + k]);
}

// ---------------- modulation vectors m = silu(cond) @ mw.T + mb ----------------
__global__ void k_mods(const float* __restrict__ cond,
                       const float* __restrict__ w1, const float* __restrict__ b1,
                       const float* __restrict__ w2, const float* __restrict__ b2,
                       const float* __restrict__ wp, const float* __restrict__ bp,
                       float* __restrict__ m1, float* __restrict__ m2,
                       float* __restrict__ mp) {
  __shared__ float sc[2048];
  int t = threadIdx.x;
  for (int i = t; i < 2048; i += 256) sc[i] = siluf(cond[i]);
  __syncthreads();
  for (int o = t; o < 1536; o += 256) {
    int mat = o / 512, rem = o - mat * 512;
    int b = rem >> 6, oo = rem & 63;
    const float* w = (mat == 0) ? w1 : ((mat == 1) ? w2 : wp);
    const float* bb = (mat == 0) ? b1 : ((mat == 1) ? b2 : bp);
    float acc = bb[oo];
    const float* wrow = w + oo * 256;
    const float* scb = sc + b * 256;
    for (int k = 0; k < 256; ++k) acc += wrow[k] * scb[k];
    float* dst = (mat == 0) ? m1 : ((mat == 1) ? m2 : mp);
    dst[b * 64 + oo] = acc;
  }
}

// ---------------- 3x3x3 conv as implicit GEMM on bf16 MFMA ----------------
template <bool AFF>
__global__ __launch_bounds__(512, 4) void k_conv(
    const u16* __restrict__ in, const u16* __restrict__ wt,
    const float* __restrict__ bias, const float* __restrict__ Ac,
    const float* __restrict__ Bc, u16* __restrict__ out) {
  __shared__ uint4 lds_w4[3456];   // 55296 B
  __shared__ uint4 lds_x4[1632];   // 26112 B
  int t = threadIdx.x;
  int blk = blockIdx.x;
  int yp = blk & 15, x = (blk >> 4) & 31, b = blk >> 9;
  int y0 = yp * 2;
  size_t bbase = (size_t)b * Vn;

  const uint4* gw = reinterpret_cast<const uint4*>(wt);
  for (int i = t; i < 3456; i += 512) lds_w4[i] = gw[i];

  for (int i = t; i < 1632; i += 512) {
    int rowid = i >> 2, c4 = i & 3;
    int col = rowid / 34, r = rowid - col * 34;
    int dxp = col >> 2, yy = col & 3;
    int gx = x + dxp - 1, gy = y0 + yy - 1, z = r - 1;
    uint4 val = make_uint4(0u, 0u, 0u, 0u);
    if (gx >= 0 && gx < 32 && gy >= 0 && gy < 32 && z >= 0 && z < 32) {
      val = *reinterpret_cast<const uint4*>(
          in + (bbase + (size_t)((gx * 32 + gy) * 32 + z)) * 32 + c4 * 8);
      if (AFF) {
        float f[8];
        unpack8(val, f);
        float4 A0 = reinterpret_cast<const float4*>(Ac)[b * 8 + c4 * 2];
        float4 A1 = reinterpret_cast<const float4*>(Ac)[b * 8 + c4 * 2 + 1];
        float4 B0 = reinterpret_cast<const float4*>(Bc)[b * 8 + c4 * 2];
        float4 B1 = reinterpret_cast<const float4*>(Bc)[b * 8 + c4 * 2 + 1];
        f[0] = siluf(f[0] * A0.x + B0.x); f[1] = siluf(f[1] * A0.y + B0.y);
        f[2] = siluf(f[2] * A0.z + B0.z); f[3] = siluf(f[3] * A0.w + B0.w);
        f[4] = siluf(f[4] * A1.x + B1.x); f[5] = siluf(f[5] * A1.y + B1.y);
        f[6] = siluf(f[6] * A1.z + B1.z); f[7] = siluf(f[7] * A1.w + B1.w);
        val.x = pack2(f[0], f[1]); val.y = pack2(f[2], f[3]);
        val.z = pack2(f[4], f[5]); val.w = pack2(f[6], f[7]);
      }
    }
    lds_x4[i] = val;
  }
  __syncthreads();

  int w = t >> 6, lane = t & 63, lr = lane & 15, lh = lane >> 4;
  int yy_out = w & 1, mt = (w >> 1) & 1, nt = (w >> 2) & 1;
  int y = y0 + yy_out;
  int co0 = nt * 16 + lh * 4;

  f32x4 acc;
  acc[0] = bias[co0]; acc[1] = bias[co0 + 1];
  acc[2] = bias[co0 + 2]; acc[3] = bias[co0 + 3];

  const u16* lw = reinterpret_cast<const u16*>(lds_w4);
  const u16* lx = reinterpret_cast<const u16*>(lds_x4);

  #pragma unroll
  for (int dxp = 0; dxp < 3; ++dxp) {
    #pragma unroll
    for (int dyp = 0; dyp < 3; ++dyp) {
      int col = dxp * 4 + yy_out + dyp;
      #pragma unroll
      for (int dzp = 0; dzp < 3; ++dzp) {
        int k = (dxp * 3 + dyp) * 3 + dzp;
        short8v a = *reinterpret_cast<const short8v*>(
            lw + ((k * 32 + nt * 16 + lr) * 32 + lh * 8));
        short8v bb = *reinterpret_cast<const short8v*>(
            lx + ((col * 34 + mt * 16 + lr + dzp) * 32 + lh * 8));
        acc = __builtin_amdgcn_mfma_f32_16x16x32_bf16(a, bb, acc, 0, 0, 0);
      }
    }
  }

  int z = mt * 16 + lr;
  size_t off = (bbase + (size_t)((x * 32 + y) * 32 + z)) * 32 + co0;
  uint2 o;
  o.x = pack2(acc[0], acc[1]);
  o.y = pack2(acc[2], acc[3]);
  *reinterpret_cast<uint2*>(out + off) = o;
}

// ---------------- per-channel sum/sumsq on channel-last bf16 (B,V,C) ----------------
__global__ void k_stats_cl(const u16* __restrict__ x, float* __restrict__ psum,
                           float* __restrict__ psq) {
  int blk = blockIdx.x;  // B*128
  int b = blk >> 7, chunk = blk & 127;
  int t = threadIdx.x;
  int c8 = t & 3, vsub = t >> 2;
  float s[8], q[8];
  #pragma unroll
  for (int j = 0; j < 8; ++j) { s[j] = 0.f; q[j] = 0.f; }
  const uint4* xb = reinterpret_cast<const uint4*>(x + (size_t)b * Vn * Cn);
  for (int it = 0; it < 4; ++it) {
    int v = chunk * 256 + it * 64 + vsub;
    uint4 u = xb[v * 4 + c8];
    float f[8];
    unpack8(u, f);
    #pragma unroll
    for (int j = 0; j < 8; ++j) { s[j] += f[j]; q[j] += f[j] * f[j]; }
  }
  #pragma unroll
  for (int m = 4; m <= 32; m <<= 1) {
    #pragma unroll
    for (int j = 0; j < 8; ++j) {
      s[j] += __shfl_xor(s[j], m);
      q[j] += __shfl_xor(q[j], m);
    }
  }
  if ((t & 63) < 4) {
    int base = b * 32 + c8 * 8;
    #pragma unroll
    for (int j = 0; j < 8; ++j) {
      atomicAdd(&psum[base + j], s[j]);
      atomicAdd(&psq[base + j], q[j]);
    }
  }
}

// ---------------- AdaGN affine coefficients (stage 1) ----------------
__global__ void k_coef1(const float* __restrict__ psum, const float* __restrict__ psq,
                        const float* __restrict__ mod, const float* __restrict__ g,
                        const float* __restrict__ bgn, float* __restrict__ A,
                        float* __restrict__ Bc) {
  int t = threadIdx.x;  // 256 = B*C
  int b = t >> 5, c = t & 31, grp = c >> 2;
  float s = 0, q = 0;
  for (int j = 0; j < 4; ++j) {
    s += psum[b * 32 + grp * 4 + j];
    q += psq[b * 32 + grp * 4 + j];
  }
  const float cntf = 4.0f * (float)Vn;
  float mean = s / cntf;
  float var = q / cntf - mean * mean;
  float rstd = rsqrtf(var + 1e-5f);
  float scale = mod[b * 64 + c], shift = mod[b * 64 + 32 + c];
  A[t] = rstd * g[c] * scale;
  Bc[t] = (bgn[c] - mean * rstd * g[c]) * scale + shift;
}

// ---------------- AdaGN stage 2 + SE -> final gather affine S,T ----------------
__global__ void k_coef2(const float* __restrict__ psum, const float* __restrict__ psq,
                        const float* __restrict__ mod, const float* __restrict__ g,
                        const float* __restrict__ bgn, const float* __restrict__ sw1,
                        const float* __restrict__ sw2, float* __restrict__ S,
                        float* __restrict__ T) {
  __shared__ float zm[8][32];
  __shared__ float hh[8][4];
  int t = threadIdx.x;  // 256 = B*C
  int b = t >> 5, c = t & 31, grp = c >> 2;
  float s = 0, q = 0;
  for (int j = 0; j < 4; ++j) {
    s += psum[b * 32 + grp * 4 + j];
    q += psq[b * 32 + grp * 4 + j];
  }
  const float cntf = 4.0f * (float)Vn;
  float mean = s / cntf;
  float var = q / cntf - mean * mean;
  float rstd = rsqrtf(var + 1e-5f);
  float scale = mod[b * 64 + c], shift = mod[b * 64 + 32 + c];
  float A = rstd * g[c] * scale;
  float Bv = (bgn[c] - mean * rstd * g[c]) * scale + shift;
  float chmean = psum[b * 32 + c] / (float)Vn;
  zm[b][c] = A * chmean + Bv;
  __syncthreads();
  if (t < 32) {
    int b2 = t >> 2, j = t & 3;
    float h = 0;
    for (int cc = 0; cc < 32; ++cc) h += sw1[j * 32 + cc] * zm[b2][cc];
    hh[b2][j] = fmaxf(h, 0.f);
  }
  __syncthreads();
  float sig = 0;
  for (int j = 0; j < 4; ++j) sig += sw2[c * 4 + j] * hh[b][j];
  sig = 1.0f / (1.0f + expf(-sig));
  S[t] = A * sig;
  T[t] = Bv * sig;
}

// ---------------- trilinear devoxelize (bf16 vox) with fused affine ----------------
__global__ void k_devox(const u16* __restrict__ vox, const float* __restrict__ nc,
                        const float* __restrict__ S, const float* __restrict__ T,
                        float* __restrict__ out) {
  int i = blockIdx.x * 256 + threadIdx.x;  // B*N
  int b = i >> 14, n = i & (Nn - 1);
  const float* ncb = nc + (size_t)b * 3 * Nn;
  float fx = ncb[n], fy = ncb[Nn + n], fz = ncb[2 * Nn + n];
  float lxf = floorf(fx), lyf = floorf(fy), lzf = floorf(fz);
  float wx1 = fx - lxf, wy1 = fy - lyf, wz1 = fz - lzf;
  int lx = (int)lxf, ly = (int)lyf, lz = (int)lzf;
  int hx = min(lx + 1, 31), hy = min(ly + 1, 31), hz = min(lz + 1, 31);
  float a[32];
  #pragma unroll
  for (int c = 0; c < 32; ++c) a[c] = 0.f;
  for (int corner = 0; corner < 8; ++corner) {
    int cx = (corner & 4) ? hx : lx;
    int cy = (corner & 2) ? hy : ly;
    int cz = (corner & 1) ? hz : lz;
    float ww = ((corner & 4) ? wx1 : 1.f - wx1) *
               ((corner & 2) ? wy1 : 1.f - wy1) *
               ((corner & 1) ? wz1 : 1.f - wz1);
    const uint4* p = reinterpret_cast<const uint4*>(
        vox + ((size_t)b * Vn + (size_t)((cx * 32 + cy) * 32 + cz)) * 32);
    #pragma unroll
    for (int qq = 0; qq < 4; ++qq) {
      float f[8];
      unpack8(p[qq], f);
      #pragma unroll
      for (int j = 0; j < 8; ++j) a[qq * 8 + j] += ww * f[j];
    }
  }
  float* o = out + (size_t)b * 32 * Nn + n;
  #pragma unroll
  for (int c = 0; c < 32; ++c) {
    o[(size_t)c * Nn] = a[c] * S[b * 32 + c] + T[b * 32 + c];
  }
}

// ---------------- point branch: 1x1 conv (32x32 GEMM per point) ----------------
__global__ void k_pxlin(const float* __restrict__ feat, const float* __restrict__ w,
                        const float* __restrict__ bias, float* __restrict__ px) {
  __shared__ float lw[1024];
  __shared__ float lb[32];
  int t = threadIdx.x;
  for (int i = t; i < 1024; i += 256) lw[i] = w[i];
  if (t < 32) lb[t] = bias[t];
  __syncthreads();
  int blk = blockIdx.x;  // B*64
  int b = blk >> 6, tile = blk & 63;
  int n = tile * 256 + t;
  float fr[32];
  const float* fb = feat + (size_t)b * 32 * Nn + n;
  #pragma unroll
  for (int ci = 0; ci < 32; ++ci) fr[ci] = fb[(size_t)ci * Nn];
  float* ob = px + (size_t)b * 32 * Nn + n;
  for (int co = 0; co < 32; ++co) {
    float acc = lb[co];
    #pragma unroll
    for (int ci = 0; ci < 32; ++ci) acc += lw[co * 32 + ci] * fr[ci];
    ob[(size_t)co * Nn] = acc;
  }
}

// ---------------- point-branch group stats (channel-first) ----------------
__global__ void k_statsp(const float* __restrict__ px, float* __restrict__ mean_out,
                         float* __restrict__ rstd_out) {
  int blk = blockIdx.x;  // 64 = B*G
  int b = blk >> 3, g = blk & 7;
  const float4* base = reinterpret_cast<const float4*>(
      px + (size_t)b * 32 * Nn + (size_t)g * 4 * Nn);
  float s = 0, q = 0;
  int t = threadIdx.x;
  for (int i = t; i < 16384; i += 256) {
    float4 v = base[i];
    s += v.x + v.y + v.z + v.w;
    q += v.x * v.x + v.y * v.y + v.z * v.z + v.w * v.w;
  }
  __shared__ float rs[256], rq[256];
  rs[t] = s; rq[t] = q; __syncthreads();
  for (int st = 128; st > 0; st >>= 1) {
    if (t < st) { rs[t] += rs[t + st]; rq[t] += rq[t + st]; }
    __syncthreads();
  }
  if (t == 0) {
    float mean = rs[0] / 65536.f;
    float var = rq[0] / 65536.f - mean * mean;
    mean_out[blk] = mean;
    rstd_out[blk] = rsqrtf(var + 1e-5f);
  }
}

// ---------------- point-branch affine coefficients ----------------
__global__ void k_coefp(const float* __restrict__ mean, const float* __restrict__ rstd,
                        const float* __restrict__ mod, const float* __restrict__ g,
                        const float* __restrict__ bgn, float* __restrict__ A,
                        float* __restrict__ Bc) {
  int t = threadIdx.x;  // 256
  int b = t >> 5, c = t & 31, grp = c >> 2;
  float m = mean[b * 8 + grp], r = rstd[b * 8 + grp];
  float scale = mod[b * 64 + c], shift = mod[b * 64 + 32 + c];
  A[t] = r * g[c] * scale;
  Bc[t] = (bgn[c] - m * r * g[c]) * scale + shift;
}

// ---------------- final: out += silu(px*A+B) ----------------
__global__ void k_final(const float* __restrict__ px, const float* __restrict__ A,
                        const float* __restrict__ Bc, float* __restrict__ out) {
  int i = blockIdx.x * 256 + threadIdx.x;  // B*C*N
  int bc = i >> 14;
  float y = px[i] * A[bc] + Bc[bc];
  out[i] += y / (1.0f + expf(-y));
}

}  // namespace

extern "C" void kernel_launch(void* const* d_in, const int* in_sizes, int n_in,
                              void* d_out, int out_size, void* d_ws, size_t ws_size,
                              hipStream_t stream) {
  (void)in_sizes; (void)n_in; (void)out_size; (void)ws_size;
  const float* features = (const float*)d_in[0];
  const float* coords = (const float*)d_in[1];
  const float* condition = (const float*)d_in[2];
  const float* conv1_w = (const float*)d_in[3];
  const float* conv1_b = (const float*)d_in[4];
  const float* gn1_g = (const float*)d_in[5];
  const float* gn1_b = (const float*)d_in[6];
  const float* mod1_w = (const float*)d_in[7];
  const float* mod1_b = (const float*)d_in[8];
  const float* conv2_w = (const float*)d_in[9];
  const float* conv2_b = (const float*)d_in[10];
  const float* gn2_g = (const float*)d_in[11];
  const float* gn2_b = (const float*)d_in[12];
  const float* mod2_w = (const float*)d_in[13];
  const float* mod2_b = (const float*)d_in[14];
  const float* se_w1 = (const float*)d_in[15];
  const float* se_w2 = (const float*)d_in[16];
  const float* pc_w = (const float*)d_in[17];
  const float* pc_b = (const float*)d_in[18];
  const float* gnp_g = (const float*)d_in[19];
  const float* gnp_b = (const float*)d_in[20];
  const float* modp_w = (const float*)d_in[21];
  const float* modp_b = (const float*)d_in[22];

  char* w = (char*)d_ws;
  // R0 (33.5 MB): [first half] featT f32 (until voxavg) -> vox1 bf16 (conv1 out,
  //               dead after conv2) -> px f32 (pxlin..final). [second half] vox2.
  float* featT = (float*)w;
  u16* vox1 = (u16*)w;
  float* px = (float*)w;
  u16* vox2 = (u16*)(w + 16777216);
  w += 33554432;
  // R1 (16.8 MB): vox0 bf16 (voxavg -> conv1)
  u16* vox0 = (u16*)w; w += 16777216;
  int* hist = (int*)w;  w += 1048576;   // hist + psums share one memset block
  float* psum1 = (float*)w; w += 1024;
  float* psq1 = (float*)w;  w += 1024;
  float* psum2 = (float*)w; w += 1024;
  float* psq2 = (float*)w;  w += 1024;
  int* offs = (int*)w;  w += 1048576;
  int* bsum = (int*)w;  w += 1024;
  int* bbase = (int*)w; w += 1024;
  int* pidx = (int*)w;  w += 524288;
  float* ncb = (float*)w;   w += 1572864;
  int* vidx = (int*)w;      w += 524288;
  u16* wt1b = (u16*)w;      w += 55296;
  u16* wt2b = (u16*)w;      w += 55296;
  float* m1 = (float*)w;    w += 2048;
  float* m2 = (float*)w;    w += 2048;
  float* mp = (float*)w;    w += 2048;
  float* A1 = (float*)w;    w += 1024;
  float* B1 = (float*)w;    w += 1024;
  float* Sc = (float*)w;    w += 1024;
  float* Tc = (float*)w;    w += 1024;
  float* Ap = (float*)w;    w += 1024;
  float* Bp = (float*)w;    w += 1024;
  float* pmean = (float*)w; w += 256;
  float* prstd = (float*)w; w += 256;
  float* out = (float*)d_out;

  hipMemsetAsync(hist, 0, 1048576 + 4096, stream);

  k_coords<<<Bn, 256, 0, stream>>>(coords, ncb, vidx, hist);
  k_ftr<<<Bn * 256, 256, 0, stream>>>(features, featT);
  k_twz<<<108, 256, 0, stream>>>(conv1_w, wt1b);
  k_twz<<<108, 256, 0, stream>>>(conv2_w, wt2b);
  k_mods<<<1, 256, 0, stream>>>(condition, mod1_w, mod1_b, mod2_w, mod2_b,
                                modp_w, modp_b, m1, m2, mp);
  k_scan1<<<256, 256, 0, stream>>>(hist, offs, bsum);
  k_scan2<<<1, 256, 0, stream>>>(bsum, bbase);
  k_sortidx<<<(Bn * Nn) / 256, 256, 0, stream>>>(vidx, offs, bbase, pidx);
  k_voxavg<<<(Bn * Vn) / 4, 256, 0, stream>>>(hist, offs, bbase, pidx, featT,
                                              (uint2*)vox0);
  k_conv<false><<<4096, 512, 0, stream>>>(vox0, wt1b, conv1_b, nullptr, nullptr, vox1);
  k_stats_cl<<<Bn * 128, 256, 0, stream>>>(vox1, psum1, psq1);
  k_coef1<<<1, 256, 0, stream>>>(psum1, psq1, m1, gn1_g, gn1_b, A1, B1);
  k_conv<true><<<4096, 512, 0, stream>>>(vox1, wt2b, conv2_b, A1, B1, vox2);
  k_stats_cl<<<Bn * 128, 256, 0, stream>>>(vox2, psum2, psq2);
  k_coef2<<<1, 256, 0, stream>>>(psum2, psq2, m2, gn2_g, gn2_b, se_w1, se_w2, Sc, Tc);
  k_devox<<<(Bn * Nn) / 256, 256, 0, stream>>>(vox2, ncb, Sc, Tc, out);
  k_pxlin<<<Bn * 64, 256, 0, stream>>>(features, pc_w, pc_b, px);
  k_statsp<<<64, 256, 0, stream>>>(px, pmean, prstd);
  k_coefp<<<1, 256, 0, stream>>>(pmean, prstd, mp, gnp_g, gnp_b, Ap, Bp);
  k_final<<<(Bn * Cn * Nn) / 256, 256, 0, stream>>>(px, Ap, Bp, out);
}

// Round 4
// 365.628 us; speedup vs baseline: 25.2843x; 1.7320x over previous
//
#include <hip/hip_runtime.h>
#include <math.h>

#define DEV_INLINE __device__ __forceinline__

namespace {

typedef unsigned short u16;
typedef unsigned int u32;
typedef __attribute__((ext_vector_type(8))) short short8v;
typedef __attribute__((ext_vector_type(4))) float f32x4;

constexpr int Bn = 8, Cn = 32, Nn = 16384, Rn = 32, Vn = Rn * Rn * Rn;

DEV_INLINE float siluf(float x) { return x / (1.0f + expf(-x)); }
DEV_INLINE float bf2f(u16 u) { union { u32 i; float f; } x; x.i = (u32)u << 16; return x.f; }
DEV_INLINE u16 f2bf(float f) {
  union { float f; u32 i; } x; x.f = f;
  return (u16)((x.i + 0x7FFFu + ((x.i >> 16) & 1u)) >> 16);
}
DEV_INLINE u32 pack2(float a, float b) { return (u32)f2bf(a) | ((u32)f2bf(b) << 16); }
DEV_INLINE void unpack8(uint4 u, float* f) {
  f[0] = bf2f(u.x & 0xffff); f[1] = bf2f(u.x >> 16);
  f[2] = bf2f(u.y & 0xffff); f[3] = bf2f(u.y >> 16);
  f[4] = bf2f(u.z & 0xffff); f[5] = bf2f(u.z >> 16);
  f[6] = bf2f(u.w & 0xffff); f[7] = bf2f(u.w >> 16);
}

// ---------------- coords: mean, max-norm, nc, voxel idx, histogram ----------------
__global__ void k_coords(const float* __restrict__ coords,
                         float* __restrict__ nc, int* __restrict__ vidx,
                         int* __restrict__ hist) {
  int b = blockIdx.x;
  int t = threadIdx.x;  // 256
  __shared__ float red[256];
  __shared__ float mean_s[3];
  __shared__ float denom_s;
  const float* cb = coords + (size_t)b * 3 * Nn;

  float sx = 0.f, sy = 0.f, sz = 0.f;
  for (int n = t; n < Nn; n += 256) {
    sx += cb[n]; sy += cb[Nn + n]; sz += cb[2 * Nn + n];
  }
  float vals[3] = {sx, sy, sz};
  for (int a = 0; a < 3; ++a) {
    red[t] = vals[a]; __syncthreads();
    for (int s = 128; s > 0; s >>= 1) {
      if (t < s) red[t] += red[t + s];
      __syncthreads();
    }
    if (t == 0) mean_s[a] = red[0] / (float)Nn;
    __syncthreads();
  }
  float mx = mean_s[0], my = mean_s[1], mz = mean_s[2];

  float mq = 0.f;
  for (int n = t; n < Nn; n += 256) {
    float x = cb[n] - mx, y = cb[Nn + n] - my, z = cb[2 * Nn + n] - mz;
    mq = fmaxf(mq, x * x + y * y + z * z);
  }
  red[t] = mq; __syncthreads();
  for (int s = 128; s > 0; s >>= 1) {
    if (t < s) red[t] = fmaxf(red[t], red[t + s]);
    __syncthreads();
  }
  if (t == 0) denom_s = 2.0f * sqrtf(red[0]);
  __syncthreads();
  float inv = 1.0f / denom_s;

  float* ncb = nc + (size_t)b * 3 * Nn;
  int* ib = vidx + (size_t)b * Nn;
  for (int n = t; n < Nn; n += 256) {
    float x = (cb[n] - mx) * inv + 0.5f;
    float y = (cb[Nn + n] - my) * inv + 0.5f;
    float z = (cb[2 * Nn + n] - mz) * inv + 0.5f;
    x = fminf(fmaxf(x * (float)Rn, 0.f), (float)(Rn - 1));
    y = fminf(fmaxf(y * (float)Rn, 0.f), (float)(Rn - 1));
    z = fminf(fmaxf(z * (float)Rn, 0.f), (float)(Rn - 1));
    ncb[n] = x; ncb[Nn + n] = y; ncb[2 * Nn + n] = z;
    int vx = (int)rintf(x), vy = (int)rintf(y), vz = (int)rintf(z);
    int v = (vx * Rn + vy) * Rn + vz;
    ib[n] = v;
    atomicAdd(&hist[b * Vn + v], 1);
  }
}

// ---------------- transpose features (B,C,N) f32 -> (B,N,C) f32 ----------------
__global__ void k_ftr(const float* __restrict__ feat, float* __restrict__ featT) {
  __shared__ float lds[32 * 65];
  int t = threadIdx.x;
  int blk = blockIdx.x;  // B * N/64
  int b = blk >> 8, tile = blk & 255;
  int n0 = tile * 64;
  for (int idx = t; idx < 2048; idx += 256) {
    int c = idx >> 6, nn = idx & 63;
    lds[c * 65 + nn] = feat[((size_t)b * 32 + c) * Nn + n0 + nn];
  }
  __syncthreads();
  for (int idx = t; idx < 2048; idx += 256) {
    int n = idx >> 5, c = idx & 31;
    featT[((size_t)b * Nn + n0 + n) * 32 + c] = lds[c * 65 + n];
  }
}

// ---------------- scan stage 1: per-1024-chunk exclusive prefix ----------------
__global__ void k_scan1(const int* __restrict__ hist, int* __restrict__ offs,
                        int* __restrict__ bsum) {
  __shared__ int sd[256];
  int t = threadIdx.x, blk = blockIdx.x;  // 256 blocks
  int4 h = reinterpret_cast<const int4*>(hist)[blk * 256 + t];
  int s = h.x + h.y + h.z + h.w;
  sd[t] = s; __syncthreads();
  for (int off = 1; off < 256; off <<= 1) {
    int add = (t >= off) ? sd[t - off] : 0;
    __syncthreads();
    sd[t] += add;
    __syncthreads();
  }
  int excl = sd[t] - s;
  int4 o;
  o.x = excl; o.y = excl + h.x; o.z = o.y + h.y; o.w = o.z + h.z;
  reinterpret_cast<int4*>(offs)[blk * 256 + t] = o;
  if (t == 0) bsum[blk] = sd[255];
}

// ---------------- scan stage 2: exclusive scan of 256 block sums ----------------
__global__ void k_scan2(const int* __restrict__ bsum, int* __restrict__ bbase) {
  __shared__ int sd[256];
  int t = threadIdx.x;
  int s = bsum[t];
  sd[t] = s; __syncthreads();
  for (int off = 1; off < 256; off <<= 1) {
    int add = (t >= off) ? sd[t - off] : 0;
    __syncthreads();
    sd[t] += add;
    __syncthreads();
  }
  bbase[t] = sd[t] - s;
}

// ---------------- cursor-scatter point indices into sorted order ----------------
__global__ void k_sortidx(const int* __restrict__ vidx, int* __restrict__ offs,
                          const int* __restrict__ bbase, int* __restrict__ pidx) {
  int i = blockIdx.x * 256 + threadIdx.x;  // B*N
  int b = i >> 14, n = i & (Nn - 1);
  int g = b * Vn + vidx[i];
  int p = atomicAdd(&offs[g], 1) + bbase[g >> 10];
  pidx[p] = n;
}

// ---------------- per-voxel average -> bf16 channel-last vox0 ----------------
__global__ void k_voxavg(const int* __restrict__ hist, const int* __restrict__ offs,
                         const int* __restrict__ bbase, const int* __restrict__ pidx,
                         const float* __restrict__ featT, uint2* __restrict__ vox0) {
  int t = threadIdx.x;
  int wv = blockIdx.x * 4 + (t >> 6);  // global voxel id, B*V total
  int lane = t & 63;
  int c4 = lane & 7, j = lane >> 3;
  int b = wv >> 15;
  int cnt = hist[wv];
  float ax = 0.f, ay = 0.f, az = 0.f, aw = 0.f;
  if (cnt > 0) {
    int end = offs[wv] + bbase[wv >> 10];  // offs is post-scatter cursor = local end
    int start = end - cnt;
    const float4* ft = reinterpret_cast<const float4*>(featT) + (size_t)b * Nn * 8;
    for (int k = start + j; k < end; k += 8) {
      int n = pidx[k];
      float4 v = ft[n * 8 + c4];
      ax += v.x; ay += v.y; az += v.z; aw += v.w;
    }
    #pragma unroll
    for (int m = 8; m <= 32; m <<= 1) {
      ax += __shfl_xor(ax, m); ay += __shfl_xor(ay, m);
      az += __shfl_xor(az, m); aw += __shfl_xor(aw, m);
    }
    float invc = 1.0f / (float)cnt;
    ax *= invc; ay *= invc; az *= invc; aw *= invc;
  }
  if (j == 0) {
    uint2 o;
    o.x = pack2(ax, ay);
    o.y = pack2(az, aw);
    vox0[(size_t)wv * 8 + c4] = o;
  }
}

// ---------------- weight transpose: w[co][ci][k] -> wt_bf16[k][co][ci] ----------------
__global__ void k_twz(const float* __restrict__ w, u16* __restrict__ wt) {
  int i = blockIdx.x * 256 + threadIdx.x;
  if (i >= 27 * 32 * 32) return;
  int ci = i & 31, co = (i >> 5) & 31, k = i >> 10;
  wt[i] = f2bf(w[(co * 32 + ci) * 27 + k]);
}

// ---------------- modulation vectors m = silu(cond) @ mw.T + mb ----------------
__global__ void k_mods(const float* __restrict__ cond,
                       const float* __restrict__ w1, const float* __restrict__ b1,
                       const float* __restrict__ w2, const float* __restrict__ b2,
                       const float* __restrict__ wp, const float* __restrict__ bp,
                       float* __restrict__ m1, float* __restrict__ m2,
                       float* __restrict__ mp) {
  __shared__ float sc[2048];
  int t = threadIdx.x;
  for (int i = t; i < 2048; i += 256) sc[i] = siluf(cond[i]);
  __syncthreads();
  for (int o = t; o < 1536; o += 256) {
    int mat = o / 512, rem = o - mat * 512;
    int b = rem >> 6, oo = rem & 63;
    const float* w = (mat == 0) ? w1 : ((mat == 1) ? w2 : wp);
    const float* bb = (mat == 0) ? b1 : ((mat == 1) ? b2 : bp);
    float acc = bb[oo];
    const float* wrow = w + oo * 256;
    const float* scb = sc + b * 256;
    for (int k = 0; k < 256; ++k) acc += wrow[k] * scb[k];
    float* dst = (mat == 0) ? m1 : ((mat == 1) ? m2 : mp);
    dst[b * 64 + oo] = acc;
  }
}

// ---------------- 3x3x3 conv as implicit GEMM on bf16 MFMA ----------------
template <bool AFF>
__global__ __launch_bounds__(512, 4) void k_conv(
    const u16* __restrict__ in, const u16* __restrict__ wt,
    const float* __restrict__ bias, const float* __restrict__ Ac,
    const float* __restrict__ Bc, u16* __restrict__ out) {
  __shared__ uint4 lds_w4[3456];   // 55296 B
  __shared__ uint4 lds_x4[1632];   // 26112 B
  int t = threadIdx.x;
  int blk = blockIdx.x;
  int yp = blk & 15, x = (blk >> 4) & 31, b = blk >> 9;
  int y0 = yp * 2;
  size_t bbase = (size_t)b * Vn;

  const uint4* gw = reinterpret_cast<const uint4*>(wt);
  for (int i = t; i < 3456; i += 512) lds_w4[i] = gw[i];

  for (int i = t; i < 1632; i += 512) {
    int rowid = i >> 2, c4 = i & 3;
    int col = rowid / 34, r = rowid - col * 34;
    int dxp = col >> 2, yy = col & 3;
    int gx = x + dxp - 1, gy = y0 + yy - 1, z = r - 1;
    uint4 val = make_uint4(0u, 0u, 0u, 0u);
    if (gx >= 0 && gx < 32 && gy >= 0 && gy < 32 && z >= 0 && z < 32) {
      val = *reinterpret_cast<const uint4*>(
          in + (bbase + (size_t)((gx * 32 + gy) * 32 + z)) * 32 + c4 * 8);
      if (AFF) {
        float f[8];
        unpack8(val, f);
        float4 A0 = reinterpret_cast<const float4*>(Ac)[b * 8 + c4 * 2];
        float4 A1 = reinterpret_cast<const float4*>(Ac)[b * 8 + c4 * 2 + 1];
        float4 B0 = reinterpret_cast<const float4*>(Bc)[b * 8 + c4 * 2];
        float4 B1 = reinterpret_cast<const float4*>(Bc)[b * 8 + c4 * 2 + 1];
        f[0] = siluf(f[0] * A0.x + B0.x); f[1] = siluf(f[1] * A0.y + B0.y);
        f[2] = siluf(f[2] * A0.z + B0.z); f[3] = siluf(f[3] * A0.w + B0.w);
        f[4] = siluf(f[4] * A1.x + B1.x); f[5] = siluf(f[5] * A1.y + B1.y);
        f[6] = siluf(f[6] * A1.z + B1.z); f[7] = siluf(f[7] * A1.w + B1.w);
        val.x = pack2(f[0], f[1]); val.y = pack2(f[2], f[3]);
        val.z = pack2(f[4], f[5]); val.w = pack2(f[6], f[7]);
      }
    }
    lds_x4[i] = val;
  }
  __syncthreads();

  int w = t >> 6, lane = t & 63, lr = lane & 15, lh = lane >> 4;
  int yy_out = w & 1, mt = (w >> 1) & 1, nt = (w >> 2) & 1;
  int y = y0 + yy_out;
  int co0 = nt * 16 + lh * 4;

  f32x4 acc;
  acc[0] = bias[co0]; acc[1] = bias[co0 + 1];
  acc[2] = bias[co0 + 2]; acc[3] = bias[co0 + 3];

  const u16* lw = reinterpret_cast<const u16*>(lds_w4);
  const u16* lx = reinterpret_cast<const u16*>(lds_x4);

  #pragma unroll
  for (int dxp = 0; dxp < 3; ++dxp) {
    #pragma unroll
    for (int dyp = 0; dyp < 3; ++dyp) {
      int col = dxp * 4 + yy_out + dyp;
      #pragma unroll
      for (int dzp = 0; dzp < 3; ++dzp) {
        int k = (dxp * 3 + dyp) * 3 + dzp;
        short8v a = *reinterpret_cast<const short8v*>(
            lw + ((k * 32 + nt * 16 + lr) * 32 + lh * 8));
        short8v bb = *reinterpret_cast<const short8v*>(
            lx + ((col * 34 + mt * 16 + lr + dzp) * 32 + lh * 8));
        acc = __builtin_amdgcn_mfma_f32_16x16x32_bf16(a, bb, acc, 0, 0, 0);
      }
    }
  }

  int z = mt * 16 + lr;
  size_t off = (bbase + (size_t)((x * 32 + y) * 32 + z)) * 32 + co0;
  uint2 o;
  o.x = pack2(acc[0], acc[1]);
  o.y = pack2(acc[2], acc[3]);
  *reinterpret_cast<uint2*>(out + off) = o;
}

// ---------------- per-channel sum/sumsq, block-reduced (few atomics) ----------------
__global__ void k_stats_cl(const u16* __restrict__ x, float* __restrict__ psum,
                           float* __restrict__ psq) {
  int blk = blockIdx.x;  // 256 = B * 32 segments
  int b = blk >> 5, seg = blk & 31;
  int t = threadIdx.x;
  int c8 = t & 3, vsub = t >> 2;  // vsub 0..63 across block (16 per wave)
  float s[8], q[8];
  #pragma unroll
  for (int j = 0; j < 8; ++j) { s[j] = 0.f; q[j] = 0.f; }
  const uint4* xb = reinterpret_cast<const uint4*>(x + (size_t)b * Vn * Cn) +
                    (size_t)seg * 4096;
  for (int it = 0; it < 16; ++it) {
    int v = it * 64 + vsub;
    uint4 u = xb[v * 4 + c8];
    float f[8];
    unpack8(u, f);
    #pragma unroll
    for (int j = 0; j < 8; ++j) { s[j] += f[j]; q[j] += f[j] * f[j]; }
  }
  #pragma unroll
  for (int m = 4; m <= 32; m <<= 1) {
    #pragma unroll
    for (int j = 0; j < 8; ++j) {
      s[j] += __shfl_xor(s[j], m);
      q[j] += __shfl_xor(q[j], m);
    }
  }
  __shared__ float ls[2][4][4][8];  // [sum|sq][wave][c8][j]
  int wv = t >> 6;
  if ((t & 63) < 4) {
    #pragma unroll
    for (int j = 0; j < 8; ++j) { ls[0][wv][c8][j] = s[j]; ls[1][wv][c8][j] = q[j]; }
  }
  __syncthreads();
  if (t < 64) {
    int arr = t >> 5, c = t & 31;
    float v = ls[arr][0][c >> 3][c & 7] + ls[arr][1][c >> 3][c & 7] +
              ls[arr][2][c >> 3][c & 7] + ls[arr][3][c >> 3][c & 7];
    atomicAdd((arr == 0 ? psum : psq) + b * 32 + c, v);
  }
}

// ---------------- AdaGN affine coefficients (stage 1) ----------------
__global__ void k_coef1(const float* __restrict__ psum, const float* __restrict__ psq,
                        const float* __restrict__ mod, const float* __restrict__ g,
                        const float* __restrict__ bgn, float* __restrict__ A,
                        float* __restrict__ Bc) {
  int t = threadIdx.x;  // 256 = B*C
  int b = t >> 5, c = t & 31, grp = c >> 2;
  float s = 0, q = 0;
  for (int j = 0; j < 4; ++j) {
    s += psum[b * 32 + grp * 4 + j];
    q += psq[b * 32 + grp * 4 + j];
  }
  const float cntf = 4.0f * (float)Vn;
  float mean = s / cntf;
  float var = q / cntf - mean * mean;
  float rstd = rsqrtf(var + 1e-5f);
  float scale = mod[b * 64 + c], shift = mod[b * 64 + 32 + c];
  A[t] = rstd * g[c] * scale;
  Bc[t] = (bgn[c] - mean * rstd * g[c]) * scale + shift;
}

// ---------------- AdaGN stage 2 + SE -> final gather affine S,T ----------------
__global__ void k_coef2(const float* __restrict__ psum, const float* __restrict__ psq,
                        const float* __restrict__ mod, const float* __restrict__ g,
                        const float* __restrict__ bgn, const float* __restrict__ sw1,
                        const float* __restrict__ sw2, float* __restrict__ S,
                        float* __restrict__ T) {
  __shared__ float zm[8][32];
  __shared__ float hh[8][4];
  int t = threadIdx.x;  // 256 = B*C
  int b = t >> 5, c = t & 31, grp = c >> 2;
  float s = 0, q = 0;
  for (int j = 0; j < 4; ++j) {
    s += psum[b * 32 + grp * 4 + j];
    q += psq[b * 32 + grp * 4 + j];
  }
  const float cntf = 4.0f * (float)Vn;
  float mean = s / cntf;
  float var = q / cntf - mean * mean;
  float rstd = rsqrtf(var + 1e-5f);
  float scale = mod[b * 64 + c], shift = mod[b * 64 + 32 + c];
  float A = rstd * g[c] * scale;
  float Bv = (bgn[c] - mean * rstd * g[c]) * scale + shift;
  float chmean = psum[b * 32 + c] / (float)Vn;
  zm[b][c] = A * chmean + Bv;
  __syncthreads();
  if (t < 32) {
    int b2 = t >> 2, j = t & 3;
    float h = 0;
    for (int cc = 0; cc < 32; ++cc) h += sw1[j * 32 + cc] * zm[b2][cc];
    hh[b2][j] = fmaxf(h, 0.f);
  }
  __syncthreads();
  float sig = 0;
  for (int j = 0; j < 4; ++j) sig += sw2[c * 4 + j] * hh[b][j];
  sig = 1.0f / (1.0f + expf(-sig));
  S[t] = A * sig;
  T[t] = Bv * sig;
}

// ---------------- trilinear devoxelize (bf16 vox) with fused affine ----------------
__global__ void k_devox(const u16* __restrict__ vox, const float* __restrict__ nc,
                        const float* __restrict__ S, const float* __restrict__ T,
                        float* __restrict__ out) {
  int i = blockIdx.x * 256 + threadIdx.x;  // B*N
  int b = i >> 14, n = i & (Nn - 1);
  const float* ncb = nc + (size_t)b * 3 * Nn;
  float fx = ncb[n], fy = ncb[Nn + n], fz = ncb[2 * Nn + n];
  float lxf = floorf(fx), lyf = floorf(fy), lzf = floorf(fz);
  float wx1 = fx - lxf, wy1 = fy - lyf, wz1 = fz - lzf;
  int lx = (int)lxf, ly = (int)lyf, lz = (int)lzf;
  int hx = min(lx + 1, 31), hy = min(ly + 1, 31), hz = min(lz + 1, 31);
  float a[32];
  #pragma unroll
  for (int c = 0; c < 32; ++c) a[c] = 0.f;
  for (int corner = 0; corner < 8; ++corner) {
    int cx = (corner & 4) ? hx : lx;
    int cy = (corner & 2) ? hy : ly;
    int cz = (corner & 1) ? hz : lz;
    float ww = ((corner & 4) ? wx1 : 1.f - wx1) *
               ((corner & 2) ? wy1 : 1.f - wy1) *
               ((corner & 1) ? wz1 : 1.f - wz1);
    const uint4* p = reinterpret_cast<const uint4*>(
        vox + ((size_t)b * Vn + (size_t)((cx * 32 + cy) * 32 + cz)) * 32);
    #pragma unroll
    for (int qq = 0; qq < 4; ++qq) {
      float f[8];
      unpack8(p[qq], f);
      #pragma unroll
      for (int j = 0; j < 8; ++j) a[qq * 8 + j] += ww * f[j];
    }
  }
  float* o = out + (size_t)b * 32 * Nn + n;
  #pragma unroll
  for (int c = 0; c < 32; ++c) {
    o[(size_t)c * Nn] = a[c] * S[b * 32 + c] + T[b * 32 + c];
  }
}

// ---------------- point branch: 1x1 conv (32x32 GEMM per point) ----------------
__global__ void k_pxlin(const float* __restrict__ feat, const float* __restrict__ w,
                        const float* __restrict__ bias, float* __restrict__ px) {
  __shared__ float lw[1024];
  __shared__ float lb[32];
  int t = threadIdx.x;
  for (int i = t; i < 1024; i += 256) lw[i] = w[i];
  if (t < 32) lb[t] = bias[t];
  __syncthreads();
  int blk = blockIdx.x;  // B*64
  int b = blk >> 6, tile = blk & 63;
  int n = tile * 256 + t;
  float fr[32];
  const float* fb = feat + (size_t)b * 32 * Nn + n;
  #pragma unroll
  for (int ci = 0; ci < 32; ++ci) fr[ci] = fb[(size_t)ci * Nn];
  float* ob = px + (size_t)b * 32 * Nn + n;
  for (int co = 0; co < 32; ++co) {
    float acc = lb[co];
    #pragma unroll
    for (int ci = 0; ci < 32; ++ci) acc += lw[co * 32 + ci] * fr[ci];
    ob[(size_t)co * Nn] = acc;
  }
}

// ---------------- point-branch group partial stats (few atomics) ----------------
__global__ void k_statsp(const float* __restrict__ px, float* __restrict__ pgsum,
                         float* __restrict__ pgsq) {
  int blk = blockIdx.x;  // 256 = B * G * 4 quarters
  int b = blk >> 5, g = (blk >> 2) & 7, qr = blk & 3;
  const float4* base = reinterpret_cast<const float4*>(
      px + (size_t)b * 32 * Nn + (size_t)g * 4 * Nn) + qr * 4096;
  float s = 0, q = 0;
  int t = threadIdx.x;
  for (int i = t; i < 4096; i += 256) {
    float4 v = base[i];
    s += v.x + v.y + v.z + v.w;
    q += v.x * v.x + v.y * v.y + v.z * v.z + v.w * v.w;
  }
  #pragma unroll
  for (int m = 1; m <= 32; m <<= 1) {
    s += __shfl_xor(s, m);
    q += __shfl_xor(q, m);
  }
  __shared__ float rs[4], rq[4];
  if ((t & 63) == 0) { rs[t >> 6] = s; rq[t >> 6] = q; }
  __syncthreads();
  if (t == 0) {
    atomicAdd(&pgsum[b * 8 + g], rs[0] + rs[1] + rs[2] + rs[3]);
    atomicAdd(&pgsq[b * 8 + g], rq[0] + rq[1] + rq[2] + rq[3]);
  }
}

// ---------------- point-branch affine coefficients ----------------
__global__ void k_coefp(const float* __restrict__ pgsum, const float* __restrict__ pgsq,
                        const float* __restrict__ mod, const float* __restrict__ g,
                        const float* __restrict__ bgn, float* __restrict__ A,
                        float* __restrict__ Bc) {
  int t = threadIdx.x;  // 256
  int b = t >> 5, c = t & 31, grp = c >> 2;
  float m = pgsum[b * 8 + grp] / 65536.f;
  float var = pgsq[b * 8 + grp] / 65536.f - m * m;
  float r = rsqrtf(var + 1e-5f);
  float scale = mod[b * 64 + c], shift = mod[b * 64 + 32 + c];
  A[t] = r * g[c] * scale;
  Bc[t] = (bgn[c] - m * r * g[c]) * scale + shift;
}

// ---------------- final: out += silu(px*A+B) ----------------
__global__ void k_final(const float* __restrict__ px, const float* __restrict__ A,
                        const float* __restrict__ Bc, float* __restrict__ out) {
  int i = blockIdx.x * 256 + threadIdx.x;  // B*C*N
  int bc = i >> 14;
  float y = px[i] * A[bc] + Bc[bc];
  out[i] += y / (1.0f + expf(-y));
}

}  // namespace

extern "C" void kernel_launch(void* const* d_in, const int* in_sizes, int n_in,
                              void* d_out, int out_size, void* d_ws, size_t ws_size,
                              hipStream_t stream) {
  (void)in_sizes; (void)n_in; (void)out_size; (void)ws_size;
  const float* features = (const float*)d_in[0];
  const float* coords = (const float*)d_in[1];
  const float* condition = (const float*)d_in[2];
  const float* conv1_w = (const float*)d_in[3];
  const float* conv1_b = (const float*)d_in[4];
  const float* gn1_g = (const float*)d_in[5];
  const float* gn1_b = (const float*)d_in[6];
  const float* mod1_w = (const float*)d_in[7];
  const float* mod1_b = (const float*)d_in[8];
  const float* conv2_w = (const float*)d_in[9];
  const float* conv2_b = (const float*)d_in[10];
  const float* gn2_g = (const float*)d_in[11];
  const float* gn2_b = (const float*)d_in[12];
  const float* mod2_w = (const float*)d_in[13];
  const float* mod2_b = (const float*)d_in[14];
  const float* se_w1 = (const float*)d_in[15];
  const float* se_w2 = (const float*)d_in[16];
  const float* pc_w = (const float*)d_in[17];
  const float* pc_b = (const float*)d_in[18];
  const float* gnp_g = (const float*)d_in[19];
  const float* gnp_b = (const float*)d_in[20];
  const float* modp_w = (const float*)d_in[21];
  const float* modp_b = (const float*)d_in[22];

  char* w = (char*)d_ws;
  // R0 (33.5 MB): [first half] featT f32 (until voxavg) -> vox1 bf16 (conv1 out,
  //               dead after conv2) -> px f32 (pxlin..final). [second half] vox2.
  float* featT = (float*)w;
  u16* vox1 = (u16*)w;
  float* px = (float*)w;
  u16* vox2 = (u16*)(w + 16777216);
  w += 33554432;
  // R1 (16.8 MB): vox0 bf16 (voxavg -> conv1)
  u16* vox0 = (u16*)w; w += 16777216;
  int* hist = (int*)w;  w += 1048576;   // hist + psums + pg* share one memset block
  float* psum1 = (float*)w; w += 1024;
  float* psq1 = (float*)w;  w += 1024;
  float* psum2 = (float*)w; w += 1024;
  float* psq2 = (float*)w;  w += 1024;
  float* pgsum = (float*)w; w += 256;
  float* pgsq = (float*)w;  w += 256;
  int* offs = (int*)w;  w += 1048576;
  int* bsum = (int*)w;  w += 1024;
  int* bbase = (int*)w; w += 1024;
  int* pidx = (int*)w;  w += 524288;
  float* ncb = (float*)w;   w += 1572864;
  int* vidx = (int*)w;      w += 524288;
  u16* wt1b = (u16*)w;      w += 55296;
  u16* wt2b = (u16*)w;      w += 55296;
  float* m1 = (float*)w;    w += 2048;
  float* m2 = (float*)w;    w += 2048;
  float* mp = (float*)w;    w += 2048;
  float* A1 = (float*)w;    w += 1024;
  float* B1 = (float*)w;    w += 1024;
  float* Sc = (float*)w;    w += 1024;
  float* Tc = (float*)w;    w += 1024;
  float* Ap = (float*)w;    w += 1024;
  float* Bp = (float*)w;    w += 1024;
  float* out = (float*)d_out;

  hipMemsetAsync(hist, 0, 1048576 + 4096 + 512, stream);

  k_coords<<<Bn, 256, 0, stream>>>(coords, ncb, vidx, hist);
  k_ftr<<<Bn * 256, 256, 0, stream>>>(features, featT);
  k_twz<<<108, 256, 0, stream>>>(conv1_w, wt1b);
  k_twz<<<108, 256, 0, stream>>>(conv2_w, wt2b);
  k_mods<<<1, 256, 0, stream>>>(condition, mod1_w, mod1_b, mod2_w, mod2_b,
                                modp_w, modp_b, m1, m2, mp);
  k_scan1<<<256, 256, 0, stream>>>(hist, offs, bsum);
  k_scan2<<<1, 256, 0, stream>>>(bsum, bbase);
  k_sortidx<<<(Bn * Nn) / 256, 256, 0, stream>>>(vidx, offs, bbase, pidx);
  k_voxavg<<<(Bn * Vn) / 4, 256, 0, stream>>>(hist, offs, bbase, pidx, featT,
                                              (uint2*)vox0);
  k_conv<false><<<4096, 512, 0, stream>>>(vox0, wt1b, conv1_b, nullptr, nullptr, vox1);
  k_stats_cl<<<256, 256, 0, stream>>>(vox1, psum1, psq1);
  k_coef1<<<1, 256, 0, stream>>>(psum1, psq1, m1, gn1_g, gn1_b, A1, B1);
  k_conv<true><<<4096, 512, 0, stream>>>(vox1, wt2b, conv2_b, A1, B1, vox2);
  k_stats_cl<<<256, 256, 0, stream>>>(vox2, psum2, psq2);
  k_coef2<<<1, 256, 0, stream>>>(psum2, psq2, m2, gn2_g, gn2_b, se_w1, se_w2, Sc, Tc);
  k_devox<<<(Bn * Nn) / 256, 256, 0, stream>>>(vox2, ncb, Sc, Tc, out);
  k_pxlin<<<Bn * 64, 256, 0, stream>>>(features, pc_w, pc_b, px);
  k_statsp<<<256, 256, 0, stream>>>(px, pgsum, pgsq);
  k_coefp<<<1, 256, 0, stream>>>(pgsum, pgsq, mp, gnp_g, gnp_b, Ap, Bp);
  k_final<<<(Bn * Cn * Nn) / 256, 256, 0, stream>>>(px, Ap, Bp, out);
}

// Round 5
// 297.296 us; speedup vs baseline: 31.0958x; 1.2298x over previous
//
#include <hip/hip_runtime.h>
#include <math.h>

#define DEV_INLINE __device__ __forceinline__

namespace {

typedef unsigned short u16;
typedef unsigned int u32;
typedef __attribute__((ext_vector_type(8))) short short8v;
typedef __attribute__((ext_vector_type(4))) float f32x4;

constexpr int Bn = 8, Cn = 32, Nn = 16384, Rn = 32, Vn = Rn * Rn * Rn;

DEV_INLINE float siluf(float x) { return x / (1.0f + __expf(-x)); }
DEV_INLINE float bf2f(u16 u) { union { u32 i; float f; } x; x.i = (u32)u << 16; return x.f; }
DEV_INLINE u16 f2bf(float f) {
  union { float f; u32 i; } x; x.f = f;
  return (u16)((x.i + 0x7FFFu + ((x.i >> 16) & 1u)) >> 16);
}
DEV_INLINE u32 pack2(float a, float b) { return (u32)f2bf(a) | ((u32)f2bf(b) << 16); }
DEV_INLINE void unpack8(uint4 u, float* f) {
  f[0] = bf2f(u.x & 0xffff); f[1] = bf2f(u.x >> 16);
  f[2] = bf2f(u.y & 0xffff); f[3] = bf2f(u.y >> 16);
  f[4] = bf2f(u.z & 0xffff); f[5] = bf2f(u.z >> 16);
  f[6] = bf2f(u.w & 0xffff); f[7] = bf2f(u.w >> 16);
}

// ---------------- coords stage 1: partial xyz sums ----------------
__global__ void k_cpart1(const float* __restrict__ coords, float* __restrict__ csum) {
  int blk = blockIdx.x;  // B*8
  int b = blk >> 3, s = blk & 7;
  int t = threadIdx.x;
  const float* cb = coords + (size_t)b * 3 * Nn;
  int n0 = s * 2048;
  float sx = 0.f, sy = 0.f, sz = 0.f;
  for (int n = n0 + t; n < n0 + 2048; n += 256) {
    sx += cb[n]; sy += cb[Nn + n]; sz += cb[2 * Nn + n];
  }
  #pragma unroll
  for (int m = 1; m <= 32; m <<= 1) {
    sx += __shfl_xor(sx, m); sy += __shfl_xor(sy, m); sz += __shfl_xor(sz, m);
  }
  __shared__ float rs[3][4];
  if ((t & 63) == 0) { rs[0][t >> 6] = sx; rs[1][t >> 6] = sy; rs[2][t >> 6] = sz; }
  __syncthreads();
  if (t < 3) atomicAdd(&csum[b * 4 + t], rs[t][0] + rs[t][1] + rs[t][2] + rs[t][3]);
}

// ---------------- coords stage 2: partial max of squared norm ----------------
__global__ void k_cpart2(const float* __restrict__ coords, const float* __restrict__ csum,
                         int* __restrict__ cmax) {
  int blk = blockIdx.x;  // B*8
  int b = blk >> 3, s = blk & 7;
  int t = threadIdx.x;
  const float* cb = coords + (size_t)b * 3 * Nn;
  const float invn = 1.0f / (float)Nn;
  float mx = csum[b * 4] * invn, my = csum[b * 4 + 1] * invn, mz = csum[b * 4 + 2] * invn;
  int n0 = s * 2048;
  float mq = 0.f;
  for (int n = n0 + t; n < n0 + 2048; n += 256) {
    float x = cb[n] - mx, y = cb[Nn + n] - my, z = cb[2 * Nn + n] - mz;
    mq = fmaxf(mq, x * x + y * y + z * z);
  }
  #pragma unroll
  for (int m = 1; m <= 32; m <<= 1) mq = fmaxf(mq, __shfl_xor(mq, m));
  __shared__ float rm[4];
  if ((t & 63) == 0) rm[t >> 6] = mq;
  __syncthreads();
  if (t == 0) {
    float v = fmaxf(fmaxf(rm[0], rm[1]), fmaxf(rm[2], rm[3]));
    atomicMax(cmax + b, __float_as_int(v));  // values >= 0 -> int-bits order ok
  }
}

// ---------------- coords stage 3: nc, voxel idx, histogram ----------------
__global__ void k_cfinal(const float* __restrict__ coords, const float* __restrict__ csum,
                         const int* __restrict__ cmax, float* __restrict__ nc,
                         int* __restrict__ vidx, int* __restrict__ hist) {
  int i = blockIdx.x * 256 + threadIdx.x;  // B*N
  int b = i >> 14, n = i & (Nn - 1);
  const float* cb = coords + (size_t)b * 3 * Nn;
  const float invn = 1.0f / (float)Nn;
  float mx = csum[b * 4] * invn, my = csum[b * 4 + 1] * invn, mz = csum[b * 4 + 2] * invn;
  float inv = 1.0f / (2.0f * sqrtf(__int_as_float(cmax[b])));
  float x = (cb[n] - mx) * inv + 0.5f;
  float y = (cb[Nn + n] - my) * inv + 0.5f;
  float z = (cb[2 * Nn + n] - mz) * inv + 0.5f;
  x = fminf(fmaxf(x * (float)Rn, 0.f), (float)(Rn - 1));
  y = fminf(fmaxf(y * (float)Rn, 0.f), (float)(Rn - 1));
  z = fminf(fmaxf(z * (float)Rn, 0.f), (float)(Rn - 1));
  float* ncb = nc + (size_t)b * 3 * Nn;
  ncb[n] = x; ncb[Nn + n] = y; ncb[2 * Nn + n] = z;
  int vx = (int)rintf(x), vy = (int)rintf(y), vz = (int)rintf(z);
  int v = (vx * Rn + vy) * Rn + vz;
  vidx[i] = v;
  atomicAdd(&hist[b * Vn + v], 1);
}

// ---------------- transpose features (B,C,N) f32 -> (B,N,C) f32 ----------------
__global__ void k_ftr(const float* __restrict__ feat, float* __restrict__ featT) {
  __shared__ float lds[32 * 65];
  int t = threadIdx.x;
  int blk = blockIdx.x;  // B * N/64
  int b = blk >> 8, tile = blk & 255;
  int n0 = tile * 64;
  for (int idx = t; idx < 2048; idx += 256) {
    int c = idx >> 6, nn = idx & 63;
    lds[c * 65 + nn] = feat[((size_t)b * 32 + c) * Nn + n0 + nn];
  }
  __syncthreads();
  for (int idx = t; idx < 2048; idx += 256) {
    int n = idx >> 5, c = idx & 31;
    featT[((size_t)b * Nn + n0 + n) * 32 + c] = lds[c * 65 + n];
  }
}

// ---------------- scan stage 1: per-1024-chunk exclusive prefix ----------------
__global__ void k_scan1(const int* __restrict__ hist, int* __restrict__ offs,
                        int* __restrict__ bsum) {
  __shared__ int sd[256];
  int t = threadIdx.x, blk = blockIdx.x;  // 256 blocks
  int4 h = reinterpret_cast<const int4*>(hist)[blk * 256 + t];
  int s = h.x + h.y + h.z + h.w;
  sd[t] = s; __syncthreads();
  for (int off = 1; off < 256; off <<= 1) {
    int add = (t >= off) ? sd[t - off] : 0;
    __syncthreads();
    sd[t] += add;
    __syncthreads();
  }
  int excl = sd[t] - s;
  int4 o;
  o.x = excl; o.y = excl + h.x; o.z = o.y + h.y; o.w = o.z + h.z;
  reinterpret_cast<int4*>(offs)[blk * 256 + t] = o;
  if (t == 0) bsum[blk] = sd[255];
}

// ---------------- scan stage 2: exclusive scan of 256 block sums ----------------
__global__ void k_scan2(const int* __restrict__ bsum, int* __restrict__ bbase) {
  __shared__ int sd[256];
  int t = threadIdx.x;
  int s = bsum[t];
  sd[t] = s; __syncthreads();
  for (int off = 1; off < 256; off <<= 1) {
    int add = (t >= off) ? sd[t - off] : 0;
    __syncthreads();
    sd[t] += add;
    __syncthreads();
  }
  bbase[t] = sd[t] - s;
}

// ---------------- cursor-scatter point indices into sorted order ----------------
__global__ void k_sortidx(const int* __restrict__ vidx, int* __restrict__ offs,
                          const int* __restrict__ bbase, int* __restrict__ pidx) {
  int i = blockIdx.x * 256 + threadIdx.x;  // B*N
  int b = i >> 14, n = i & (Nn - 1);
  int g = b * Vn + vidx[i];
  int p = atomicAdd(&offs[g], 1) + bbase[g >> 10];
  pidx[p] = n;
}

// ---------------- per-voxel average -> bf16 channel-last vox0 ----------------
__global__ void k_voxavg(const int* __restrict__ hist, const int* __restrict__ offs,
                         const int* __restrict__ bbase, const int* __restrict__ pidx,
                         const float* __restrict__ featT, uint2* __restrict__ vox0) {
  int t = threadIdx.x;
  int wv = blockIdx.x * 4 + (t >> 6);  // global voxel id, B*V total
  int lane = t & 63;
  int c4 = lane & 7, j = lane >> 3;
  int b = wv >> 15;
  int cnt = hist[wv];
  float ax = 0.f, ay = 0.f, az = 0.f, aw = 0.f;
  if (cnt > 0) {
    int end = offs[wv] + bbase[wv >> 10];  // offs is post-scatter cursor = local end
    int start = end - cnt;
    const float4* ft = reinterpret_cast<const float4*>(featT) + (size_t)b * Nn * 8;
    for (int k = start + j; k < end; k += 8) {
      int n = pidx[k];
      float4 v = ft[n * 8 + c4];
      ax += v.x; ay += v.y; az += v.z; aw += v.w;
    }
    #pragma unroll
    for (int m = 8; m <= 32; m <<= 1) {
      ax += __shfl_xor(ax, m); ay += __shfl_xor(ay, m);
      az += __shfl_xor(az, m); aw += __shfl_xor(aw, m);
    }
    float invc = 1.0f / (float)cnt;
    ax *= invc; ay *= invc; az *= invc; aw *= invc;
  }
  if (j == 0) {
    uint2 o;
    o.x = pack2(ax, ay);
    o.y = pack2(az, aw);
    vox0[(size_t)wv * 8 + c4] = o;
  }
}

// -------- weight transpose: w[co][ci][k] -> wt_bf16[k][nt][lane][e] (MFMA-linear) ----
// lane = lh*16+lr; co = nt*16+lr; ci = lh*8+e. A-frag read becomes base+lane*16B.
__global__ void k_twz(const float* __restrict__ w, u16* __restrict__ wt) {
  int i = blockIdx.x * 256 + threadIdx.x;
  if (i >= 27 * 32 * 32) return;
  int e = i & 7, lane = (i >> 3) & 63, nt = (i >> 9) & 1, k = i >> 10;
  int lr = lane & 15, lh = lane >> 4;
  int co = nt * 16 + lr, ci = lh * 8 + e;
  wt[i] = f2bf(w[(co * 32 + ci) * 27 + k]);
}

// ---------------- modulation vectors m = silu(cond) @ mw.T + mb ----------------
__global__ void k_mods(const float* __restrict__ cond,
                       const float* __restrict__ w1, const float* __restrict__ b1,
                       const float* __restrict__ w2, const float* __restrict__ b2,
                       const float* __restrict__ wp, const float* __restrict__ bp,
                       float* __restrict__ m1, float* __restrict__ m2,
                       float* __restrict__ mp) {
  __shared__ float sc[2048];
  int t = threadIdx.x;
  for (int i = t; i < 2048; i += 256) sc[i] = siluf(cond[i]);
  __syncthreads();
  for (int o = t; o < 1536; o += 256) {
    int mat = o / 512, rem = o - mat * 512;
    int b = rem >> 6, oo = rem & 63;
    const float* w = (mat == 0) ? w1 : ((mat == 1) ? w2 : wp);
    const float* bb = (mat == 0) ? b1 : ((mat == 1) ? b2 : bp);
    float acc = bb[oo];
    const float* wrow = w + oo * 256;
    const float* scb = sc + b * 256;
    for (int k = 0; k < 256; ++k) acc += wrow[k] * scb[k];
    float* dst = (mat == 0) ? m1 : ((mat == 1) ? m2 : mp);
    dst[b * 64 + oo] = acc;
  }
}

// ---------------- 3x3x3 conv as implicit GEMM on bf16 MFMA ----------------
// W LDS layout: [k][nt][lane] 16B chunks (pre-permuted in k_twz) -> linear lane read.
// X LDS layout: [col(12)][c4(4)][r(34)] 16B chunks -> B-frag lanes read consecutive r.
template <bool AFF>
__global__ __launch_bounds__(512, 4) void k_conv(
    const u16* __restrict__ in, const u16* __restrict__ wt,
    const float* __restrict__ bias, const float* __restrict__ Ac,
    const float* __restrict__ Bc, u16* __restrict__ out) {
  __shared__ uint4 lds_w4[3456];   // 55296 B
  __shared__ uint4 lds_x4[1632];   // 26112 B
  int t = threadIdx.x;
  int blk = blockIdx.x;
  int yp = blk & 15, x = (blk >> 4) & 31, b = blk >> 9;
  int y0 = yp * 2;
  size_t bbase = (size_t)b * Vn;

  const uint4* gw = reinterpret_cast<const uint4*>(wt);
  for (int i = t; i < 3456; i += 512) lds_w4[i] = gw[i];

  for (int i = t; i < 1632; i += 512) {
    int rowid = i >> 2, c4 = i & 3;
    int col = rowid / 34, r = rowid - col * 34;
    int dxp = col >> 2, yy = col & 3;
    int gx = x + dxp - 1, gy = y0 + yy - 1, z = r - 1;
    uint4 val = make_uint4(0u, 0u, 0u, 0u);
    if (gx >= 0 && gx < 32 && gy >= 0 && gy < 32 && z >= 0 && z < 32) {
      val = *reinterpret_cast<const uint4*>(
          in + (bbase + (size_t)((gx * 32 + gy) * 32 + z)) * 32 + c4 * 8);
      if (AFF) {
        float f[8];
        unpack8(val, f);
        float4 A0 = reinterpret_cast<const float4*>(Ac)[b * 8 + c4 * 2];
        float4 A1 = reinterpret_cast<const float4*>(Ac)[b * 8 + c4 * 2 + 1];
        float4 B0 = reinterpret_cast<const float4*>(Bc)[b * 8 + c4 * 2];
        float4 B1 = reinterpret_cast<const float4*>(Bc)[b * 8 + c4 * 2 + 1];
        f[0] = siluf(f[0] * A0.x + B0.x); f[1] = siluf(f[1] * A0.y + B0.y);
        f[2] = siluf(f[2] * A0.z + B0.z); f[3] = siluf(f[3] * A0.w + B0.w);
        f[4] = siluf(f[4] * A1.x + B1.x); f[5] = siluf(f[5] * A1.y + B1.y);
        f[6] = siluf(f[6] * A1.z + B1.z); f[7] = siluf(f[7] * A1.w + B1.w);
        val.x = pack2(f[0], f[1]); val.y = pack2(f[2], f[3]);
        val.z = pack2(f[4], f[5]); val.w = pack2(f[6], f[7]);
      }
    }
    lds_x4[(col * 4 + c4) * 34 + r] = val;
  }
  __syncthreads();

  int w = t >> 6, lane = t & 63, lr = lane & 15, lh = lane >> 4;
  int yy_out = w & 1, mt = (w >> 1) & 1, nt = (w >> 2) & 1;
  int y = y0 + yy_out;
  int co0 = nt * 16 + lh * 4;

  f32x4 acc;
  acc[0] = bias[co0]; acc[1] = bias[co0 + 1];
  acc[2] = bias[co0 + 2]; acc[3] = bias[co0 + 3];

  const u16* lw = reinterpret_cast<const u16*>(lds_w4);
  const u16* lx = reinterpret_cast<const u16*>(lds_x4);

  #pragma unroll
  for (int dxp = 0; dxp < 3; ++dxp) {
    #pragma unroll
    for (int dyp = 0; dyp < 3; ++dyp) {
      int col = dxp * 4 + yy_out + dyp;
      #pragma unroll
      for (int dzp = 0; dzp < 3; ++dzp) {
        int k = (dxp * 3 + dyp) * 3 + dzp;
        short8v a = *reinterpret_cast<const short8v*>(
            lw + (k * 2 + nt) * 512 + lane * 8);
        short8v bb = *reinterpret_cast<const short8v*>(
            lx + ((col * 4 + lh) * 34 + mt * 16 + lr + dzp) * 8);
        acc = __builtin_amdgcn_mfma_f32_16x16x32_bf16(a, bb, acc, 0, 0, 0);
      }
    }
  }

  int z = mt * 16 + lr;
  size_t off = (bbase + (size_t)((x * 32 + y) * 32 + z)) * 32 + co0;
  uint2 o;
  o.x = pack2(acc[0], acc[1]);
  o.y = pack2(acc[2], acc[3]);
  *reinterpret_cast<uint2*>(out + off) = o;
}

// ---------------- per-channel sum/sumsq, block-reduced (few atomics) ----------------
__global__ void k_stats_cl(const u16* __restrict__ x, float* __restrict__ psum,
                           float* __restrict__ psq) {
  int blk = blockIdx.x;  // 256 = B * 32 segments
  int b = blk >> 5, seg = blk & 31;
  int t = threadIdx.x;
  int c8 = t & 3, vsub = t >> 2;  // vsub 0..63 across block (16 per wave)
  float s[8], q[8];
  #pragma unroll
  for (int j = 0; j < 8; ++j) { s[j] = 0.f; q[j] = 0.f; }
  const uint4* xb = reinterpret_cast<const uint4*>(x + (size_t)b * Vn * Cn) +
                    (size_t)seg * 4096;
  for (int it = 0; it < 16; ++it) {
    int v = it * 64 + vsub;
    uint4 u = xb[v * 4 + c8];
    float f[8];
    unpack8(u, f);
    #pragma unroll
    for (int j = 0; j < 8; ++j) { s[j] += f[j]; q[j] += f[j] * f[j]; }
  }
  #pragma unroll
  for (int m = 4; m <= 32; m <<= 1) {
    #pragma unroll
    for (int j = 0; j < 8; ++j) {
      s[j] += __shfl_xor(s[j], m);
      q[j] += __shfl_xor(q[j], m);
    }
  }
  __shared__ float ls[2][4][4][8];  // [sum|sq][wave][c8][j]
  int wv = t >> 6;
  if ((t & 63) < 4) {
    #pragma unroll
    for (int j = 0; j < 8; ++j) { ls[0][wv][c8][j] = s[j]; ls[1][wv][c8][j] = q[j]; }
  }
  __syncthreads();
  if (t < 64) {
    int arr = t >> 5, c = t & 31;
    float v = ls[arr][0][c >> 3][c & 7] + ls[arr][1][c >> 3][c & 7] +
              ls[arr][2][c >> 3][c & 7] + ls[arr][3][c >> 3][c & 7];
    atomicAdd((arr == 0 ? psum : psq) + b * 32 + c, v);
  }
}

// ---------------- AdaGN affine coefficients (stage 1) ----------------
__global__ void k_coef1(const float* __restrict__ psum, const float* __restrict__ psq,
                        const float* __restrict__ mod, const float* __restrict__ g,
                        const float* __restrict__ bgn, float* __restrict__ A,
                        float* __restrict__ Bc) {
  int t = threadIdx.x;  // 256 = B*C
  int b = t >> 5, c = t & 31, grp = c >> 2;
  float s = 0, q = 0;
  for (int j = 0; j < 4; ++j) {
    s += psum[b * 32 + grp * 4 + j];
    q += psq[b * 32 + grp * 4 + j];
  }
  const float cntf = 4.0f * (float)Vn;
  float mean = s / cntf;
  float var = q / cntf - mean * mean;
  float rstd = rsqrtf(var + 1e-5f);
  float scale = mod[b * 64 + c], shift = mod[b * 64 + 32 + c];
  A[t] = rstd * g[c] * scale;
  Bc[t] = (bgn[c] - mean * rstd * g[c]) * scale + shift;
}

// ---------------- AdaGN stage 2 + SE -> final gather affine S,T ----------------
__global__ void k_coef2(const float* __restrict__ psum, const float* __restrict__ psq,
                        const float* __restrict__ mod, const float* __restrict__ g,
                        const float* __restrict__ bgn, const float* __restrict__ sw1,
                        const float* __restrict__ sw2, float* __restrict__ S,
                        float* __restrict__ T) {
  __shared__ float zm[8][32];
  __shared__ float hh[8][4];
  int t = threadIdx.x;  // 256 = B*C
  int b = t >> 5, c = t & 31, grp = c >> 2;
  float s = 0, q = 0;
  for (int j = 0; j < 4; ++j) {
    s += psum[b * 32 + grp * 4 + j];
    q += psq[b * 32 + grp * 4 + j];
  }
  const float cntf = 4.0f * (float)Vn;
  float mean = s / cntf;
  float var = q / cntf - mean * mean;
  float rstd = rsqrtf(var + 1e-5f);
  float scale = mod[b * 64 + c], shift = mod[b * 64 + 32 + c];
  float A = rstd * g[c] * scale;
  float Bv = (bgn[c] - mean * rstd * g[c]) * scale + shift;
  float chmean = psum[b * 32 + c] / (float)Vn;
  zm[b][c] = A * chmean + Bv;
  __syncthreads();
  if (t < 32) {
    int b2 = t >> 2, j = t & 3;
    float h = 0;
    for (int cc = 0; cc < 32; ++cc) h += sw1[j * 32 + cc] * zm[b2][cc];
    hh[b2][j] = fmaxf(h, 0.f);
  }
  __syncthreads();
  float sig = 0;
  for (int j = 0; j < 4; ++j) sig += sw2[c * 4 + j] * hh[b][j];
  sig = 1.0f / (1.0f + __expf(-sig));
  S[t] = A * sig;
  T[t] = Bv * sig;
}

// ---------------- trilinear devoxelize (bf16 vox) with fused affine ----------------
__global__ void k_devox(const u16* __restrict__ vox, const float* __restrict__ nc,
                        const float* __restrict__ S, const float* __restrict__ T,
                        float* __restrict__ out) {
  int i = blockIdx.x * 256 + threadIdx.x;  // B*N
  int b = i >> 14, n = i & (Nn - 1);
  const float* ncb = nc + (size_t)b * 3 * Nn;
  float fx = ncb[n], fy = ncb[Nn + n], fz = ncb[2 * Nn + n];
  float lxf = floorf(fx), lyf = floorf(fy), lzf = floorf(fz);
  float wx1 = fx - lxf, wy1 = fy - lyf, wz1 = fz - lzf;
  int lx = (int)lxf, ly = (int)lyf, lz = (int)lzf;
  int hx = min(lx + 1, 31), hy = min(ly + 1, 31), hz = min(lz + 1, 31);
  float a[32];
  #pragma unroll
  for (int c = 0; c < 32; ++c) a[c] = 0.f;
  for (int corner = 0; corner < 8; ++corner) {
    int cx = (corner & 4) ? hx : lx;
    int cy = (corner & 2) ? hy : ly;
    int cz = (corner & 1) ? hz : lz;
    float ww = ((corner & 4) ? wx1 : 1.f - wx1) *
               ((corner & 2) ? wy1 : 1.f - wy1) *
               ((corner & 1) ? wz1 : 1.f - wz1);
    const uint4* p = reinterpret_cast<const uint4*>(
        vox + ((size_t)b * Vn + (size_t)((cx * 32 + cy) * 32 + cz)) * 32);
    #pragma unroll
    for (int qq = 0; qq < 4; ++qq) {
      float f[8];
      unpack8(p[qq], f);
      #pragma unroll
      for (int j = 0; j < 8; ++j) a[qq * 8 + j] += ww * f[j];
    }
  }
  float* o = out + (size_t)b * 32 * Nn + n;
  #pragma unroll
  for (int c = 0; c < 32; ++c) {
    o[(size_t)c * Nn] = a[c] * S[b * 32 + c] + T[b * 32 + c];
  }
}

// ---------------- point branch: 1x1 conv (32x32 GEMM per point) ----------------
__global__ void k_pxlin(const float* __restrict__ feat, const float* __restrict__ w,
                        const float* __restrict__ bias, float* __restrict__ px) {
  __shared__ float lw[1024];
  __shared__ float lb[32];
  int t = threadIdx.x;
  for (int i = t; i < 1024; i += 256) lw[i] = w[i];
  if (t < 32) lb[t] = bias[t];
  __syncthreads();
  int blk = blockIdx.x;  // B*64
  int b = blk >> 6, tile = blk & 63;
  int n = tile * 256 + t;
  float fr[32];
  const float* fb = feat + (size_t)b * 32 * Nn + n;
  #pragma unroll
  for (int ci = 0; ci < 32; ++ci) fr[ci] = fb[(size_t)ci * Nn];
  float* ob = px + (size_t)b * 32 * Nn + n;
  for (int co = 0; co < 32; ++co) {
    float acc = lb[co];
    #pragma unroll
    for (int ci = 0; ci < 32; ++ci) acc += lw[co * 32 + ci] * fr[ci];
    ob[(size_t)co * Nn] = acc;
  }
}

// ---------------- point-branch group partial stats (few atomics) ----------------
__global__ void k_statsp(const float* __restrict__ px, float* __restrict__ pgsum,
                         float* __restrict__ pgsq) {
  int blk = blockIdx.x;  // 256 = B * G * 4 quarters
  int b = blk >> 5, g = (blk >> 2) & 7, qr = blk & 3;
  const float4* base = reinterpret_cast<const float4*>(
      px + (size_t)b * 32 * Nn + (size_t)g * 4 * Nn) + qr * 4096;
  float s = 0, q = 0;
  int t = threadIdx.x;
  for (int i = t; i < 4096; i += 256) {
    float4 v = base[i];
    s += v.x + v.y + v.z + v.w;
    q += v.x * v.x + v.y * v.y + v.z * v.z + v.w * v.w;
  }
  #pragma unroll
  for (int m = 1; m <= 32; m <<= 1) {
    s += __shfl_xor(s, m);
    q += __shfl_xor(q, m);
  }
  __shared__ float rs[4], rq[4];
  if ((t & 63) == 0) { rs[t >> 6] = s; rq[t >> 6] = q; }
  __syncthreads();
  if (t == 0) {
    atomicAdd(&pgsum[b * 8 + g], rs[0] + rs[1] + rs[2] + rs[3]);
    atomicAdd(&pgsq[b * 8 + g], rq[0] + rq[1] + rq[2] + rq[3]);
  }
}

// ---------------- point-branch affine coefficients ----------------
__global__ void k_coefp(const float* __restrict__ pgsum, const float* __restrict__ pgsq,
                        const float* __restrict__ mod, const float* __restrict__ g,
                        const float* __restrict__ bgn, float* __restrict__ A,
                        float* __restrict__ Bc) {
  int t = threadIdx.x;  // 256
  int b = t >> 5, c = t & 31, grp = c >> 2;
  float m = pgsum[b * 8 + grp] / 65536.f;
  float var = pgsq[b * 8 + grp] / 65536.f - m * m;
  float r = rsqrtf(var + 1e-5f);
  float scale = mod[b * 64 + c], shift = mod[b * 64 + 32 + c];
  A[t] = r * g[c] * scale;
  Bc[t] = (bgn[c] - m * r * g[c]) * scale + shift;
}

// ---------------- final: out += silu(px*A+B) ----------------
__global__ void k_final(const float* __restrict__ px, const float* __restrict__ A,
                        const float* __restrict__ Bc, float* __restrict__ out) {
  int i = blockIdx.x * 256 + threadIdx.x;  // B*C*N
  int bc = i >> 14;
  float y = px[i] * A[bc] + Bc[bc];
  out[i] += siluf(y);
}

}  // namespace

extern "C" void kernel_launch(void* const* d_in, const int* in_sizes, int n_in,
                              void* d_out, int out_size, void* d_ws, size_t ws_size,
                              hipStream_t stream) {
  (void)in_sizes; (void)n_in; (void)out_size; (void)ws_size;
  const float* features = (const float*)d_in[0];
  const float* coords = (const float*)d_in[1];
  const float* condition = (const float*)d_in[2];
  const float* conv1_w = (const float*)d_in[3];
  const float* conv1_b = (const float*)d_in[4];
  const float* gn1_g = (const float*)d_in[5];
  const float* gn1_b = (const float*)d_in[6];
  const float* mod1_w = (const float*)d_in[7];
  const float* mod1_b = (const float*)d_in[8];
  const float* conv2_w = (const float*)d_in[9];
  const float* conv2_b = (const float*)d_in[10];
  const float* gn2_g = (const float*)d_in[11];
  const float* gn2_b = (const float*)d_in[12];
  const float* mod2_w = (const float*)d_in[13];
  const float* mod2_b = (const float*)d_in[14];
  const float* se_w1 = (const float*)d_in[15];
  const float* se_w2 = (const float*)d_in[16];
  const float* pc_w = (const float*)d_in[17];
  const float* pc_b = (const float*)d_in[18];
  const float* gnp_g = (const float*)d_in[19];
  const float* gnp_b = (const float*)d_in[20];
  const float* modp_w = (const float*)d_in[21];
  const float* modp_b = (const float*)d_in[22];

  char* w = (char*)d_ws;
  // R0 (33.5 MB): [first half] featT f32 (until voxavg) -> vox1 bf16 (conv1 out,
  //               dead after conv2) -> px f32 (pxlin..final). [second half] vox2.
  float* featT = (float*)w;
  u16* vox1 = (u16*)w;
  float* px = (float*)w;
  u16* vox2 = (u16*)(w + 16777216);
  w += 33554432;
  // R1 (16.8 MB): vox0 bf16 (voxavg -> conv1)
  u16* vox0 = (u16*)w; w += 16777216;
  int* hist = (int*)w;  w += 1048576;   // hist..cmax share one memset block
  float* psum1 = (float*)w; w += 1024;
  float* psq1 = (float*)w;  w += 1024;
  float* psum2 = (float*)w; w += 1024;
  float* psq2 = (float*)w;  w += 1024;
  float* pgsum = (float*)w; w += 256;
  float* pgsq = (float*)w;  w += 256;
  float* csum = (float*)w;  w += 128;
  int* cmax = (int*)w;      w += 64;
  int* offs = (int*)w;  w += 1048576;
  int* bsum = (int*)w;  w += 1024;
  int* bbase = (int*)w; w += 1024;
  int* pidx = (int*)w;  w += 524288;
  float* ncb = (float*)w;   w += 1572864;
  int* vidx = (int*)w;      w += 524288;
  u16* wt1b = (u16*)w;      w += 55296;
  u16* wt2b = (u16*)w;      w += 55296;
  float* m1 = (float*)w;    w += 2048;
  float* m2 = (float*)w;    w += 2048;
  float* mp = (float*)w;    w += 2048;
  float* A1 = (float*)w;    w += 1024;
  float* B1 = (float*)w;    w += 1024;
  float* Sc = (float*)w;    w += 1024;
  float* Tc = (float*)w;    w += 1024;
  float* Ap = (float*)w;    w += 1024;
  float* Bp = (float*)w;    w += 1024;
  float* out = (float*)d_out;

  hipMemsetAsync(hist, 0, 1048576 + 4096 + 512 + 192, stream);

  k_cpart1<<<Bn * 8, 256, 0, stream>>>(coords, csum);
  k_ftr<<<Bn * 256, 256, 0, stream>>>(features, featT);
  k_twz<<<108, 256, 0, stream>>>(conv1_w, wt1b);
  k_twz<<<108, 256, 0, stream>>>(conv2_w, wt2b);
  k_mods<<<1, 256, 0, stream>>>(condition, mod1_w, mod1_b, mod2_w, mod2_b,
                                modp_w, modp_b, m1, m2, mp);
  k_cpart2<<<Bn * 8, 256, 0, stream>>>(coords, csum, cmax);
  k_cfinal<<<(Bn * Nn) / 256, 256, 0, stream>>>(coords, csum, cmax, ncb, vidx, hist);
  k_scan1<<<256, 256, 0, stream>>>(hist, offs, bsum);
  k_scan2<<<1, 256, 0, stream>>>(bsum, bbase);
  k_sortidx<<<(Bn * Nn) / 256, 256, 0, stream>>>(vidx, offs, bbase, pidx);
  k_voxavg<<<(Bn * Vn) / 4, 256, 0, stream>>>(hist, offs, bbase, pidx, featT,
                                              (uint2*)vox0);
  k_conv<false><<<4096, 512, 0, stream>>>(vox0, wt1b, conv1_b, nullptr, nullptr, vox1);
  k_stats_cl<<<256, 256, 0, stream>>>(vox1, psum1, psq1);
  k_coef1<<<1, 256, 0, stream>>>(psum1, psq1, m1, gn1_g, gn1_b, A1, B1);
  k_conv<true><<<4096, 512, 0, stream>>>(vox1, wt2b, conv2_b, A1, B1, vox2);
  k_stats_cl<<<256, 256, 0, stream>>>(vox2, psum2, psq2);
  k_coef2<<<1, 256, 0, stream>>>(psum2, psq2, m2, gn2_g, gn2_b, se_w1, se_w2, Sc, Tc);
  k_devox<<<(Bn * Nn) / 256, 256, 0, stream>>>(vox2, ncb, Sc, Tc, out);
  k_pxlin<<<Bn * 64, 256, 0, stream>>>(features, pc_w, pc_b, px);
  k_statsp<<<256, 256, 0, stream>>>(px, pgsum, pgsq);
  k_coefp<<<1, 256, 0, stream>>>(pgsum, pgsq, mp, gnp_g, gnp_b, Ap, Bp);
  k_final<<<(Bn * Cn * Nn) / 256, 256, 0, stream>>>(px, Ap, Bp, out);
}

// Round 6
// 271.342 us; speedup vs baseline: 34.0702x; 1.0957x over previous
//
#include <hip/hip_runtime.h>
#include <math.h>

#define DEV_INLINE __device__ __forceinline__

namespace {

typedef unsigned short u16;
typedef unsigned int u32;
typedef __attribute__((ext_vector_type(8))) short short8v;
typedef __attribute__((ext_vector_type(4))) float f32x4;
typedef __attribute__((ext_vector_type(16))) float f32x16;

constexpr int Bn = 8, Cn = 32, Nn = 16384, Rn = 32, Vn = Rn * Rn * Rn;

DEV_INLINE float siluf(float x) { return x / (1.0f + __expf(-x)); }
DEV_INLINE float bf2f(u16 u) { union { u32 i; float f; } x; x.i = (u32)u << 16; return x.f; }
DEV_INLINE u16 f2bf(float f) {
  union { float f; u32 i; } x; x.f = f;
  return (u16)((x.i + 0x7FFFu + ((x.i >> 16) & 1u)) >> 16);
}
DEV_INLINE u32 pack2(float a, float b) { return (u32)f2bf(a) | ((u32)f2bf(b) << 16); }
DEV_INLINE void unpack8(uint4 u, float* f) {
  f[0] = bf2f(u.x & 0xffff); f[1] = bf2f(u.x >> 16);
  f[2] = bf2f(u.y & 0xffff); f[3] = bf2f(u.y >> 16);
  f[4] = bf2f(u.z & 0xffff); f[5] = bf2f(u.z >> 16);
  f[6] = bf2f(u.w & 0xffff); f[7] = bf2f(u.w >> 16);
}

// ---------------- coords stage 1: partial xyz sums ----------------
__global__ void k_cpart1(const float* __restrict__ coords, float* __restrict__ csum) {
  int blk = blockIdx.x;  // B*8
  int b = blk >> 3, s = blk & 7;
  int t = threadIdx.x;
  const float* cb = coords + (size_t)b * 3 * Nn;
  int n0 = s * 2048;
  float sx = 0.f, sy = 0.f, sz = 0.f;
  for (int n = n0 + t; n < n0 + 2048; n += 256) {
    sx += cb[n]; sy += cb[Nn + n]; sz += cb[2 * Nn + n];
  }
  #pragma unroll
  for (int m = 1; m <= 32; m <<= 1) {
    sx += __shfl_xor(sx, m); sy += __shfl_xor(sy, m); sz += __shfl_xor(sz, m);
  }
  __shared__ float rs[3][4];
  if ((t & 63) == 0) { rs[0][t >> 6] = sx; rs[1][t >> 6] = sy; rs[2][t >> 6] = sz; }
  __syncthreads();
  if (t < 3) atomicAdd(&csum[b * 4 + t], rs[t][0] + rs[t][1] + rs[t][2] + rs[t][3]);
}

// ---------------- coords stage 2: partial max of squared norm ----------------
__global__ void k_cpart2(const float* __restrict__ coords, const float* __restrict__ csum,
                         int* __restrict__ cmax) {
  int blk = blockIdx.x;  // B*8
  int b = blk >> 3, s = blk & 7;
  int t = threadIdx.x;
  const float* cb = coords + (size_t)b * 3 * Nn;
  const float invn = 1.0f / (float)Nn;
  float mx = csum[b * 4] * invn, my = csum[b * 4 + 1] * invn, mz = csum[b * 4 + 2] * invn;
  int n0 = s * 2048;
  float mq = 0.f;
  for (int n = n0 + t; n < n0 + 2048; n += 256) {
    float x = cb[n] - mx, y = cb[Nn + n] - my, z = cb[2 * Nn + n] - mz;
    mq = fmaxf(mq, x * x + y * y + z * z);
  }
  #pragma unroll
  for (int m = 1; m <= 32; m <<= 1) mq = fmaxf(mq, __shfl_xor(mq, m));
  __shared__ float rm[4];
  if ((t & 63) == 0) rm[t >> 6] = mq;
  __syncthreads();
  if (t == 0) {
    float v = fmaxf(fmaxf(rm[0], rm[1]), fmaxf(rm[2], rm[3]));
    atomicMax(cmax + b, __float_as_int(v));  // values >= 0 -> int-bits order ok
  }
}

// ---------------- coords stage 3: nc, voxel idx, histogram ----------------
__global__ void k_cfinal(const float* __restrict__ coords, const float* __restrict__ csum,
                         const int* __restrict__ cmax, float* __restrict__ nc,
                         int* __restrict__ vidx, int* __restrict__ hist) {
  int i = blockIdx.x * 256 + threadIdx.x;  // B*N
  int b = i >> 14, n = i & (Nn - 1);
  const float* cb = coords + (size_t)b * 3 * Nn;
  const float invn = 1.0f / (float)Nn;
  float mx = csum[b * 4] * invn, my = csum[b * 4 + 1] * invn, mz = csum[b * 4 + 2] * invn;
  float inv = 1.0f / (2.0f * sqrtf(__int_as_float(cmax[b])));
  float x = (cb[n] - mx) * inv + 0.5f;
  float y = (cb[Nn + n] - my) * inv + 0.5f;
  float z = (cb[2 * Nn + n] - mz) * inv + 0.5f;
  x = fminf(fmaxf(x * (float)Rn, 0.f), (float)(Rn - 1));
  y = fminf(fmaxf(y * (float)Rn, 0.f), (float)(Rn - 1));
  z = fminf(fmaxf(z * (float)Rn, 0.f), (float)(Rn - 1));
  float* ncb = nc + (size_t)b * 3 * Nn;
  ncb[n] = x; ncb[Nn + n] = y; ncb[2 * Nn + n] = z;
  int vx = (int)rintf(x), vy = (int)rintf(y), vz = (int)rintf(z);
  int v = (vx * Rn + vy) * Rn + vz;
  vidx[i] = v;
  atomicAdd(&hist[b * Vn + v], 1);
}

// ---------------- transpose features (B,C,N) f32 -> (B,N,C) f32 ----------------
__global__ void k_ftr(const float* __restrict__ feat, float* __restrict__ featT) {
  __shared__ float lds[32 * 65];
  int t = threadIdx.x;
  int blk = blockIdx.x;  // B * N/64
  int b = blk >> 8, tile = blk & 255;
  int n0 = tile * 64;
  for (int idx = t; idx < 2048; idx += 256) {
    int c = idx >> 6, nn = idx & 63;
    lds[c * 65 + nn] = feat[((size_t)b * 32 + c) * Nn + n0 + nn];
  }
  __syncthreads();
  for (int idx = t; idx < 2048; idx += 256) {
    int n = idx >> 5, c = idx & 31;
    featT[((size_t)b * Nn + n0 + n) * 32 + c] = lds[c * 65 + n];
  }
}

// ---------------- scan stage 1: per-1024-chunk exclusive prefix ----------------
__global__ void k_scan1(const int* __restrict__ hist, int* __restrict__ offs,
                        int* __restrict__ bsum) {
  __shared__ int sd[256];
  int t = threadIdx.x, blk = blockIdx.x;  // 256 blocks
  int4 h = reinterpret_cast<const int4*>(hist)[blk * 256 + t];
  int s = h.x + h.y + h.z + h.w;
  sd[t] = s; __syncthreads();
  for (int off = 1; off < 256; off <<= 1) {
    int add = (t >= off) ? sd[t - off] : 0;
    __syncthreads();
    sd[t] += add;
    __syncthreads();
  }
  int excl = sd[t] - s;
  int4 o;
  o.x = excl; o.y = excl + h.x; o.z = o.y + h.y; o.w = o.z + h.z;
  reinterpret_cast<int4*>(offs)[blk * 256 + t] = o;
  if (t == 0) bsum[blk] = sd[255];
}

// ---------------- scan stage 2: exclusive scan of 256 block sums ----------------
__global__ void k_scan2(const int* __restrict__ bsum, int* __restrict__ bbase) {
  __shared__ int sd[256];
  int t = threadIdx.x;
  int s = bsum[t];
  sd[t] = s; __syncthreads();
  for (int off = 1; off < 256; off <<= 1) {
    int add = (t >= off) ? sd[t - off] : 0;
    __syncthreads();
    sd[t] += add;
    __syncthreads();
  }
  bbase[t] = sd[t] - s;
}

// ---------------- cursor-scatter point indices into sorted order ----------------
__global__ void k_sortidx(const int* __restrict__ vidx, int* __restrict__ offs,
                          const int* __restrict__ bbase, int* __restrict__ pidx) {
  int i = blockIdx.x * 256 + threadIdx.x;  // B*N
  int b = i >> 14, n = i & (Nn - 1);
  int g = b * Vn + vidx[i];
  int p = atomicAdd(&offs[g], 1) + bbase[g >> 10];
  pidx[p] = n;
}

// ---------------- per-voxel average -> bf16 channel-last vox0 ----------------
__global__ void k_voxavg(const int* __restrict__ hist, const int* __restrict__ offs,
                         const int* __restrict__ bbase, const int* __restrict__ pidx,
                         const float* __restrict__ featT, uint2* __restrict__ vox0) {
  int t = threadIdx.x;
  int wv = blockIdx.x * 4 + (t >> 6);  // global voxel id, B*V total
  int lane = t & 63;
  int c4 = lane & 7, j = lane >> 3;
  int b = wv >> 15;
  int cnt = hist[wv];
  float ax = 0.f, ay = 0.f, az = 0.f, aw = 0.f;
  if (cnt > 0) {
    int end = offs[wv] + bbase[wv >> 10];  // offs is post-scatter cursor = local end
    int start = end - cnt;
    const float4* ft = reinterpret_cast<const float4*>(featT) + (size_t)b * Nn * 8;
    for (int k = start + j; k < end; k += 8) {
      int n = pidx[k];
      float4 v = ft[n * 8 + c4];
      ax += v.x; ay += v.y; az += v.z; aw += v.w;
    }
    #pragma unroll
    for (int m = 8; m <= 32; m <<= 1) {
      ax += __shfl_xor(ax, m); ay += __shfl_xor(ay, m);
      az += __shfl_xor(az, m); aw += __shfl_xor(aw, m);
    }
    float invc = 1.0f / (float)cnt;
    ax *= invc; ay *= invc; az *= invc; aw *= invc;
  }
  if (j == 0) {
    uint2 o;
    o.x = pack2(ax, ay);
    o.y = pack2(az, aw);
    vox0[(size_t)wv * 8 + c4] = o;
  }
}

// -------- weight permute for 32x32x16 A-frag: w[co][ci][k] -> wt[k][h][lane][e] ----
// lane l holds A row co=l&31, k-half elems ci = h*16 + (l>>5)*8 + e.
__global__ void k_twz(const float* __restrict__ w, u16* __restrict__ wt) {
  int i = blockIdx.x * 256 + threadIdx.x;
  if (i >= 27 * 32 * 32) return;
  int e = i & 7, l = (i >> 3) & 63, h = (i >> 9) & 1, k = i >> 10;
  int co = l & 31, ci = h * 16 + ((l >> 5) << 3) + e;
  wt[i] = f2bf(w[(co * 32 + ci) * 27 + k]);
}

// ---------------- modulation vectors m = silu(cond) @ mw.T + mb ----------------
__global__ void k_mods(const float* __restrict__ cond,
                       const float* __restrict__ w1, const float* __restrict__ b1,
                       const float* __restrict__ w2, const float* __restrict__ b2,
                       const float* __restrict__ wp, const float* __restrict__ bp,
                       float* __restrict__ m1, float* __restrict__ m2,
                       float* __restrict__ mp) {
  __shared__ float sc[2048];
  int t = threadIdx.x;
  for (int i = t; i < 2048; i += 256) sc[i] = siluf(cond[i]);
  __syncthreads();
  for (int o = t; o < 1536; o += 256) {
    int mat = o / 512, rem = o - mat * 512;
    int b = rem >> 6, oo = rem & 63;
    const float* w = (mat == 0) ? w1 : ((mat == 1) ? w2 : wp);
    const float* bb = (mat == 0) ? b1 : ((mat == 1) ? b2 : bp);
    float acc = bb[oo];
    const float* wrow = w + oo * 256;
    const float* scb = sc + b * 256;
    for (int k = 0; k < 256; ++k) acc += wrow[k] * scb[k];
    float* dst = (mat == 0) ? m1 : ((mat == 1) ? m2 : mp);
    dst[b * 64 + oo] = acc;
  }
}

// ---------------- 3x3x3 conv as implicit GEMM on bf16 MFMA 32x32x16 ----------------
// Block = (b, x, 8-y strip). 8 waves, wave = one y; acc = full 32z x 32co tile.
// W LDS: [k27][h2][lane64] 16B chunks -> A-read = base + lane*16B (linear).
// X LDS: [col30][c4 4][r34] 16B chunks -> B-read = 32 consecutive chunks per half-wave.
__global__ __launch_bounds__(512, 2) void k_conv(
    const u16* __restrict__ in, const u16* __restrict__ wt,
    const float* __restrict__ bias, u16* __restrict__ out) {
  __shared__ uint4 lds_w4[3456];   // 55296 B
  __shared__ uint4 lds_x4[4096];   // 65536 B (4080 used)
  int t = threadIdx.x;
  int blk = blockIdx.x;
  int yp = blk & 3, x = (blk >> 2) & 31, b = blk >> 7;
  int y0 = yp * 8;
  size_t bbase = (size_t)b * Vn;

  const uint4* gw = reinterpret_cast<const uint4*>(wt);
  for (int i = t; i < 3456; i += 512) lds_w4[i] = gw[i];

  for (int i = t; i < 4080; i += 512) {
    int col = i / 136, rem = i - col * 136;
    int c4 = rem / 34, r = rem - c4 * 34;
    int dxp = col / 10, yy = col - dxp * 10;
    int gx = x + dxp - 1, gy = y0 + yy - 1, z = r - 1;
    uint4 val = make_uint4(0u, 0u, 0u, 0u);
    if (gx >= 0 && gx < 32 && (unsigned)gy < 32u && (unsigned)z < 32u) {
      val = *reinterpret_cast<const uint4*>(
          in + (bbase + (size_t)((gx * 32 + gy) * 32 + z)) * 32 + c4 * 8);
    }
    lds_x4[i] = val;
  }
  __syncthreads();

  int w = t >> 6, lane = t & 63;
  int zc = lane & 31, hi = lane >> 5;
  int y = y0 + w;

  f32x16 acc;
  #pragma unroll
  for (int q = 0; q < 4; ++q) {
    float4 bq = *reinterpret_cast<const float4*>(bias + q * 8 + hi * 4);
    acc[q * 4 + 0] = bq.x; acc[q * 4 + 1] = bq.y;
    acc[q * 4 + 2] = bq.z; acc[q * 4 + 3] = bq.w;
  }

  const u16* lw = reinterpret_cast<const u16*>(lds_w4);
  const u16* lx = reinterpret_cast<const u16*>(lds_x4);

  #pragma unroll
  for (int dxp = 0; dxp < 3; ++dxp) {
    #pragma unroll
    for (int dyp = 0; dyp < 3; ++dyp) {
      int col = dxp * 10 + w + dyp;
      #pragma unroll
      for (int dzp = 0; dzp < 3; ++dzp) {
        int k = (dxp * 3 + dyp) * 3 + dzp;
        short8v a0 = *reinterpret_cast<const short8v*>(lw + ((k * 2 + 0) * 64 + lane) * 8);
        short8v a1 = *reinterpret_cast<const short8v*>(lw + ((k * 2 + 1) * 64 + lane) * 8);
        short8v b0 = *reinterpret_cast<const short8v*>(
            lx + ((col * 4 + hi) * 34 + zc + dzp) * 8);
        short8v b1 = *reinterpret_cast<const short8v*>(
            lx + ((col * 4 + 2 + hi) * 34 + zc + dzp) * 8);
        acc = __builtin_amdgcn_mfma_f32_32x32x16_bf16(a0, b0, acc, 0, 0, 0);
        acc = __builtin_amdgcn_mfma_f32_32x32x16_bf16(a1, b1, acc, 0, 0, 0);
      }
    }
  }

  // C/D: col(z)=lane&31, row(co)=(reg&3)+8*(reg>>2)+4*(lane>>5)
  size_t off = (bbase + (size_t)((x * 32 + y) * 32 + zc)) * 32;
  #pragma unroll
  for (int q = 0; q < 4; ++q) {
    uint2 o;
    o.x = pack2(acc[q * 4 + 0], acc[q * 4 + 1]);
    o.y = pack2(acc[q * 4 + 2], acc[q * 4 + 3]);
    *reinterpret_cast<uint2*>(out + off + q * 8 + hi * 4) = o;
  }
}

// ---------------- elementwise affine+silu on vox (in place) ----------------
__global__ void k_affsilu(uint4* __restrict__ x, const float* __restrict__ Ac,
                          const float* __restrict__ Bc) {
  int i = blockIdx.x * 256 + threadIdx.x;  // B*V*4 uint4s
  int c4 = i & 3, b = i >> 17;
  uint4 v = x[i];
  float f[8];
  unpack8(v, f);
  float4 A0 = reinterpret_cast<const float4*>(Ac)[b * 8 + c4 * 2];
  float4 A1 = reinterpret_cast<const float4*>(Ac)[b * 8 + c4 * 2 + 1];
  float4 B0 = reinterpret_cast<const float4*>(Bc)[b * 8 + c4 * 2];
  float4 B1 = reinterpret_cast<const float4*>(Bc)[b * 8 + c4 * 2 + 1];
  f[0] = siluf(f[0] * A0.x + B0.x); f[1] = siluf(f[1] * A0.y + B0.y);
  f[2] = siluf(f[2] * A0.z + B0.z); f[3] = siluf(f[3] * A0.w + B0.w);
  f[4] = siluf(f[4] * A1.x + B1.x); f[5] = siluf(f[5] * A1.y + B1.y);
  f[6] = siluf(f[6] * A1.z + B1.z); f[7] = siluf(f[7] * A1.w + B1.w);
  uint4 o;
  o.x = pack2(f[0], f[1]); o.y = pack2(f[2], f[3]);
  o.z = pack2(f[4], f[5]); o.w = pack2(f[6], f[7]);
  x[i] = o;
}

// ---------------- per-channel sum/sumsq, block-reduced (few atomics) ----------------
__global__ void k_stats_cl(const u16* __restrict__ x, float* __restrict__ psum,
                           float* __restrict__ psq) {
  int blk = blockIdx.x;  // 256 = B * 32 segments
  int b = blk >> 5, seg = blk & 31;
  int t = threadIdx.x;
  int c8 = t & 3, vsub = t >> 2;  // vsub 0..63 across block (16 per wave)
  float s[8], q[8];
  #pragma unroll
  for (int j = 0; j < 8; ++j) { s[j] = 0.f; q[j] = 0.f; }
  const uint4* xb = reinterpret_cast<const uint4*>(x + (size_t)b * Vn * Cn) +
                    (size_t)seg * 4096;
  for (int it = 0; it < 16; ++it) {
    int v = it * 64 + vsub;
    uint4 u = xb[v * 4 + c8];
    float f[8];
    unpack8(u, f);
    #pragma unroll
    for (int j = 0; j < 8; ++j) { s[j] += f[j]; q[j] += f[j] * f[j]; }
  }
  #pragma unroll
  for (int m = 4; m <= 32; m <<= 1) {
    #pragma unroll
    for (int j = 0; j < 8; ++j) {
      s[j] += __shfl_xor(s[j], m);
      q[j] += __shfl_xor(q[j], m);
    }
  }
  __shared__ float ls[2][4][4][8];  // [sum|sq][wave][c8][j]
  int wv = t >> 6;
  if ((t & 63) < 4) {
    #pragma unroll
    for (int j = 0; j < 8; ++j) { ls[0][wv][c8][j] = s[j]; ls[1][wv][c8][j] = q[j]; }
  }
  __syncthreads();
  if (t < 64) {
    int arr = t >> 5, c = t & 31;
    float v = ls[arr][0][c >> 3][c & 7] + ls[arr][1][c >> 3][c & 7] +
              ls[arr][2][c >> 3][c & 7] + ls[arr][3][c >> 3][c & 7];
    atomicAdd((arr == 0 ? psum : psq) + b * 32 + c, v);
  }
}

// ---------------- AdaGN affine coefficients (stage 1) ----------------
__global__ void k_coef1(const float* __restrict__ psum, const float* __restrict__ psq,
                        const float* __restrict__ mod, const float* __restrict__ g,
                        const float* __restrict__ bgn, float* __restrict__ A,
                        float* __restrict__ Bc) {
  int t = threadIdx.x;  // 256 = B*C
  int b = t >> 5, c = t & 31, grp = c >> 2;
  float s = 0, q = 0;
  for (int j = 0; j < 4; ++j) {
    s += psum[b * 32 + grp * 4 + j];
    q += psq[b * 32 + grp * 4 + j];
  }
  const float cntf = 4.0f * (float)Vn;
  float mean = s / cntf;
  float var = q / cntf - mean * mean;
  float rstd = rsqrtf(var + 1e-5f);
  float scale = mod[b * 64 + c], shift = mod[b * 64 + 32 + c];
  A[t] = rstd * g[c] * scale;
  Bc[t] = (bgn[c] - mean * rstd * g[c]) * scale + shift;
}

// ---------------- AdaGN stage 2 + SE -> final gather affine S,T ----------------
__global__ void k_coef2(const float* __restrict__ psum, const float* __restrict__ psq,
                        const float* __restrict__ mod, const float* __restrict__ g,
                        const float* __restrict__ bgn, const float* __restrict__ sw1,
                        const float* __restrict__ sw2, float* __restrict__ S,
                        float* __restrict__ T) {
  __shared__ float zm[8][32];
  __shared__ float hh[8][4];
  int t = threadIdx.x;  // 256 = B*C
  int b = t >> 5, c = t & 31, grp = c >> 2;
  float s = 0, q = 0;
  for (int j = 0; j < 4; ++j) {
    s += psum[b * 32 + grp * 4 + j];
    q += psq[b * 32 + grp * 4 + j];
  }
  const float cntf = 4.0f * (float)Vn;
  float mean = s / cntf;
  float var = q / cntf - mean * mean;
  float rstd = rsqrtf(var + 1e-5f);
  float scale = mod[b * 64 + c], shift = mod[b * 64 + 32 + c];
  float A = rstd * g[c] * scale;
  float Bv = (bgn[c] - mean * rstd * g[c]) * scale + shift;
  float chmean = psum[b * 32 + c] / (float)Vn;
  zm[b][c] = A * chmean + Bv;
  __syncthreads();
  if (t < 32) {
    int b2 = t >> 2, j = t & 3;
    float h = 0;
    for (int cc = 0; cc < 32; ++cc) h += sw1[j * 32 + cc] * zm[b2][cc];
    hh[b2][j] = fmaxf(h, 0.f);
  }
  __syncthreads();
  float sig = 0;
  for (int j = 0; j < 4; ++j) sig += sw2[c * 4 + j] * hh[b][j];
  sig = 1.0f / (1.0f + __expf(-sig));
  S[t] = A * sig;
  T[t] = Bv * sig;
}

// ---------------- trilinear devoxelize (bf16 vox) with fused affine ----------------
__global__ void k_devox(const u16* __restrict__ vox, const float* __restrict__ nc,
                        const float* __restrict__ S, const float* __restrict__ T,
                        float* __restrict__ out) {
  int i = blockIdx.x * 256 + threadIdx.x;  // B*N
  int b = i >> 14, n = i & (Nn - 1);
  const float* ncb = nc + (size_t)b * 3 * Nn;
  float fx = ncb[n], fy = ncb[Nn + n], fz = ncb[2 * Nn + n];
  float lxf = floorf(fx), lyf = floorf(fy), lzf = floorf(fz);
  float wx1 = fx - lxf, wy1 = fy - lyf, wz1 = fz - lzf;
  int lx = (int)lxf, ly = (int)lyf, lz = (int)lzf;
  int hx = min(lx + 1, 31), hy = min(ly + 1, 31), hz = min(lz + 1, 31);
  float a[32];
  #pragma unroll
  for (int c = 0; c < 32; ++c) a[c] = 0.f;
  for (int corner = 0; corner < 8; ++corner) {
    int cx = (corner & 4) ? hx : lx;
    int cy = (corner & 2) ? hy : ly;
    int cz = (corner & 1) ? hz : lz;
    float ww = ((corner & 4) ? wx1 : 1.f - wx1) *
               ((corner & 2) ? wy1 : 1.f - wy1) *
               ((corner & 1) ? wz1 : 1.f - wz1);
    const uint4* p = reinterpret_cast<const uint4*>(
        vox + ((size_t)b * Vn + (size_t)((cx * 32 + cy) * 32 + cz)) * 32);
    #pragma unroll
    for (int qq = 0; qq < 4; ++qq) {
      float f[8];
      unpack8(p[qq], f);
      #pragma unroll
      for (int j = 0; j < 8; ++j) a[qq * 8 + j] += ww * f[j];
    }
  }
  float* o = out + (size_t)b * 32 * Nn + n;
  #pragma unroll
  for (int c = 0; c < 32; ++c) {
    o[(size_t)c * Nn] = a[c] * S[b * 32 + c] + T[b * 32 + c];
  }
}

// ---------------- point branch: 1x1 conv (32x32 GEMM per point) ----------------
__global__ void k_pxlin(const float* __restrict__ feat, const float* __restrict__ w,
                        const float* __restrict__ bias, float* __restrict__ px) {
  __shared__ float lw[1024];
  __shared__ float lb[32];
  int t = threadIdx.x;
  for (int i = t; i < 1024; i += 256) lw[i] = w[i];
  if (t < 32) lb[t] = bias[t];
  __syncthreads();
  int blk = blockIdx.x;  // B*64
  int b = blk >> 6, tile = blk & 63;
  int n = tile * 256 + t;
  float fr[32];
  const float* fb = feat + (size_t)b * 32 * Nn + n;
  #pragma unroll
  for (int ci = 0; ci < 32; ++ci) fr[ci] = fb[(size_t)ci * Nn];
  float* ob = px + (size_t)b * 32 * Nn + n;
  for (int co = 0; co < 32; ++co) {
    float acc = lb[co];
    #pragma unroll
    for (int ci = 0; ci < 32; ++ci) acc += lw[co * 32 + ci] * fr[ci];
    ob[(size_t)co * Nn] = acc;
  }
}

// ---------------- point-branch group partial stats (few atomics) ----------------
__global__ void k_statsp(const float* __restrict__ px, float* __restrict__ pgsum,
                         float* __restrict__ pgsq) {
  int blk = blockIdx.x;  // 256 = B * G * 4 quarters
  int b = blk >> 5, g = (blk >> 2) & 7, qr = blk & 3;
  const float4* base = reinterpret_cast<const float4*>(
      px + (size_t)b * 32 * Nn + (size_t)g * 4 * Nn) + qr * 4096;
  float s = 0, q = 0;
  int t = threadIdx.x;
  for (int i = t; i < 4096; i += 256) {
    float4 v = base[i];
    s += v.x + v.y + v.z + v.w;
    q += v.x * v.x + v.y * v.y + v.z * v.z + v.w * v.w;
  }
  #pragma unroll
  for (int m = 1; m <= 32; m <<= 1) {
    s += __shfl_xor(s, m);
    q += __shfl_xor(q, m);
  }
  __shared__ float rs[4], rq[4];
  if ((t & 63) == 0) { rs[t >> 6] = s; rq[t >> 6] = q; }
  __syncthreads();
  if (t == 0) {
    atomicAdd(&pgsum[b * 8 + g], rs[0] + rs[1] + rs[2] + rs[3]);
    atomicAdd(&pgsq[b * 8 + g], rq[0] + rq[1] + rq[2] + rq[3]);
  }
}

// ---------------- point-branch affine coefficients ----------------
__global__ void k_coefp(const float* __restrict__ pgsum, const float* __restrict__ pgsq,
                        const float* __restrict__ mod, const float* __restrict__ g,
                        const float* __restrict__ bgn, float* __restrict__ A,
                        float* __restrict__ Bc) {
  int t = threadIdx.x;  // 256
  int b = t >> 5, c = t & 31, grp = c >> 2;
  float m = pgsum[b * 8 + grp] / 65536.f;
  float var = pgsq[b * 8 + grp] / 65536.f - m * m;
  float r = rsqrtf(var + 1e-5f);
  float scale = mod[b * 64 + c], shift = mod[b * 64 + 32 + c];
  A[t] = r * g[c] * scale;
  Bc[t] = (bgn[c] - m * r * g[c]) * scale + shift;
}

// ---------------- final: out += silu(px*A+B) ----------------
__global__ void k_final(const float* __restrict__ px, const float* __restrict__ A,
                        const float* __restrict__ Bc, float* __restrict__ out) {
  int i = blockIdx.x * 256 + threadIdx.x;  // B*C*N
  int bc = i >> 14;
  float y = px[i] * A[bc] + Bc[bc];
  out[i] += siluf(y);
}

}  // namespace

extern "C" void kernel_launch(void* const* d_in, const int* in_sizes, int n_in,
                              void* d_out, int out_size, void* d_ws, size_t ws_size,
                              hipStream_t stream) {
  (void)in_sizes; (void)n_in; (void)out_size; (void)ws_size;
  const float* features = (const float*)d_in[0];
  const float* coords = (const float*)d_in[1];
  const float* condition = (const float*)d_in[2];
  const float* conv1_w = (const float*)d_in[3];
  const float* conv1_b = (const float*)d_in[4];
  const float* gn1_g = (const float*)d_in[5];
  const float* gn1_b = (const float*)d_in[6];
  const float* mod1_w = (const float*)d_in[7];
  const float* mod1_b = (const float*)d_in[8];
  const float* conv2_w = (const float*)d_in[9];
  const float* conv2_b = (const float*)d_in[10];
  const float* gn2_g = (const float*)d_in[11];
  const float* gn2_b = (const float*)d_in[12];
  const float* mod2_w = (const float*)d_in[13];
  const float* mod2_b = (const float*)d_in[14];
  const float* se_w1 = (const float*)d_in[15];
  const float* se_w2 = (const float*)d_in[16];
  const float* pc_w = (const float*)d_in[17];
  const float* pc_b = (const float*)d_in[18];
  const float* gnp_g = (const float*)d_in[19];
  const float* gnp_b = (const float*)d_in[20];
  const float* modp_w = (const float*)d_in[21];
  const float* modp_b = (const float*)d_in[22];

  char* w = (char*)d_ws;
  // R0 (33.5 MB): [first half] featT f32 (until voxavg) -> vox1 bf16 (conv1 out,
  //               dead after conv2) -> px f32 (pxlin..final). [second half] vox2.
  float* featT = (float*)w;
  u16* vox1 = (u16*)w;
  float* px = (float*)w;
  u16* vox2 = (u16*)(w + 16777216);
  w += 33554432;
  // R1 (16.8 MB): vox0 bf16 (voxavg -> conv1)
  u16* vox0 = (u16*)w; w += 16777216;
  int* hist = (int*)w;  w += 1048576;   // hist..cmax share one memset block
  float* psum1 = (float*)w; w += 1024;
  float* psq1 = (float*)w;  w += 1024;
  float* psum2 = (float*)w; w += 1024;
  float* psq2 = (float*)w;  w += 1024;
  float* pgsum = (float*)w; w += 256;
  float* pgsq = (float*)w;  w += 256;
  float* csum = (float*)w;  w += 128;
  int* cmax = (int*)w;      w += 64;
  int* offs = (int*)w;  w += 1048576;
  int* bsum = (int*)w;  w += 1024;
  int* bbase = (int*)w; w += 1024;
  int* pidx = (int*)w;  w += 524288;
  float* ncb = (float*)w;   w += 1572864;
  int* vidx = (int*)w;      w += 524288;
  u16* wt1b = (u16*)w;      w += 55296;
  u16* wt2b = (u16*)w;      w += 55296;
  float* m1 = (float*)w;    w += 2048;
  float* m2 = (float*)w;    w += 2048;
  float* mp = (float*)w;    w += 2048;
  float* A1 = (float*)w;    w += 1024;
  float* B1 = (float*)w;    w += 1024;
  float* Sc = (float*)w;    w += 1024;
  float* Tc = (float*)w;    w += 1024;
  float* Ap = (float*)w;    w += 1024;
  float* Bp = (float*)w;    w += 1024;
  float* out = (float*)d_out;

  hipMemsetAsync(hist, 0, 1048576 + 4096 + 512 + 192, stream);

  k_cpart1<<<Bn * 8, 256, 0, stream>>>(coords, csum);
  k_ftr<<<Bn * 256, 256, 0, stream>>>(features, featT);
  k_twz<<<108, 256, 0, stream>>>(conv1_w, wt1b);
  k_twz<<<108, 256, 0, stream>>>(conv2_w, wt2b);
  k_mods<<<1, 256, 0, stream>>>(condition, mod1_w, mod1_b, mod2_w, mod2_b,
                                modp_w, modp_b, m1, m2, mp);
  k_cpart2<<<Bn * 8, 256, 0, stream>>>(coords, csum, cmax);
  k_cfinal<<<(Bn * Nn) / 256, 256, 0, stream>>>(coords, csum, cmax, ncb, vidx, hist);
  k_scan1<<<256, 256, 0, stream>>>(hist, offs, bsum);
  k_scan2<<<1, 256, 0, stream>>>(bsum, bbase);
  k_sortidx<<<(Bn * Nn) / 256, 256, 0, stream>>>(vidx, offs, bbase, pidx);
  k_voxavg<<<(Bn * Vn) / 4, 256, 0, stream>>>(hist, offs, bbase, pidx, featT,
                                              (uint2*)vox0);
  k_conv<<<1024, 512, 0, stream>>>(vox0, wt1b, conv1_b, vox1);
  k_stats_cl<<<256, 256, 0, stream>>>(vox1, psum1, psq1);
  k_coef1<<<1, 256, 0, stream>>>(psum1, psq1, m1, gn1_g, gn1_b, A1, B1);
  k_affsilu<<<4096, 256, 0, stream>>>((uint4*)vox1, A1, B1);
  k_conv<<<1024, 512, 0, stream>>>(vox1, wt2b, conv2_b, vox2);
  k_stats_cl<<<256, 256, 0, stream>>>(vox2, psum2, psq2);
  k_coef2<<<1, 256, 0, stream>>>(psum2, psq2, m2, gn2_g, gn2_b, se_w1, se_w2, Sc, Tc);
  k_devox<<<(Bn * Nn) / 256, 256, 0, stream>>>(vox2, ncb, Sc, Tc, out);
  k_pxlin<<<Bn * 64, 256, 0, stream>>>(features, pc_w, pc_b, px);
  k_statsp<<<256, 256, 0, stream>>>(px, pgsum, pgsq);
  k_coefp<<<1, 256, 0, stream>>>(pgsum, pgsq, mp, gnp_g, gnp_b, Ap, Bp);
  k_final<<<(Bn * Cn * Nn) / 256, 256, 0, stream>>>(px, Ap, Bp, out);
}

// Round 7
// 234.880 us; speedup vs baseline: 39.3590x; 1.1552x over previous
//
#include <hip/hip_runtime.h>
#include <math.h>

#define DEV_INLINE __device__ __forceinline__

namespace {

typedef unsigned short u16;
typedef unsigned int u32;
typedef __attribute__((ext_vector_type(8))) short short8v;
typedef __attribute__((ext_vector_type(4))) float f32x4;
typedef __attribute__((ext_vector_type(16))) float f32x16;

constexpr int Bn = 8, Cn = 32, Nn = 16384, Rn = 32, Vn = Rn * Rn * Rn;

DEV_INLINE float siluf(float x) { return x / (1.0f + __expf(-x)); }
DEV_INLINE float bf2f(u16 u) { union { u32 i; float f; } x; x.i = (u32)u << 16; return x.f; }
DEV_INLINE u16 f2bf(float f) {
  union { float f; u32 i; } x; x.f = f;
  return (u16)((x.i + 0x7FFFu + ((x.i >> 16) & 1u)) >> 16);
}
DEV_INLINE u32 pack2(float a, float b) { return (u32)f2bf(a) | ((u32)f2bf(b) << 16); }
DEV_INLINE void unpack8(uint4 u, float* f) {
  f[0] = bf2f(u.x & 0xffff); f[1] = bf2f(u.x >> 16);
  f[2] = bf2f(u.y & 0xffff); f[3] = bf2f(u.y >> 16);
  f[4] = bf2f(u.z & 0xffff); f[5] = bf2f(u.z >> 16);
  f[6] = bf2f(u.w & 0xffff); f[7] = bf2f(u.w >> 16);
}

// ---------------- coords stage 1: partial xyz sums ----------------
__global__ void k_cpart1(const float* __restrict__ coords, float* __restrict__ csum) {
  int blk = blockIdx.x;  // B*8
  int b = blk >> 3, s = blk & 7;
  int t = threadIdx.x;
  const float* cb = coords + (size_t)b * 3 * Nn;
  int n0 = s * 2048;
  float sx = 0.f, sy = 0.f, sz = 0.f;
  for (int n = n0 + t; n < n0 + 2048; n += 256) {
    sx += cb[n]; sy += cb[Nn + n]; sz += cb[2 * Nn + n];
  }
  #pragma unroll
  for (int m = 1; m <= 32; m <<= 1) {
    sx += __shfl_xor(sx, m); sy += __shfl_xor(sy, m); sz += __shfl_xor(sz, m);
  }
  __shared__ float rs[3][4];
  if ((t & 63) == 0) { rs[0][t >> 6] = sx; rs[1][t >> 6] = sy; rs[2][t >> 6] = sz; }
  __syncthreads();
  if (t < 3) atomicAdd(&csum[b * 4 + t], rs[t][0] + rs[t][1] + rs[t][2] + rs[t][3]);
}

// ---------------- coords stage 2: partial max of squared norm ----------------
__global__ void k_cpart2(const float* __restrict__ coords, const float* __restrict__ csum,
                         int* __restrict__ cmax) {
  int blk = blockIdx.x;  // B*8
  int b = blk >> 3, s = blk & 7;
  int t = threadIdx.x;
  const float* cb = coords + (size_t)b * 3 * Nn;
  const float invn = 1.0f / (float)Nn;
  float mx = csum[b * 4] * invn, my = csum[b * 4 + 1] * invn, mz = csum[b * 4 + 2] * invn;
  int n0 = s * 2048;
  float mq = 0.f;
  for (int n = n0 + t; n < n0 + 2048; n += 256) {
    float x = cb[n] - mx, y = cb[Nn + n] - my, z = cb[2 * Nn + n] - mz;
    mq = fmaxf(mq, x * x + y * y + z * z);
  }
  #pragma unroll
  for (int m = 1; m <= 32; m <<= 1) mq = fmaxf(mq, __shfl_xor(mq, m));
  __shared__ float rm[4];
  if ((t & 63) == 0) rm[t >> 6] = mq;
  __syncthreads();
  if (t == 0) {
    float v = fmaxf(fmaxf(rm[0], rm[1]), fmaxf(rm[2], rm[3]));
    atomicMax(cmax + b, __float_as_int(v));  // values >= 0 -> int-bits order ok
  }
}

// ---------------- coords stage 3: nc, voxel idx, histogram ----------------
__global__ void k_cfinal(const float* __restrict__ coords, const float* __restrict__ csum,
                         const int* __restrict__ cmax, float* __restrict__ nc,
                         int* __restrict__ vidx, int* __restrict__ hist) {
  int i = blockIdx.x * 256 + threadIdx.x;  // B*N
  int b = i >> 14, n = i & (Nn - 1);
  const float* cb = coords + (size_t)b * 3 * Nn;
  const float invn = 1.0f / (float)Nn;
  float mx = csum[b * 4] * invn, my = csum[b * 4 + 1] * invn, mz = csum[b * 4 + 2] * invn;
  float inv = 1.0f / (2.0f * sqrtf(__int_as_float(cmax[b])));
  float x = (cb[n] - mx) * inv + 0.5f;
  float y = (cb[Nn + n] - my) * inv + 0.5f;
  float z = (cb[2 * Nn + n] - mz) * inv + 0.5f;
  x = fminf(fmaxf(x * (float)Rn, 0.f), (float)(Rn - 1));
  y = fminf(fmaxf(y * (float)Rn, 0.f), (float)(Rn - 1));
  z = fminf(fmaxf(z * (float)Rn, 0.f), (float)(Rn - 1));
  float* ncb = nc + (size_t)b * 3 * Nn;
  ncb[n] = x; ncb[Nn + n] = y; ncb[2 * Nn + n] = z;
  int vx = (int)rintf(x), vy = (int)rintf(y), vz = (int)rintf(z);
  int v = (vx * Rn + vy) * Rn + vz;
  vidx[i] = v;
  atomicAdd(&hist[b * Vn + v], 1);
}

// ---------------- transpose features (B,C,N) f32 -> (B,N,C) f32 ----------------
__global__ void k_ftr(const float* __restrict__ feat, float* __restrict__ featT) {
  __shared__ float lds[32 * 65];
  int t = threadIdx.x;
  int blk = blockIdx.x;  // B * N/64
  int b = blk >> 8, tile = blk & 255;
  int n0 = tile * 64;
  for (int idx = t; idx < 2048; idx += 256) {
    int c = idx >> 6, nn = idx & 63;
    lds[c * 65 + nn] = feat[((size_t)b * 32 + c) * Nn + n0 + nn];
  }
  __syncthreads();
  for (int idx = t; idx < 2048; idx += 256) {
    int n = idx >> 5, c = idx & 31;
    featT[((size_t)b * Nn + n0 + n) * 32 + c] = lds[c * 65 + n];
  }
}

// ---------------- scan stage 1: per-1024-chunk exclusive prefix ----------------
__global__ void k_scan1(const int* __restrict__ hist, int* __restrict__ offs,
                        int* __restrict__ bsum) {
  __shared__ int sd[256];
  int t = threadIdx.x, blk = blockIdx.x;  // 256 blocks
  int4 h = reinterpret_cast<const int4*>(hist)[blk * 256 + t];
  int s = h.x + h.y + h.z + h.w;
  sd[t] = s; __syncthreads();
  for (int off = 1; off < 256; off <<= 1) {
    int add = (t >= off) ? sd[t - off] : 0;
    __syncthreads();
    sd[t] += add;
    __syncthreads();
  }
  int excl = sd[t] - s;
  int4 o;
  o.x = excl; o.y = excl + h.x; o.z = o.y + h.y; o.w = o.z + h.z;
  reinterpret_cast<int4*>(offs)[blk * 256 + t] = o;
  if (t == 0) bsum[blk] = sd[255];
}

// ---------------- scan stage 2: exclusive scan of 256 block sums ----------------
__global__ void k_scan2(const int* __restrict__ bsum, int* __restrict__ bbase) {
  __shared__ int sd[256];
  int t = threadIdx.x;
  int s = bsum[t];
  sd[t] = s; __syncthreads();
  for (int off = 1; off < 256; off <<= 1) {
    int add = (t >= off) ? sd[t - off] : 0;
    __syncthreads();
    sd[t] += add;
    __syncthreads();
  }
  bbase[t] = sd[t] - s;
}

// ---------------- cursor-scatter point indices into sorted order ----------------
__global__ void k_sortidx(const int* __restrict__ vidx, int* __restrict__ offs,
                          const int* __restrict__ bbase, int* __restrict__ pidx) {
  int i = blockIdx.x * 256 + threadIdx.x;  // B*N
  int b = i >> 14, n = i & (Nn - 1);
  int g = b * Vn + vidx[i];
  int p = atomicAdd(&offs[g], 1) + bbase[g >> 10];
  pidx[p] = n;
}

// ---------------- per-voxel average -> bf16 channel-last vox0 ----------------
__global__ void k_voxavg(const int* __restrict__ hist, const int* __restrict__ offs,
                         const int* __restrict__ bbase, const int* __restrict__ pidx,
                         const float* __restrict__ featT, uint2* __restrict__ vox0) {
  int t = threadIdx.x;
  int wv = blockIdx.x * 4 + (t >> 6);  // global voxel id, B*V total
  int lane = t & 63;
  int c4 = lane & 7, j = lane >> 3;
  int b = wv >> 15;
  int cnt = hist[wv];
  float ax = 0.f, ay = 0.f, az = 0.f, aw = 0.f;
  if (cnt > 0) {
    int end = offs[wv] + bbase[wv >> 10];  // offs is post-scatter cursor = local end
    int start = end - cnt;
    const float4* ft = reinterpret_cast<const float4*>(featT) + (size_t)b * Nn * 8;
    for (int k = start + j; k < end; k += 8) {
      int n = pidx[k];
      float4 v = ft[n * 8 + c4];
      ax += v.x; ay += v.y; az += v.z; aw += v.w;
    }
    #pragma unroll
    for (int m = 8; m <= 32; m <<= 1) {
      ax += __shfl_xor(ax, m); ay += __shfl_xor(ay, m);
      az += __shfl_xor(az, m); aw += __shfl_xor(aw, m);
    }
    float invc = 1.0f / (float)cnt;
    ax *= invc; ay *= invc; az *= invc; aw *= invc;
  }
  if (j == 0) {
    uint2 o;
    o.x = pack2(ax, ay);
    o.y = pack2(az, aw);
    vox0[(size_t)wv * 8 + c4] = o;
  }
}

// -------- weight permute for 32x32x16 A-frag: w[co][ci][k] -> wt[k][h][lane][e] ----
// lane l holds A row co=l&31, k-half elems ci = h*16 + (l>>5)*8 + e.
__global__ void k_twz(const float* __restrict__ w, u16* __restrict__ wt) {
  int i = blockIdx.x * 256 + threadIdx.x;
  if (i >= 27 * 32 * 32) return;
  int e = i & 7, l = (i >> 3) & 63, h = (i >> 9) & 1, k = i >> 10;
  int co = l & 31, ci = h * 16 + ((l >> 5) << 3) + e;
  wt[i] = f2bf(w[(co * 32 + ci) * 27 + k]);
}

// ------- modulation vectors m = silu(cond) @ mw.T + mb (wave-per-row, coalesced) ----
__global__ void k_mods(const float* __restrict__ cond,
                       const float* __restrict__ w1, const float* __restrict__ b1,
                       const float* __restrict__ w2, const float* __restrict__ b2,
                       const float* __restrict__ wp, const float* __restrict__ bp,
                       float* __restrict__ m1, float* __restrict__ m2,
                       float* __restrict__ mp) {
  int blk = blockIdx.x;  // 24 = mat*8 + b
  int mat = blk >> 3, b = blk & 7;
  int t = threadIdx.x;  // 256
  __shared__ float sc[256];
  sc[t] = siluf(cond[b * 256 + t]);
  __syncthreads();
  const float* w = (mat == 0) ? w1 : ((mat == 1) ? w2 : wp);
  const float* bb = (mat == 0) ? b1 : ((mat == 1) ? b2 : bp);
  float* dst = (mat == 0) ? m1 : ((mat == 1) ? m2 : mp);
  int wave = t >> 6, lane = t & 63;
  const float4* w4 = reinterpret_cast<const float4*>(w);
  float4 sv = reinterpret_cast<const float4*>(sc)[lane];
  #pragma unroll
  for (int i = 0; i < 16; ++i) {
    int oo = wave * 16 + i;
    float4 wv = w4[oo * 64 + lane];  // 64 lanes = one 1KB row, coalesced
    float p = wv.x * sv.x + wv.y * sv.y + wv.z * sv.z + wv.w * sv.w;
    #pragma unroll
    for (int m = 1; m <= 32; m <<= 1) p += __shfl_xor(p, m);
    if (lane == 0) dst[b * 64 + oo] = p + bb[oo];
  }
}

// ---------------- 3x3x3 conv as implicit GEMM on bf16 MFMA 32x32x16 ----------------
// Block = (b, x, 8-y strip). 8 waves, wave = one y; acc = full 32z x 32co tile.
// W LDS: [k27][h2][lane64] 16B chunks -> A-read = base + lane*16B (linear).
// X LDS: [col30][c4 4][r34] 16B chunks -> B-read = 32 consecutive chunks per half-wave.
__global__ __launch_bounds__(512, 2) void k_conv(
    const u16* __restrict__ in, const u16* __restrict__ wt,
    const float* __restrict__ bias, u16* __restrict__ out) {
  __shared__ uint4 lds_w4[3456];   // 55296 B
  __shared__ uint4 lds_x4[4096];   // 65536 B (4080 used)
  int t = threadIdx.x;
  int blk = blockIdx.x;
  int yp = blk & 3, x = (blk >> 2) & 31, b = blk >> 7;
  int y0 = yp * 8;
  size_t bbase = (size_t)b * Vn;

  const uint4* gw = reinterpret_cast<const uint4*>(wt);
  for (int i = t; i < 3456; i += 512) lds_w4[i] = gw[i];

  for (int i = t; i < 4080; i += 512) {
    int col = i / 136, rem = i - col * 136;
    int c4 = rem / 34, r = rem - c4 * 34;
    int dxp = col / 10, yy = col - dxp * 10;
    int gx = x + dxp - 1, gy = y0 + yy - 1, z = r - 1;
    uint4 val = make_uint4(0u, 0u, 0u, 0u);
    if (gx >= 0 && gx < 32 && (unsigned)gy < 32u && (unsigned)z < 32u) {
      val = *reinterpret_cast<const uint4*>(
          in + (bbase + (size_t)((gx * 32 + gy) * 32 + z)) * 32 + c4 * 8);
    }
    lds_x4[i] = val;
  }
  __syncthreads();

  int w = t >> 6, lane = t & 63;
  int zc = lane & 31, hi = lane >> 5;
  int y = y0 + w;

  f32x16 acc;
  #pragma unroll
  for (int q = 0; q < 4; ++q) {
    float4 bq = *reinterpret_cast<const float4*>(bias + q * 8 + hi * 4);
    acc[q * 4 + 0] = bq.x; acc[q * 4 + 1] = bq.y;
    acc[q * 4 + 2] = bq.z; acc[q * 4 + 3] = bq.w;
  }

  const u16* lw = reinterpret_cast<const u16*>(lds_w4);
  const u16* lx = reinterpret_cast<const u16*>(lds_x4);

  #pragma unroll
  for (int dxp = 0; dxp < 3; ++dxp) {
    #pragma unroll
    for (int dyp = 0; dyp < 3; ++dyp) {
      int col = dxp * 10 + w + dyp;
      #pragma unroll
      for (int dzp = 0; dzp < 3; ++dzp) {
        int k = (dxp * 3 + dyp) * 3 + dzp;
        short8v a0 = *reinterpret_cast<const short8v*>(lw + ((k * 2 + 0) * 64 + lane) * 8);
        short8v a1 = *reinterpret_cast<const short8v*>(lw + ((k * 2 + 1) * 64 + lane) * 8);
        short8v b0 = *reinterpret_cast<const short8v*>(
            lx + ((col * 4 + hi) * 34 + zc + dzp) * 8);
        short8v b1 = *reinterpret_cast<const short8v*>(
            lx + ((col * 4 + 2 + hi) * 34 + zc + dzp) * 8);
        acc = __builtin_amdgcn_mfma_f32_32x32x16_bf16(a0, b0, acc, 0, 0, 0);
        acc = __builtin_amdgcn_mfma_f32_32x32x16_bf16(a1, b1, acc, 0, 0, 0);
      }
    }
  }

  // C/D: col(z)=lane&31, row(co)=(reg&3)+8*(reg>>2)+4*(lane>>5)
  size_t off = (bbase + (size_t)((x * 32 + y) * 32 + zc)) * 32;
  #pragma unroll
  for (int q = 0; q < 4; ++q) {
    uint2 o;
    o.x = pack2(acc[q * 4 + 0], acc[q * 4 + 1]);
    o.y = pack2(acc[q * 4 + 2], acc[q * 4 + 3]);
    *reinterpret_cast<uint2*>(out + off + q * 8 + hi * 4) = o;
  }
}

// ---------------- elementwise affine+silu on vox (in place) ----------------
__global__ void k_affsilu(uint4* __restrict__ x, const float* __restrict__ Ac,
                          const float* __restrict__ Bc) {
  int i = blockIdx.x * 256 + threadIdx.x;  // B*V*4 uint4s
  int c4 = i & 3, b = i >> 17;
  uint4 v = x[i];
  float f[8];
  unpack8(v, f);
  float4 A0 = reinterpret_cast<const float4*>(Ac)[b * 8 + c4 * 2];
  float4 A1 = reinterpret_cast<const float4*>(Ac)[b * 8 + c4 * 2 + 1];
  float4 B0 = reinterpret_cast<const float4*>(Bc)[b * 8 + c4 * 2];
  float4 B1 = reinterpret_cast<const float4*>(Bc)[b * 8 + c4 * 2 + 1];
  f[0] = siluf(f[0] * A0.x + B0.x); f[1] = siluf(f[1] * A0.y + B0.y);
  f[2] = siluf(f[2] * A0.z + B0.z); f[3] = siluf(f[3] * A0.w + B0.w);
  f[4] = siluf(f[4] * A1.x + B1.x); f[5] = siluf(f[5] * A1.y + B1.y);
  f[6] = siluf(f[6] * A1.z + B1.z); f[7] = siluf(f[7] * A1.w + B1.w);
  uint4 o;
  o.x = pack2(f[0], f[1]); o.y = pack2(f[2], f[3]);
  o.z = pack2(f[4], f[5]); o.w = pack2(f[6], f[7]);
  x[i] = o;
}

// ---------------- per-channel sum/sumsq, block-reduced (few atomics) ----------------
__global__ void k_stats_cl(const u16* __restrict__ x, float* __restrict__ psum,
                           float* __restrict__ psq) {
  int blk = blockIdx.x;  // 256 = B * 32 segments
  int b = blk >> 5, seg = blk & 31;
  int t = threadIdx.x;
  int c8 = t & 3, vsub = t >> 2;  // vsub 0..63 across block (16 per wave)
  float s[8], q[8];
  #pragma unroll
  for (int j = 0; j < 8; ++j) { s[j] = 0.f; q[j] = 0.f; }
  const uint4* xb = reinterpret_cast<const uint4*>(x + (size_t)b * Vn * Cn) +
                    (size_t)seg * 4096;
  for (int it = 0; it < 16; ++it) {
    int v = it * 64 + vsub;
    uint4 u = xb[v * 4 + c8];
    float f[8];
    unpack8(u, f);
    #pragma unroll
    for (int j = 0; j < 8; ++j) { s[j] += f[j]; q[j] += f[j] * f[j]; }
  }
  #pragma unroll
  for (int m = 4; m <= 32; m <<= 1) {
    #pragma unroll
    for (int j = 0; j < 8; ++j) {
      s[j] += __shfl_xor(s[j], m);
      q[j] += __shfl_xor(q[j], m);
    }
  }
  __shared__ float ls[2][4][4][8];  // [sum|sq][wave][c8][j]
  int wv = t >> 6;
  if ((t & 63) < 4) {
    #pragma unroll
    for (int j = 0; j < 8; ++j) { ls[0][wv][c8][j] = s[j]; ls[1][wv][c8][j] = q[j]; }
  }
  __syncthreads();
  if (t < 64) {
    int arr = t >> 5, c = t & 31;
    float v = ls[arr][0][c >> 3][c & 7] + ls[arr][1][c >> 3][c & 7] +
              ls[arr][2][c >> 3][c & 7] + ls[arr][3][c >> 3][c & 7];
    atomicAdd((arr == 0 ? psum : psq) + b * 32 + c, v);
  }
}

// ---------------- AdaGN affine coefficients (stage 1) ----------------
__global__ void k_coef1(const float* __restrict__ psum, const float* __restrict__ psq,
                        const float* __restrict__ mod, const float* __restrict__ g,
                        const float* __restrict__ bgn, float* __restrict__ A,
                        float* __restrict__ Bc) {
  int t = threadIdx.x;  // 256 = B*C
  int b = t >> 5, c = t & 31, grp = c >> 2;
  float s = 0, q = 0;
  for (int j = 0; j < 4; ++j) {
    s += psum[b * 32 + grp * 4 + j];
    q += psq[b * 32 + grp * 4 + j];
  }
  const float cntf = 4.0f * (float)Vn;
  float mean = s / cntf;
  float var = q / cntf - mean * mean;
  float rstd = rsqrtf(var + 1e-5f);
  float scale = mod[b * 64 + c], shift = mod[b * 64 + 32 + c];
  A[t] = rstd * g[c] * scale;
  Bc[t] = (bgn[c] - mean * rstd * g[c]) * scale + shift;
}

// ---------------- AdaGN stage 2 + SE -> final gather affine S,T ----------------
__global__ void k_coef2(const float* __restrict__ psum, const float* __restrict__ psq,
                        const float* __restrict__ mod, const float* __restrict__ g,
                        const float* __restrict__ bgn, const float* __restrict__ sw1,
                        const float* __restrict__ sw2, float* __restrict__ S,
                        float* __restrict__ T) {
  __shared__ float zm[8][32];
  __shared__ float hh[8][4];
  int t = threadIdx.x;  // 256 = B*C
  int b = t >> 5, c = t & 31, grp = c >> 2;
  float s = 0, q = 0;
  for (int j = 0; j < 4; ++j) {
    s += psum[b * 32 + grp * 4 + j];
    q += psq[b * 32 + grp * 4 + j];
  }
  const float cntf = 4.0f * (float)Vn;
  float mean = s / cntf;
  float var = q / cntf - mean * mean;
  float rstd = rsqrtf(var + 1e-5f);
  float scale = mod[b * 64 + c], shift = mod[b * 64 + 32 + c];
  float A = rstd * g[c] * scale;
  float Bv = (bgn[c] - mean * rstd * g[c]) * scale + shift;
  float chmean = psum[b * 32 + c] / (float)Vn;
  zm[b][c] = A * chmean + Bv;
  __syncthreads();
  if (t < 32) {
    int b2 = t >> 2, j = t & 3;
    float h = 0;
    for (int cc = 0; cc < 32; ++cc) h += sw1[j * 32 + cc] * zm[b2][cc];
    hh[b2][j] = fmaxf(h, 0.f);
  }
  __syncthreads();
  float sig = 0;
  for (int j = 0; j < 4; ++j) sig += sw2[c * 4 + j] * hh[b][j];
  sig = 1.0f / (1.0f + __expf(-sig));
  S[t] = A * sig;
  T[t] = Bv * sig;
}

// ---------------- trilinear devoxelize (bf16 vox) with fused affine ----------------
__global__ void k_devox(const u16* __restrict__ vox, const float* __restrict__ nc,
                        const float* __restrict__ S, const float* __restrict__ T,
                        float* __restrict__ out) {
  int i = blockIdx.x * 256 + threadIdx.x;  // B*N
  int b = i >> 14, n = i & (Nn - 1);
  const float* ncb = nc + (size_t)b * 3 * Nn;
  float fx = ncb[n], fy = ncb[Nn + n], fz = ncb[2 * Nn + n];
  float lxf = floorf(fx), lyf = floorf(fy), lzf = floorf(fz);
  float wx1 = fx - lxf, wy1 = fy - lyf, wz1 = fz - lzf;
  int lx = (int)lxf, ly = (int)lyf, lz = (int)lzf;
  int hx = min(lx + 1, 31), hy = min(ly + 1, 31), hz = min(lz + 1, 31);
  float a[32];
  #pragma unroll
  for (int c = 0; c < 32; ++c) a[c] = 0.f;
  for (int corner = 0; corner < 8; ++corner) {
    int cx = (corner & 4) ? hx : lx;
    int cy = (corner & 2) ? hy : ly;
    int cz = (corner & 1) ? hz : lz;
    float ww = ((corner & 4) ? wx1 : 1.f - wx1) *
               ((corner & 2) ? wy1 : 1.f - wy1) *
               ((corner & 1) ? wz1 : 1.f - wz1);
    const uint4* p = reinterpret_cast<const uint4*>(
        vox + ((size_t)b * Vn + (size_t)((cx * 32 + cy) * 32 + cz)) * 32);
    #pragma unroll
    for (int qq = 0; qq < 4; ++qq) {
      float f[8];
      unpack8(p[qq], f);
      #pragma unroll
      for (int j = 0; j < 8; ++j) a[qq * 8 + j] += ww * f[j];
    }
  }
  float* o = out + (size_t)b * 32 * Nn + n;
  #pragma unroll
  for (int c = 0; c < 32; ++c) {
    o[(size_t)c * Nn] = a[c] * S[b * 32 + c] + T[b * 32 + c];
  }
}

// ---------------- point branch: 1x1 conv (32x32 GEMM per point) ----------------
__global__ void k_pxlin(const float* __restrict__ feat, const float* __restrict__ w,
                        const float* __restrict__ bias, float* __restrict__ px) {
  __shared__ float lw[1024];
  __shared__ float lb[32];
  int t = threadIdx.x;
  for (int i = t; i < 1024; i += 256) lw[i] = w[i];
  if (t < 32) lb[t] = bias[t];
  __syncthreads();
  int blk = blockIdx.x;  // B*64
  int b = blk >> 6, tile = blk & 63;
  int n = tile * 256 + t;
  float fr[32];
  const float* fb = feat + (size_t)b * 32 * Nn + n;
  #pragma unroll
  for (int ci = 0; ci < 32; ++ci) fr[ci] = fb[(size_t)ci * Nn];
  float* ob = px + (size_t)b * 32 * Nn + n;
  for (int co = 0; co < 32; ++co) {
    float acc = lb[co];
    #pragma unroll
    for (int ci = 0; ci < 32; ++ci) acc += lw[co * 32 + ci] * fr[ci];
    ob[(size_t)co * Nn] = acc;
  }
}

// ---------------- point-branch group partial stats (few atomics) ----------------
__global__ void k_statsp(const float* __restrict__ px, float* __restrict__ pgsum,
                         float* __restrict__ pgsq) {
  int blk = blockIdx.x;  // 256 = B * G * 4 quarters
  int b = blk >> 5, g = (blk >> 2) & 7, qr = blk & 3;
  const float4* base = reinterpret_cast<const float4*>(
      px + (size_t)b * 32 * Nn + (size_t)g * 4 * Nn) + qr * 4096;
  float s = 0, q = 0;
  int t = threadIdx.x;
  for (int i = t; i < 4096; i += 256) {
    float4 v = base[i];
    s += v.x + v.y + v.z + v.w;
    q += v.x * v.x + v.y * v.y + v.z * v.z + v.w * v.w;
  }
  #pragma unroll
  for (int m = 1; m <= 32; m <<= 1) {
    s += __shfl_xor(s, m);
    q += __shfl_xor(q, m);
  }
  __shared__ float rs[4], rq[4];
  if ((t & 63) == 0) { rs[t >> 6] = s; rq[t >> 6] = q; }
  __syncthreads();
  if (t == 0) {
    atomicAdd(&pgsum[b * 8 + g], rs[0] + rs[1] + rs[2] + rs[3]);
    atomicAdd(&pgsq[b * 8 + g], rq[0] + rq[1] + rq[2] + rq[3]);
  }
}

// ---------------- point-branch affine coefficients ----------------
__global__ void k_coefp(const float* __restrict__ pgsum, const float* __restrict__ pgsq,
                        const float* __restrict__ mod, const float* __restrict__ g,
                        const float* __restrict__ bgn, float* __restrict__ A,
                        float* __restrict__ Bc) {
  int t = threadIdx.x;  // 256
  int b = t >> 5, c = t & 31, grp = c >> 2;
  float m = pgsum[b * 8 + grp] / 65536.f;
  float var = pgsq[b * 8 + grp] / 65536.f - m * m;
  float r = rsqrtf(var + 1e-5f);
  float scale = mod[b * 64 + c], shift = mod[b * 64 + 32 + c];
  A[t] = r * g[c] * scale;
  Bc[t] = (bgn[c] - m * r * g[c]) * scale + shift;
}

// ---------------- final: out += silu(px*A+B) ----------------
__global__ void k_final(const float* __restrict__ px, const float* __restrict__ A,
                        const float* __restrict__ Bc, float* __restrict__ out) {
  int i = blockIdx.x * 256 + threadIdx.x;  // B*C*N
  int bc = i >> 14;
  float y = px[i] * A[bc] + Bc[bc];
  out[i] += siluf(y);
}

}  // namespace

extern "C" void kernel_launch(void* const* d_in, const int* in_sizes, int n_in,
                              void* d_out, int out_size, void* d_ws, size_t ws_size,
                              hipStream_t stream) {
  (void)in_sizes; (void)n_in; (void)out_size; (void)ws_size;
  const float* features = (const float*)d_in[0];
  const float* coords = (const float*)d_in[1];
  const float* condition = (const float*)d_in[2];
  const float* conv1_w = (const float*)d_in[3];
  const float* conv1_b = (const float*)d_in[4];
  const float* gn1_g = (const float*)d_in[5];
  const float* gn1_b = (const float*)d_in[6];
  const float* mod1_w = (const float*)d_in[7];
  const float* mod1_b = (const float*)d_in[8];
  const float* conv2_w = (const float*)d_in[9];
  const float* conv2_b = (const float*)d_in[10];
  const float* gn2_g = (const float*)d_in[11];
  const float* gn2_b = (const float*)d_in[12];
  const float* mod2_w = (const float*)d_in[13];
  const float* mod2_b = (const float*)d_in[14];
  const float* se_w1 = (const float*)d_in[15];
  const float* se_w2 = (const float*)d_in[16];
  const float* pc_w = (const float*)d_in[17];
  const float* pc_b = (const float*)d_in[18];
  const float* gnp_g = (const float*)d_in[19];
  const float* gnp_b = (const float*)d_in[20];
  const float* modp_w = (const float*)d_in[21];
  const float* modp_b = (const float*)d_in[22];

  char* w = (char*)d_ws;
  // R0 (33.5 MB): [first half] featT f32 (until voxavg) -> vox1 bf16 (conv1 out,
  //               dead after conv2) -> px f32 (pxlin..final). [second half] vox2.
  float* featT = (float*)w;
  u16* vox1 = (u16*)w;
  float* px = (float*)w;
  u16* vox2 = (u16*)(w + 16777216);
  w += 33554432;
  // R1 (16.8 MB): vox0 bf16 (voxavg -> conv1)
  u16* vox0 = (u16*)w; w += 16777216;
  int* hist = (int*)w;  w += 1048576;   // hist..cmax share one memset block
  float* psum1 = (float*)w; w += 1024;
  float* psq1 = (float*)w;  w += 1024;
  float* psum2 = (float*)w; w += 1024;
  float* psq2 = (float*)w;  w += 1024;
  float* pgsum = (float*)w; w += 256;
  float* pgsq = (float*)w;  w += 256;
  float* csum = (float*)w;  w += 128;
  int* cmax = (int*)w;      w += 64;
  int* offs = (int*)w;  w += 1048576;
  int* bsum = (int*)w;  w += 1024;
  int* bbase = (int*)w; w += 1024;
  int* pidx = (int*)w;  w += 524288;
  float* ncb = (float*)w;   w += 1572864;
  int* vidx = (int*)w;      w += 524288;
  u16* wt1b = (u16*)w;      w += 55296;
  u16* wt2b = (u16*)w;      w += 55296;
  float* m1 = (float*)w;    w += 2048;
  float* m2 = (float*)w;    w += 2048;
  float* mp = (float*)w;    w += 2048;
  float* A1 = (float*)w;    w += 1024;
  float* B1 = (float*)w;    w += 1024;
  float* Sc = (float*)w;    w += 1024;
  float* Tc = (float*)w;    w += 1024;
  float* Ap = (float*)w;    w += 1024;
  float* Bp = (float*)w;    w += 1024;
  float* out = (float*)d_out;

  hipMemsetAsync(hist, 0, 1048576 + 4096 + 512 + 192, stream);

  k_cpart1<<<Bn * 8, 256, 0, stream>>>(coords, csum);
  k_ftr<<<Bn * 256, 256, 0, stream>>>(features, featT);
  k_twz<<<108, 256, 0, stream>>>(conv1_w, wt1b);
  k_twz<<<108, 256, 0, stream>>>(conv2_w, wt2b);
  k_mods<<<24, 256, 0, stream>>>(condition, mod1_w, mod1_b, mod2_w, mod2_b,
                                 modp_w, modp_b, m1, m2, mp);
  k_cpart2<<<Bn * 8, 256, 0, stream>>>(coords, csum, cmax);
  k_cfinal<<<(Bn * Nn) / 256, 256, 0, stream>>>(coords, csum, cmax, ncb, vidx, hist);
  k_scan1<<<256, 256, 0, stream>>>(hist, offs, bsum);
  k_scan2<<<1, 256, 0, stream>>>(bsum, bbase);
  k_sortidx<<<(Bn * Nn) / 256, 256, 0, stream>>>(vidx, offs, bbase, pidx);
  k_voxavg<<<(Bn * Vn) / 4, 256, 0, stream>>>(hist, offs, bbase, pidx, featT,
                                              (uint2*)vox0);
  k_conv<<<1024, 512, 0, stream>>>(vox0, wt1b, conv1_b, vox1);
  k_stats_cl<<<256, 256, 0, stream>>>(vox1, psum1, psq1);
  k_coef1<<<1, 256, 0, stream>>>(psum1, psq1, m1, gn1_g, gn1_b, A1, B1);
  k_affsilu<<<4096, 256, 0, stream>>>((uint4*)vox1, A1, B1);
  k_conv<<<1024, 512, 0, stream>>>(vox1, wt2b, conv2_b, vox2);
  k_stats_cl<<<256, 256, 0, stream>>>(vox2, psum2, psq2);
  k_coef2<<<1, 256, 0, stream>>>(psum2, psq2, m2, gn2_g, gn2_b, se_w1, se_w2, Sc, Tc);
  k_devox<<<(Bn * Nn) / 256, 256, 0, stream>>>(vox2, ncb, Sc, Tc, out);
  k_pxlin<<<Bn * 64, 256, 0, stream>>>(features, pc_w, pc_b, px);
  k_statsp<<<256, 256, 0, stream>>>(px, pgsum, pgsq);
  k_coefp<<<1, 256, 0, stream>>>(pgsum, pgsq, mp, gnp_g, gnp_b, Ap, Bp);
  k_final<<<(Bn * Cn * Nn) / 256, 256, 0, stream>>>(px, Ap, Bp, out);
}